// Round 9
// baseline (311.217 us; speedup 1.0000x reference)
//
#include <hip/hip_runtime.h>
#include <hip/hip_bf16.h>
#include <math.h>

using bf16 = __hip_bfloat16;

static constexpr int CDIM   = 192;
static constexpr int HEADS  = 6;
static constexpr int CP     = 32;     // CDIM / HEADS
static constexpr int HIDDEN = 384;
static constexpr int HImg   = 128;
static constexpr int WImg   = 128;
static constexpr int HW     = HImg * WImg;   // 16384
static constexpr int BATCH  = 4;
static constexpr int PCHUNK = 256;    // attn contraction chunk
static constexpr int CSPLIT = 12;     // gate conv channel splits (16 ch each)

typedef __attribute__((ext_vector_type(8))) short short8;
typedef __attribute__((ext_vector_type(4))) float f32x4;
typedef __attribute__((ext_vector_type(4))) unsigned short ushort4v;
typedef __attribute__((ext_vector_type(8))) unsigned short ushort8v;

template<typename T> __device__ inline float tof(T v);
template<> __device__ inline float tof<float>(float v){ return v; }
template<> __device__ inline float tof<bf16>(bf16 v){ return __bfloat162float(v); }

template<typename T> __device__ inline T fromf(float v);
template<> __device__ inline float fromf<float>(float v){ return v; }
template<> __device__ inline bf16  fromf<bf16>(float v){ return __float2bfloat16(v); }

__device__ inline unsigned short f2bf_bits(float f){
    bf16 h = __float2bfloat16(f);
    return *reinterpret_cast<unsigned short*>(&h);
}
__device__ inline float bfbits2f(unsigned short u){
    union { unsigned int i; float f; } c; c.i = ((unsigned int)u) << 16; return c.f;
}

__device__ inline float gelu_exact(float x){
    return 0.5f * x * (1.0f + erff(x * 0.70710678118654752440f));
}

// load 4 consecutive elems as float
__device__ inline void load4f(const float* p, float* f){
    f32x4 v = *reinterpret_cast<const f32x4*>(p);
    f[0]=v[0]; f[1]=v[1]; f[2]=v[2]; f[3]=v[3];
}
__device__ inline void load4f(const bf16* p, float* f){
    ushort4v v = *reinterpret_cast<const ushort4v*>(p);
    f[0]=bfbits2f(v[0]); f[1]=bfbits2f(v[1]); f[2]=bfbits2f(v[2]); f[3]=bfbits2f(v[3]);
}

// async global(16B) -> LDS
__device__ __forceinline__ void gload16(const bf16* g, bf16* l){
    __builtin_amdgcn_global_load_lds(
        (const __attribute__((address_space(1))) void*)g,
        (__attribute__((address_space(3))) void*)l, 16, 0, 0);
}

// ---------------- merged f32 -> bf16 weight convert --------------------------
__global__ __launch_bounds__(256) void convw_kernel(
    const float* __restrict__ w_qkv, const float* __restrict__ w_proj,
    const float* __restrict__ w_fc1, const float* __restrict__ w_fc2,
    bf16* __restrict__ wq, bf16* __restrict__ wp,
    bf16* __restrict__ wf1, bf16* __restrict__ wf2)
{
    int i = blockIdx.x * 256 + threadIdx.x;
    const int n0 = 576*192, n1 = n0 + 192*192, n2 = n1 + 384*192, n3 = n2 + 192*384;
    if (i < n0)      wq[i]       = fromf<bf16>(w_qkv[i]);
    else if (i < n1) wp[i - n0]  = fromf<bf16>(w_proj[i - n0]);
    else if (i < n2) wf1[i - n1] = fromf<bf16>(w_fc1[i - n1]);
    else if (i < n3) wf2[i - n2] = fromf<bf16>(w_fc2[i - n2]);
}

// ---------------- fused LayerNorm (+optional bf16 [C][HW] copy) + transpose --
template<typename T, bool WRES>
__global__ __launch_bounds__(256) void ln_fused_kernel(
    const T* __restrict__ in, const float* __restrict__ g,
    const float* __restrict__ b, bf16* __restrict__ resF, bf16* __restrict__ outT)
{
    int z = blockIdx.y, p0 = blockIdx.x * 64;
    __shared__ float tile[CDIM][65];
    __shared__ float sred[4][64], s2red[4][64];
    __shared__ float mrow[64], rrow[64];
    const T* ib = in + (size_t)z * CDIM * HW + p0;
    int tid = threadIdx.x;
    for (int j = tid; j < CDIM * 16; j += 256){
        int c = j >> 4, p4 = (j & 15) * 4;
        float f[4];
        load4f(ib + (size_t)c * HW + p4, f);
        tile[c][p4]   = f[0]; tile[c][p4+1] = f[1];
        tile[c][p4+2] = f[2]; tile[c][p4+3] = f[3];
    }
    __syncthreads();
    int p = tid & 63, q = tid >> 6;
    float s = 0.f, s2 = 0.f;
    #pragma unroll 4
    for (int c = q * 48; c < q * 48 + 48; ++c){
        float v = tile[c][p]; s += v; s2 += v * v;
    }
    sred[q][p] = s; s2red[q][p] = s2;
    __syncthreads();
    if (tid < 64){
        float ts = sred[0][tid] + sred[1][tid] + sred[2][tid] + sred[3][tid];
        float t2 = s2red[0][tid] + s2red[1][tid] + s2red[2][tid] + s2red[3][tid];
        float mean = ts * (1.0f / CDIM);
        float var  = t2 * (1.0f / CDIM) - mean * mean;
        mrow[tid] = mean;
        rrow[tid] = rsqrtf(var + 1e-5f);
    }
    __syncthreads();
    unsigned short* oT = (unsigned short*)(outT + ((size_t)z * HW + p0) * CDIM);
    for (int j = tid; j < 64 * 48; j += 256){
        int pr = j / 48, c4 = (j % 48) * 4;
        float m = mrow[pr], r = rrow[pr];
        ushort4v o;
        #pragma unroll
        for (int k = 0; k < 4; ++k){
            int c = c4 + k;
            o[k] = f2bf_bits((tile[c][pr] - m) * r * g[c] + b[c]);
        }
        *(ushort4v*)&oT[(size_t)pr * CDIM + c4] = o;
    }
    if (WRES){
        unsigned short* oF = (unsigned short*)resF + (size_t)z * CDIM * HW + p0;
        for (int j = tid; j < CDIM * 16; j += 256){
            int c = j >> 4, p4 = (j & 15) * 4;
            float gg = g[c], bb = b[c];
            ushort4v v;
            #pragma unroll
            for (int k = 0; k < 4; ++k)
                v[k] = f2bf_bits((tile[c][p4 + k] - mrow[p4 + k]) * rrow[p4 + k] * gg + bb);
            *(ushort4v*)&oF[(size_t)c * HW + p4] = v;
        }
    }
}

// ---------------- MFMA GEMM: C[M,N] = Wb[M,K] @ XT[N,K]^T, batched -----------
// Block tile 192m x 128n (M always divisible by 192 here), 2x2 waves of
// 96m x 64n -> 24 MFMA per 10 ds_read per ks. Single-buffered LDS staging via
// global_load_lds (round-5 sync structure, known-good). LDS 52 KB -> 3 blk/CU.
// EPI: 0 = bf16 out [M][HW]; 1 = bf16 out + bf16 residual; 2 = bias+gelu bf16;
//      3 = bias+gelu -> transposed bf16 out [HW][M]
template<int EPI>
__global__ __launch_bounds__(256) void gemm_mfma_kernel(
    const bf16* __restrict__ Wb, const bf16* __restrict__ XT,
    void* __restrict__ Cout, const float* __restrict__ bias,
    const bf16* __restrict__ res, int M, int K)
{
    __shared__ bf16 smem[26624];              // 52 KB: A 192x64 (24K) + B 128x64 (16K); epilogue reuse
    bf16* Als = smem;
    bf16* Bls = smem + 12288;
    int z  = blockIdx.z;
    int n0 = blockIdx.x * 128;
    int m0 = blockIdx.y * 192;
    const bf16* Xb = XT + (size_t)z * (size_t)HW * K;
    int tid  = threadIdx.x;
    int lane = tid & 63, wid = tid >> 6;
    int wm = wid & 1, wn = wid >> 1;          // 2x2 waves, each 96m x 64n
    int r16 = lane & 15, grp = lane >> 4;

    f32x4 acc[6][4];
    #pragma unroll
    for (int i = 0; i < 6; ++i)
        #pragma unroll
        for (int j = 0; j < 4; ++j){ f32x4 zz = {0.f,0.f,0.f,0.f}; acc[i][j] = zz; }

    int nkt = K >> 6;
    for (int kt = 0; kt < nkt; ++kt){
        #pragma unroll
        for (int i = 0; i < 6; ++i){          // A: 192 rows x 8 slots = 1536
            int s = i * 256 + tid;
            int row = s >> 3, ch = s & 7;
            gload16(Wb + (size_t)(m0 + row) * K + kt * 64 + ((ch ^ (row & 7)) * 8),
                    Als + s * 8);
        }
        #pragma unroll
        for (int i = 0; i < 4; ++i){          // B: 128 rows x 8 slots = 1024
            int s = i * 256 + tid;
            int row = s >> 3, ch = s & 7;
            gload16(Xb + (size_t)(n0 + row) * K + kt * 64 + ((ch ^ (row & 7)) * 8),
                    Bls + s * 8);
        }
        asm volatile("s_waitcnt vmcnt(0)" ::: "memory");
        __syncthreads();
        #pragma unroll
        for (int ks = 0; ks < 2; ++ks){
            int kel = ks * 32 + grp * 8;
            short8 a[6], b[4];
            #pragma unroll
            for (int fi = 0; fi < 6; ++fi){
                int row = wm * 96 + fi * 16 + r16;
                a[fi] = *reinterpret_cast<const short8*>(Als + row * 64 + (kel ^ ((row & 7) * 8)));
            }
            #pragma unroll
            for (int fj = 0; fj < 4; ++fj){
                int row = wn * 64 + fj * 16 + r16;
                b[fj] = *reinterpret_cast<const short8*>(Bls + row * 64 + (kel ^ ((row & 7) * 8)));
            }
            #pragma unroll
            for (int fi = 0; fi < 6; ++fi)
                #pragma unroll
                for (int fj = 0; fj < 4; ++fj)
                    acc[fi][fj] = __builtin_amdgcn_mfma_f32_16x16x32_bf16(
                        a[fi], b[fj], acc[fi][fj], 0, 0, 0);
        }
        __syncthreads();
    }

    if (EPI == 3){
        // transposed bf16 out via LDS T[n(128)][m(192)] stride 200
        unsigned short* T = (unsigned short*)smem;
        #pragma unroll
        for (int fi = 0; fi < 6; ++fi)
            #pragma unroll
            for (int fj = 0; fj < 4; ++fj){
                int nl = wn * 64 + fj * 16 + r16;
                int mb = wm * 96 + fi * 16 + grp * 4;
                #pragma unroll
                for (int rr = 0; rr < 4; ++rr){
                    float v = gelu_exact(acc[fi][fj][rr] + bias[m0 + mb + rr]);
                    T[nl * 200 + mb + rr] = f2bf_bits(v);
                }
            }
        __syncthreads();
        bf16* Y = (bf16*)Cout;
        int nrow = tid >> 1, half = tid & 1;
        #pragma unroll
        for (int j = 0; j < 12; ++j){
            int m8 = half * 96 + j * 8;
            *reinterpret_cast<short8*>(Y + ((size_t)z * HW + n0 + nrow) * M + m0 + m8) =
                *reinterpret_cast<const short8*>(&T[nrow * 200 + m8]);
        }
        return;
    }

    // [M][HW] epilogues via LDS T[m(192)][n(128)] stride 136, 16B stores
    {
        unsigned short* T = (unsigned short*)smem;
        #pragma unroll
        for (int fi = 0; fi < 6; ++fi)
            #pragma unroll
            for (int fj = 0; fj < 4; ++fj){
                int m = wm * 96 + fi * 16 + grp * 4;
                int n = wn * 64 + fj * 16 + r16;
                #pragma unroll
                for (int rr = 0; rr < 4; ++rr)
                    T[(m + rr) * 136 + n] = f2bf_bits(acc[fi][fj][rr]);
            }
        __syncthreads();
        bf16* Cb = (bf16*)Cout;
        #pragma unroll
        for (int j = 0; j < 12; ++j){
            int chunk = j * 256 + tid;
            int row = chunk >> 4, c8 = (chunk & 15) * 8;
            size_t gbase = (size_t)z * M * HW + (size_t)(m0 + row) * HW + n0 + c8;
            ushort8v t8 = *(const ushort8v*)&T[row * 136 + c8];
            ushort8v o8;
            if (EPI == 0){
                o8 = t8;
            } else if (EPI == 1){
                ushort8v r8 = *(const ushort8v*)((const unsigned short*)res + gbase);
                #pragma unroll
                for (int k = 0; k < 8; ++k)
                    o8[k] = f2bf_bits(bfbits2f(t8[k]) + bfbits2f(r8[k]));
            } else {
                float bv = bias[m0 + row];
                #pragma unroll
                for (int k = 0; k < 8; ++k)
                    o8[k] = f2bf_bits(gelu_exact(bfbits2f(t8[k]) + bv));
            }
            *(ushort8v*)((unsigned short*)Cb + gbase) = o8;
        }
    }
}

// ---------------- depthwise 3x3 (8 px/thread, shfl halos) + q/k sumsq --------
__global__ __launch_bounds__(256) void dw_kernel(
    const bf16* __restrict__ in, const float* __restrict__ wdw,
    bf16* __restrict__ out, float* __restrict__ sqp)
{
    int ch = blockIdx.y, z = blockIdx.z;
    int tid = threadIdx.x;
    int idx = blockIdx.x * 2048 + tid * 8;        // 8 contiguous pixels, one row
    int yy = idx >> 7, xx = idx & 127;            // xx multiple of 8
    const unsigned short* p =
        (const unsigned short*)(in + ((size_t)z * 3 * CDIM + ch) * HW);
    float w[9];
    #pragma unroll
    for (int t = 0; t < 9; ++t) w[t] = wdw[ch * 9 + t];
    float f[3][8], lf[3], rf[3];
    #pragma unroll
    for (int dy = 0; dy < 3; ++dy){
        int iy = yy + dy - 1;
        if (iy >= 0 && iy < HImg){
            ushort8v v8 = *(const ushort8v*)(p + iy * WImg + xx);
            #pragma unroll
            for (int j = 0; j < 8; ++j) f[dy][j] = bfbits2f(v8[j]);
        } else {
            #pragma unroll
            for (int j = 0; j < 8; ++j) f[dy][j] = 0.f;
        }
        float l = __shfl_up(f[dy][7], 1);
        float r = __shfl_down(f[dy][0], 1);
        lf[dy] = (xx == 0) ? 0.f : l;             // 16 lanes per image row
        rf[dy] = (xx + 8 >= WImg) ? 0.f : r;
    }
    ushort8v o8;
    float sq = 0.f;
    #pragma unroll
    for (int j = 0; j < 8; ++j){
        float a = 0.f;
        #pragma unroll
        for (int dy = 0; dy < 3; ++dy){
            float e0 = (j == 0) ? lf[dy] : f[dy][j - 1];
            float e2 = (j == 7) ? rf[dy] : f[dy][j + 1];
            a = fmaf(w[dy*3], e0, fmaf(w[dy*3+1], f[dy][j], fmaf(w[dy*3+2], e2, a)));
        }
        o8[j] = f2bf_bits(a);
        sq = fmaf(a, a, sq);
    }
    *(ushort8v*)((unsigned short*)(out + ((size_t)z * 3 * CDIM + ch) * HW) + idx) = o8;
    if (ch < 2 * CDIM){
        #pragma unroll
        for (int m = 1; m < 64; m <<= 1) sq += __shfl_xor(sq, m, 64);
        __shared__ float red[4];
        if ((tid & 63) == 0) red[tid >> 6] = sq;
        __syncthreads();
        if (tid == 0)
            sqp[((size_t)ch * BATCH + z) * 8 + blockIdx.x] =
                red[0] + red[1] + red[2] + red[3];
    }
}

// ---------------- attn partials (inline l2-inv from sqp) ---------------------
__global__ __launch_bounds__(256) void attn_qk_kernel(
    const bf16* __restrict__ qkv, const float* __restrict__ sqp,
    const float* __restrict__ temp, float* __restrict__ part)
{
    int chunk = blockIdx.x;
    int h = blockIdx.y, z = blockIdx.z;
    __shared__ unsigned short qs[CP][PCHUNK + 4];
    __shared__ unsigned short ks[CP][PCHUNK + 4];
    __shared__ float invqs[CP], invks[CP];
    int tid = threadIdx.x;
    if (tid < 2 * CP){
        int which = tid >> 5, cc = tid & 31;
        int ch = which * CDIM + h * CP + cc;
        const float* sp = &sqp[((size_t)ch * BATCH + z) * 8];
        float s = sp[0]+sp[1]+sp[2]+sp[3]+sp[4]+sp[5]+sp[6]+sp[7];
        float inv = 1.0f / fmaxf(sqrtf(s), 1e-12f);
        (which ? invks : invqs)[cc] = inv;
    }
    int n0 = chunk * PCHUNK;
    const unsigned short* qb = (const unsigned short*)(qkv + ((size_t)z * 3 * CDIM + h * CP) * HW);
    const unsigned short* kb = (const unsigned short*)(qkv + ((size_t)z * 3 * CDIM + CDIM + h * CP) * HW);
    for (int i = tid; i < CP * (PCHUNK / 4); i += 256){
        int r = i >> 6, p4 = i & 63;
        *(ushort4v*)&qs[r][p4 * 4] = *(const ushort4v*)&qb[(size_t)r * HW + n0 + p4 * 4];
        *(ushort4v*)&ks[r][p4 * 4] = *(const ushort4v*)&kb[(size_t)r * HW + n0 + p4 * 4];
    }
    __syncthreads();
    int c  = tid >> 3;
    int d0 = (tid & 7) * 4;
    float acc[4] = {0.f, 0.f, 0.f, 0.f};
    for (int p4 = 0; p4 < PCHUNK / 4; ++p4){
        ushort4v qv = *(const ushort4v*)&qs[c][p4 * 4];
        float qf0 = bfbits2f(qv[0]), qf1 = bfbits2f(qv[1]);
        float qf2 = bfbits2f(qv[2]), qf3 = bfbits2f(qv[3]);
        #pragma unroll
        for (int j = 0; j < 4; ++j){
            ushort4v kv = *(const ushort4v*)&ks[d0 + j][p4 * 4];
            acc[j] = fmaf(qf0, bfbits2f(kv[0]),
                     fmaf(qf1, bfbits2f(kv[1]),
                     fmaf(qf2, bfbits2f(kv[2]),
                     fmaf(qf3, bfbits2f(kv[3]), acc[j]))));
        }
    }
    float sc = invqs[c] * temp[h];
    size_t base = ((size_t)chunk * BATCH * HEADS + (size_t)z * HEADS + h) * CP * CP
                + c * CP + d0;
    #pragma unroll
    for (int j = 0; j < 4; ++j)
        part[base + j] = acc[j] * sc * invks[d0 + j];
}

__global__ __launch_bounds__(256) void attn_reduce_kernel(
    const float* __restrict__ part, float* __restrict__ attn)
{
    int idx = blockIdx.x * 256 + threadIdx.x;
    float s = 0.f;
    for (int ch = 0; ch < HW / PCHUNK; ++ch)
        s += part[(size_t)ch * (BATCH * HEADS * CP * CP) + idx];
    attn[idx] = s;
}

// ---------------- head conv 3x3 + softmax (merged) ---------------------------
__global__ __launch_bounds__(256) void headconv_softmax_kernel(
    const float* __restrict__ attn, const float* __restrict__ wh,
    float* __restrict__ attn2)
{
    int oh = blockIdx.x, z = blockIdx.y;
    __shared__ float wsm[HEADS * 9];
    __shared__ float ain[HEADS][CP * CP];
    __shared__ float aout[CP * CP];
    int tid = threadIdx.x;
    if (tid < HEADS * 9) wsm[tid] = wh[oh * HEADS * 9 + tid];
    for (int i = tid; i < HEADS * CP * CP; i += 256)
        ain[i >> 10][i & 1023] = attn[((size_t)z * HEADS + (i >> 10)) * CP * CP + (i & 1023)];
    __syncthreads();
    for (int idx = tid; idx < CP * CP; idx += 256){
        int i = idx >> 5, j = idx & 31;
        float acc = 0.f;
        #pragma unroll
        for (int ih = 0; ih < HEADS; ++ih){
            #pragma unroll
            for (int dy = 0; dy < 3; ++dy){
                int ii = i + dy - 1;
                if (ii < 0 || ii >= CP) continue;
                #pragma unroll
                for (int dx = 0; dx < 3; ++dx){
                    int jj = j + dx - 1;
                    if (jj < 0 || jj >= CP) continue;
                    acc += wsm[ih * 9 + dy * 3 + dx] * ain[ih][ii * CP + jj];
                }
            }
        }
        aout[idx] = acc;
    }
    __syncthreads();
    int r = tid >> 3, l8 = tid & 7;
    float v[4];
    #pragma unroll
    for (int k = 0; k < 4; ++k) v[k] = aout[r * CP + l8 * 4 + k];
    float mx = fmaxf(fmaxf(v[0], v[1]), fmaxf(v[2], v[3]));
    #pragma unroll
    for (int m = 1; m < 8; m <<= 1) mx = fmaxf(mx, __shfl_xor(mx, m, 64));
    float sum = 0.f;
    #pragma unroll
    for (int k = 0; k < 4; ++k){ v[k] = expf(v[k] - mx); sum += v[k]; }
    #pragma unroll
    for (int m = 1; m < 8; m <<= 1) sum += __shfl_xor(sum, m, 64);
    float rs = 1.0f / sum;
    float* o = attn2 + ((size_t)z * HEADS + oh) * CP * CP + r * CP + l8 * 4;
    #pragma unroll
    for (int k = 0; k < 4; ++k) o[k] = v[k] * rs;
}

// ---------------- out = attn2 @ v -> transposed bf16 [HW][C] -----------------
__global__ __launch_bounds__(256) void av_kernel(
    const float* __restrict__ attn2, const bf16* __restrict__ qkv, bf16* __restrict__ outT)
{
    int h = blockIdx.y, z = blockIdx.z;
    int tid = threadIdx.x;
    __shared__ float As[CP][CP];
    __shared__ unsigned short Vs[CP][PCHUNK];
    __shared__ unsigned short ot[256][36];
    for (int i = tid; i < CP * CP; i += 256)
        As[i >> 5][i & 31] = attn2[((size_t)(z * HEADS + h)) * CP * CP + i];
    int n0 = blockIdx.x * 256;
    const unsigned short* vb =
        (const unsigned short*)(qkv + ((size_t)z * 3 * CDIM + 2 * CDIM + h * CP) * HW) + n0;
    for (int i = tid; i < CP * 64; i += 256){
        int d = i >> 6, p4 = (i & 63) * 4;
        *(ushort4v*)&Vs[d][p4] = *(const ushort4v*)(vb + (size_t)d * HW + p4);
    }
    __syncthreads();
    float vreg[CP];
    #pragma unroll
    for (int d = 0; d < CP; ++d) vreg[d] = bfbits2f(Vs[d][tid]);
    for (int c = 0; c < CP; ++c){
        float acc = 0.f;
        #pragma unroll
        for (int d = 0; d < CP; ++d) acc = fmaf(As[c][d], vreg[d], acc);
        ot[tid][c] = f2bf_bits(acc);
    }
    __syncthreads();
    unsigned short* ob = (unsigned short*)outT
        + ((size_t)z * HW + (size_t)n0) * CDIM + h * CP;
    for (int j = tid; j < 256 * 8; j += 256){
        int row = j >> 3, q4 = (j & 7) * 4;
        *(ushort4v*)&ob[(size_t)row * CDIM + q4] = *(ushort4v*)&ot[row][q4];
    }
}

// ---------------- spatial gate partials (16 ch/block, 8 px/thread, bf16 in) --
__global__ __launch_bounds__(256) void gate_partial_kernel(
    const bf16* __restrict__ y, const float* __restrict__ wsa,
    float* __restrict__ part_g)
{
    int cs = blockIdx.y, z = blockIdx.z;
    __shared__ float wsm[16 * 9];
    if (threadIdx.x < 144) wsm[threadIdx.x] = wsa[cs * 144 + threadIdx.x];
    __syncthreads();
    int idx = blockIdx.x * 2048 + threadIdx.x * 8;
    int yy = idx >> 7, xx = idx & 127;
    const unsigned short* yb =
        (const unsigned short*)(y + (size_t)z * CDIM * HW + (size_t)cs * 16 * HW);
    float acc[8] = {0.f,0.f,0.f,0.f,0.f,0.f,0.f,0.f};
    for (int c = 0; c < 16; ++c){
        const unsigned short* pc = yb + (size_t)c * HW;
        #pragma unroll
        for (int dy = 0; dy < 3; ++dy){
            int iy = yy + dy - 1;
            float f[8], lf, rf;
            if (iy >= 0 && iy < HImg){
                ushort8v v8 = *(const ushort8v*)(pc + iy * WImg + xx);
                #pragma unroll
                for (int j = 0; j < 8; ++j) f[j] = bfbits2f(v8[j]);
            } else {
                #pragma unroll
                for (int j = 0; j < 8; ++j) f[j] = 0.f;
            }
            float l = __shfl_up(f[7], 1);
            float r = __shfl_down(f[0], 1);
            lf = (xx == 0) ? 0.f : l;
            rf = (xx + 8 >= WImg) ? 0.f : r;
            const float* wr = &wsm[c * 9 + dy * 3];
            #pragma unroll
            for (int j = 0; j < 8; ++j){
                float e0 = (j == 0) ? lf : f[j - 1];
                float e2 = (j == 7) ? rf : f[j + 1];
                acc[j] = fmaf(wr[0], e0, fmaf(wr[1], f[j], fmaf(wr[2], e2, acc[j])));
            }
        }
    }
    float* og = &part_g[((size_t)cs * BATCH + z) * HW + idx];
    f32x4 o0 = {acc[0], acc[1], acc[2], acc[3]};
    f32x4 o1 = {acc[4], acc[5], acc[6], acc[7]};
    *(f32x4*)og = o0;
    *(f32x4*)(og + 4) = o1;
}

__global__ __launch_bounds__(256) void gate_finish_kernel(
    const float* __restrict__ part_g, const float* __restrict__ bsa,
    float* __restrict__ gate)
{
    int i4 = (blockIdx.x * 256 + threadIdx.x) * 4;   // < BATCH*HW
    float b0 = bsa[0];
    f32x4 acc = {b0, b0, b0, b0};
    #pragma unroll
    for (int cs = 0; cs < CSPLIT; ++cs){
        f32x4 v = *(const f32x4*)&part_g[(size_t)cs * BATCH * HW + i4];
        #pragma unroll
        for (int j = 0; j < 4; ++j) acc[j] += v[j];
    }
    f32x4 o;
    #pragma unroll
    for (int j = 0; j < 4; ++j) o[j] = 1.0f / (1.0f + expf(-acc[j]));
    *(f32x4*)&gate[i4] = o;
}

// ---------------- final: out = x2 + y2 * gate (8 px/thread, bf16 ins) --------
__global__ __launch_bounds__(256) void final_kernel(
    const bf16* __restrict__ x2, const bf16* __restrict__ y2,
    const float* __restrict__ gate, float* __restrict__ out)
{
    size_t i8 = ((size_t)blockIdx.x * 256 + threadIdx.x) * 8;
    int n = (int)(i8 % HW);
    int z = (int)(i8 / ((size_t)CDIM * HW));
    ushort8v a8 = *(const ushort8v*)((const unsigned short*)x2 + i8);
    ushort8v b8 = *(const ushort8v*)((const unsigned short*)y2 + i8);
    const float* gp = gate + (size_t)z * HW + n;
    f32x4 g0 = *(const f32x4*)gp;
    f32x4 g1 = *(const f32x4*)(gp + 4);
    f32x4 o0, o1;
    #pragma unroll
    for (int j = 0; j < 4; ++j){
        o0[j] = bfbits2f(a8[j])     + bfbits2f(b8[j])     * g0[j];
        o1[j] = bfbits2f(a8[j + 4]) + bfbits2f(b8[j + 4]) * g1[j];
    }
    *(f32x4*)(out + i8) = o0;
    *(f32x4*)(out + i8 + 4) = o1;
}

extern "C" void kernel_launch(void* const* d_in, const int* in_sizes, int n_in,
                              void* d_out, int out_size, void* d_ws, size_t ws_size,
                              hipStream_t stream)
{
    const float* x      = (const float*)d_in[0];
    const float* g1     = (const float*)d_in[1];
    const float* b1     = (const float*)d_in[2];
    const float* w_qkv  = (const float*)d_in[3];
    const float* w_dw   = (const float*)d_in[4];
    const float* temp   = (const float*)d_in[5];
    const float* w_head = (const float*)d_in[6];
    const float* w_proj = (const float*)d_in[7];
    const float* g2     = (const float*)d_in[8];
    const float* b2     = (const float*)d_in[9];
    const float* w_fc1  = (const float*)d_in[10];
    const float* b_fc1  = (const float*)d_in[11];
    const float* w_fc2  = (const float*)d_in[12];
    const float* b_fc2  = (const float*)d_in[13];
    const float* w_sa   = (const float*)d_in[14];
    const float* b_sa   = (const float*)d_in[15];
    float* out = (float*)d_out;

    char* ws = (char*)d_ws;
    const size_t FULL = (size_t)BATCH * CDIM * HW;      // 12.58M elems

    // R0 (FULL*2 B): x1 bf16 [C][HW] -> y2 bf16 [C][HW]
    bf16* x1 = (bf16*)ws;
    bf16* y2 = x1;
    // R1 (3*FULL*2 B): qkvA bf16 -> attn_outT bf16 / ln2T bf16 / y1T bf16
    char* R1 = ws + FULL * 2;
    bf16*  qkvA      = (bf16*)R1;
    bf16*  attn_outT = (bf16*)R1;
    bf16*  ln2T      = (bf16*)R1;
    bf16*  y1T       = (bf16*)(R1 + FULL * 2);
    // R2 (3*FULL*2 B): x1T bf16 -> dwB bf16 -> x2 bf16
    char* R2 = R1 + FULL * 3 * 2;
    bf16*  x1T = (bf16*)R2;
    bf16*  dwB = (bf16*)R2;
    bf16*  x2  = (bf16*)R2;
    // small region
    char* SM = R2 + FULL * 3 * 2;
    float* attn   = (float*)SM;                             // B*HEADS*CP*CP
    float* attn2  = attn + BATCH * HEADS * CP * CP;
    float* gate   = attn2 + BATCH * HEADS * CP * CP;        // B*HW
    float* sqp    = gate + BATCH * HW;                      // 2*CDIM*B*8
    float* part   = sqp + 2 * CDIM * BATCH * 8;             // 64*B*H*CP*CP (6.3MB)
    float* part_g = part;                                   // aliases part (dead)
    bf16* wq_b  = (bf16*)(part + (HW / PCHUNK) * BATCH * HEADS * CP * CP);
    bf16* wp_b  = wq_b  + 576 * 192;
    bf16* wf1_b = wp_b  + 192 * 192;
    bf16* wf2_b = wf1_b + 384 * 192;

    dim3 blk(256);

    // 0. merged weight conversion to bf16
    convw_kernel<<<dim3((294912 + 255) / 256), blk, 0, stream>>>(
        w_qkv, w_proj, w_fc1, w_fc2, wq_b, wp_b, wf1_b, wf2_b);
    // 1. LayerNorm1 fused: x -> x1 (bf16 [C][HW] residual) + x1T (bf16 [HW][C])
    ln_fused_kernel<float, true><<<dim3(HW / 64, BATCH), blk, 0, stream>>>(
        x, g1, b1, x1, x1T);
    // 2. qkv GEMM -> bf16 [3C][HW]  (M=576 = 3 x 192)
    gemm_mfma_kernel<0><<<dim3(HW / 128, 3, BATCH), blk, 0, stream>>>(
        wq_b, x1T, qkvA, nullptr, nullptr, 3 * CDIM, CDIM);
    // 3. depthwise 3x3 (8 px/thread, shfl halos) + q/k sumsq partials
    dw_kernel<<<dim3(HW / 2048, 3 * CDIM, BATCH), blk, 0, stream>>>(qkvA, w_dw, dwB, sqp);
    // 4. attn partial dot-products (inline l2-inv)
    attn_qk_kernel<<<dim3(HW / PCHUNK, HEADS, BATCH), blk, 0, stream>>>(
        dwB, sqp, temp, part);
    // 5. deterministic reduction of partials
    attn_reduce_kernel<<<dim3((BATCH * HEADS * CP * CP) / 256), blk, 0, stream>>>(part, attn);
    // 6. head conv + softmax (merged)
    headconv_softmax_kernel<<<dim3(HEADS, BATCH), blk, 0, stream>>>(attn, w_head, attn2);
    // 7. out = attn @ v -> bf16 [HW][C] (pre-transposed for proj)
    av_kernel<<<dim3(HW / 256, HEADS, BATCH), blk, 0, stream>>>(attn2, dwB, attn_outT);
    // 8. proj GEMM + residual(x1 bf16) -> x2 bf16 [C][HW]  (M=192)
    gemm_mfma_kernel<1><<<dim3(HW / 128, 1, BATCH), blk, 0, stream>>>(
        wp_b, attn_outT, x2, nullptr, x1, CDIM, CDIM);
    // 9. LayerNorm2 fused (bf16 in) -> ln2T bf16 [HW][C]
    ln_fused_kernel<bf16, false><<<dim3(HW / 64, BATCH), blk, 0, stream>>>(
        x2, g2, b2, nullptr, ln2T);
    // 10. fc1 GEMM + bias + gelu -> y1T bf16 [HW][HIDDEN]  (M=384 = 2 x 192)
    gemm_mfma_kernel<3><<<dim3(HW / 128, 2, BATCH), blk, 0, stream>>>(
        wf1_b, ln2T, y1T, b_fc1, nullptr, HIDDEN, CDIM);
    // 11. fc2 GEMM + bias + gelu -> y2 bf16 [C][HW]  (M=192, K=384)
    gemm_mfma_kernel<2><<<dim3(HW / 128, 1, BATCH), blk, 0, stream>>>(
        wf2_b, y1T, y2, b_fc2, nullptr, CDIM, HIDDEN);
    // 12. spatial gate: channel-split partials (8 px/thread) + finish
    gate_partial_kernel<<<dim3(HW / 2048, CSPLIT, BATCH), blk, 0, stream>>>(
        y2, w_sa, part_g);
    gate_finish_kernel<<<dim3(BATCH * HW / 1024), blk, 0, stream>>>(part_g, b_sa, gate);
    // 13. final: out = x2 + y2*gate (8 px/thread)
    final_kernel<<<dim3((int)(FULL / 2048)), blk, 0, stream>>>(x2, y2, gate, out);
}

// Round 10
// 297.188 us; speedup vs baseline: 1.0472x; 1.0472x over previous
//
#include <hip/hip_runtime.h>
#include <hip/hip_bf16.h>
#include <math.h>

using bf16 = __hip_bfloat16;

static constexpr int CDIM   = 192;
static constexpr int HEADS  = 6;
static constexpr int CP     = 32;     // CDIM / HEADS
static constexpr int HIDDEN = 384;
static constexpr int HImg   = 128;
static constexpr int WImg   = 128;
static constexpr int HW     = HImg * WImg;   // 16384
static constexpr int BATCH  = 4;
static constexpr int PCHUNK = 256;    // attn contraction chunk
static constexpr int CSPLIT = 12;     // gate conv channel splits (16 ch each)
static constexpr int DWCHUNK = 4;     // dw x-blocks per channel image (32 rows each)

typedef __attribute__((ext_vector_type(8))) short short8;
typedef __attribute__((ext_vector_type(4))) float f32x4;
typedef __attribute__((ext_vector_type(4))) unsigned short ushort4v;
typedef __attribute__((ext_vector_type(8))) unsigned short ushort8v;

template<typename T> __device__ inline float tof(T v);
template<> __device__ inline float tof<float>(float v){ return v; }
template<> __device__ inline float tof<bf16>(bf16 v){ return __bfloat162float(v); }

template<typename T> __device__ inline T fromf(float v);
template<> __device__ inline float fromf<float>(float v){ return v; }
template<> __device__ inline bf16  fromf<bf16>(float v){ return __float2bfloat16(v); }

__device__ inline unsigned short f2bf_bits(float f){
    bf16 h = __float2bfloat16(f);
    return *reinterpret_cast<unsigned short*>(&h);
}
__device__ inline float bfbits2f(unsigned short u){
    union { unsigned int i; float f; } c; c.i = ((unsigned int)u) << 16; return c.f;
}

__device__ inline float gelu_exact(float x){
    return 0.5f * x * (1.0f + erff(x * 0.70710678118654752440f));
}

// load 4 consecutive elems as float
__device__ inline void load4f(const float* p, float* f){
    f32x4 v = *reinterpret_cast<const f32x4*>(p);
    f[0]=v[0]; f[1]=v[1]; f[2]=v[2]; f[3]=v[3];
}
__device__ inline void load4f(const bf16* p, float* f){
    ushort4v v = *reinterpret_cast<const ushort4v*>(p);
    f[0]=bfbits2f(v[0]); f[1]=bfbits2f(v[1]); f[2]=bfbits2f(v[2]); f[3]=bfbits2f(v[3]);
}

// async global(16B) -> LDS
__device__ __forceinline__ void gload16(const bf16* g, bf16* l){
    __builtin_amdgcn_global_load_lds(
        (const __attribute__((address_space(1))) void*)g,
        (__attribute__((address_space(3))) void*)l, 16, 0, 0);
}

// ---------------- merged f32 -> bf16 weight convert --------------------------
__global__ __launch_bounds__(256) void convw_kernel(
    const float* __restrict__ w_qkv, const float* __restrict__ w_proj,
    const float* __restrict__ w_fc1, const float* __restrict__ w_fc2,
    bf16* __restrict__ wq, bf16* __restrict__ wp,
    bf16* __restrict__ wf1, bf16* __restrict__ wf2)
{
    int i = blockIdx.x * 256 + threadIdx.x;
    const int n0 = 576*192, n1 = n0 + 192*192, n2 = n1 + 384*192, n3 = n2 + 192*384;
    if (i < n0)      wq[i]       = fromf<bf16>(w_qkv[i]);
    else if (i < n1) wp[i - n0]  = fromf<bf16>(w_proj[i - n0]);
    else if (i < n2) wf1[i - n1] = fromf<bf16>(w_fc1[i - n1]);
    else if (i < n3) wf2[i - n2] = fromf<bf16>(w_fc2[i - n2]);
}

// ---------------- fused LayerNorm (+optional bf16 [C][HW] copy) + transpose --
template<typename T, bool WRES>
__global__ __launch_bounds__(256) void ln_fused_kernel(
    const T* __restrict__ in, const float* __restrict__ g,
    const float* __restrict__ b, bf16* __restrict__ resF, bf16* __restrict__ outT)
{
    int z = blockIdx.y, p0 = blockIdx.x * 64;
    __shared__ float tile[CDIM][65];
    __shared__ float sred[4][64], s2red[4][64];
    __shared__ float mrow[64], rrow[64];
    const T* ib = in + (size_t)z * CDIM * HW + p0;
    int tid = threadIdx.x;
    for (int j = tid; j < CDIM * 16; j += 256){
        int c = j >> 4, p4 = (j & 15) * 4;
        float f[4];
        load4f(ib + (size_t)c * HW + p4, f);
        tile[c][p4]   = f[0]; tile[c][p4+1] = f[1];
        tile[c][p4+2] = f[2]; tile[c][p4+3] = f[3];
    }
    __syncthreads();
    int p = tid & 63, q = tid >> 6;
    float s = 0.f, s2 = 0.f;
    #pragma unroll 4
    for (int c = q * 48; c < q * 48 + 48; ++c){
        float v = tile[c][p]; s += v; s2 += v * v;
    }
    sred[q][p] = s; s2red[q][p] = s2;
    __syncthreads();
    if (tid < 64){
        float ts = sred[0][tid] + sred[1][tid] + sred[2][tid] + sred[3][tid];
        float t2 = s2red[0][tid] + s2red[1][tid] + s2red[2][tid] + s2red[3][tid];
        float mean = ts * (1.0f / CDIM);
        float var  = t2 * (1.0f / CDIM) - mean * mean;
        mrow[tid] = mean;
        rrow[tid] = rsqrtf(var + 1e-5f);
    }
    __syncthreads();
    unsigned short* oT = (unsigned short*)(outT + ((size_t)z * HW + p0) * CDIM);
    for (int j = tid; j < 64 * 48; j += 256){
        int pr = j / 48, c4 = (j % 48) * 4;
        float m = mrow[pr], r = rrow[pr];
        ushort4v o;
        #pragma unroll
        for (int k = 0; k < 4; ++k){
            int c = c4 + k;
            o[k] = f2bf_bits((tile[c][pr] - m) * r * g[c] + b[c]);
        }
        *(ushort4v*)&oT[(size_t)pr * CDIM + c4] = o;
    }
    if (WRES){
        unsigned short* oF = (unsigned short*)resF + (size_t)z * CDIM * HW + p0;
        for (int j = tid; j < CDIM * 16; j += 256){
            int c = j >> 4, p4 = (j & 15) * 4;
            float gg = g[c], bb = b[c];
            ushort4v v;
            #pragma unroll
            for (int k = 0; k < 4; ++k)
                v[k] = f2bf_bits((tile[c][p4 + k] - mrow[p4 + k]) * rrow[p4 + k] * gg + bb);
            *(ushort4v*)&oF[(size_t)c * HW + p4] = v;
        }
    }
}

// ---------------- MFMA GEMM: C[M,N] = Wb[M,K] @ XT[N,K]^T, batched -----------
// Block tile 64m x 256n, 4 waves side-by-side in n (each 64m x 64n).
// Round-5 sync structure (single-buffered global_load_lds, vmcnt(0)+sync per
// K-tile) — only the tile width changed: 32 MFMA per barrier per wave (2x),
// A-staging amortized over 2x the output. LDS 40 KB -> exactly 4 blocks/CU.
// EPI: 0 = bf16 out [M][HW]; 1 = bf16 out + bf16 residual; 2 = bias+gelu bf16;
//      3 = bias+gelu -> transposed bf16 out [HW][M]
template<int EPI>
__global__ __launch_bounds__(256) void gemm_mfma_kernel(
    const bf16* __restrict__ Wb, const bf16* __restrict__ XT,
    void* __restrict__ Cout, const float* __restrict__ bias,
    const bf16* __restrict__ res, int M, int K)
{
    __shared__ bf16 smem[20480];              // 40 KB: A 64x64 (8KB) + B 256x64 (32KB)
    bf16* Als = smem;
    bf16* Bls = smem + 4096;
    int z  = blockIdx.z;
    int n0 = blockIdx.x * 256;
    int m0 = blockIdx.y * 64;
    const bf16* Xb = XT + (size_t)z * (size_t)HW * K;
    int tid  = threadIdx.x;
    int lane = tid & 63, wid = tid >> 6;
    int r16 = lane & 15, grp = lane >> 4;

    f32x4 acc[4][4];
    #pragma unroll
    for (int i = 0; i < 4; ++i)
        #pragma unroll
        for (int j = 0; j < 4; ++j){ f32x4 zz = {0.f,0.f,0.f,0.f}; acc[i][j] = zz; }

    int nkt = K >> 6;
    for (int kt = 0; kt < nkt; ++kt){
        #pragma unroll
        for (int i = 0; i < 2; ++i){          // A: 512 x 16B slots
            int s = i * 256 + tid;
            int row = s >> 3, ch = s & 7;
            gload16(Wb + (size_t)(m0 + row) * K + kt * 64 + ((ch ^ (row & 7)) * 8),
                    Als + s * 8);
        }
        #pragma unroll
        for (int i = 0; i < 8; ++i){          // B: 2048 x 16B slots
            int s = i * 256 + tid;
            int row = s >> 3, ch = s & 7;
            gload16(Xb + (size_t)(n0 + row) * K + kt * 64 + ((ch ^ (row & 7)) * 8),
                    Bls + s * 8);
        }
        asm volatile("s_waitcnt vmcnt(0)" ::: "memory");
        __syncthreads();
        #pragma unroll
        for (int ks = 0; ks < 2; ++ks){
            int kel = ks * 32 + grp * 8;
            short8 a[4], b[4];
            #pragma unroll
            for (int f = 0; f < 4; ++f){
                int arow = f * 16 + r16;
                a[f] = *reinterpret_cast<const short8*>(Als + arow * 64 + (kel ^ ((arow & 7) * 8)));
                int brow = wid * 64 + f * 16 + r16;
                b[f] = *reinterpret_cast<const short8*>(Bls + brow * 64 + (kel ^ ((brow & 7) * 8)));
            }
            #pragma unroll
            for (int fi = 0; fi < 4; ++fi)
                #pragma unroll
                for (int fj = 0; fj < 4; ++fj)
                    acc[fi][fj] = __builtin_amdgcn_mfma_f32_16x16x32_bf16(
                        a[fi], b[fj], acc[fi][fj], 0, 0, 0);
        }
        __syncthreads();
    }

    if (EPI == 3){
        // transposed bf16 out via LDS T[n(256)][m(64)] stride 72 (36.9 KB)
        unsigned short* T = (unsigned short*)smem;
        #pragma unroll
        for (int fi = 0; fi < 4; ++fi)
            #pragma unroll
            for (int fj = 0; fj < 4; ++fj){
                int nl = wid * 64 + fj * 16 + r16;
                int mb = fi * 16 + grp * 4;
                #pragma unroll
                for (int rr = 0; rr < 4; ++rr){
                    float v = gelu_exact(acc[fi][fj][rr] + bias[m0 + mb + rr]);
                    T[nl * 72 + mb + rr] = f2bf_bits(v);
                }
            }
        __syncthreads();
        bf16* Y = (bf16*)Cout;
        const short8* srcv = reinterpret_cast<const short8*>(T + tid * 72);
        short8* dstv = reinterpret_cast<short8*>(
            Y + ((size_t)z * HW + n0 + tid) * M + m0);
        #pragma unroll
        for (int i = 0; i < 8; ++i) dstv[i] = srcv[i];
        return;
    }

    // [M][HW] epilogues via LDS T[m(64)][n(256)] stride 264 (33.8 KB)
    {
        unsigned short* T = (unsigned short*)smem;
        #pragma unroll
        for (int fi = 0; fi < 4; ++fi)
            #pragma unroll
            for (int fj = 0; fj < 4; ++fj){
                int m = fi * 16 + grp * 4;
                int n = wid * 64 + fj * 16 + r16;
                #pragma unroll
                for (int rr = 0; rr < 4; ++rr)
                    T[(m + rr) * 264 + n] = f2bf_bits(acc[fi][fj][rr]);
            }
        __syncthreads();
        int row = tid >> 2, c8 = (tid & 3) * 8;
        bf16* Cb = (bf16*)Cout;
        size_t gbase = (size_t)z * M * HW + (size_t)(m0 + row) * HW + n0 + c8;
        float bv = (EPI == 2) ? bias[m0 + row] : 0.f;
        #pragma unroll
        for (int j = 0; j < 8; ++j){
            int coff = j * 32;
            ushort8v t8 = *(const ushort8v*)&T[row * 264 + c8 + coff];
            ushort8v o8;
            if (EPI == 0){
                o8 = t8;
            } else if (EPI == 1){
                ushort8v r8 = *(const ushort8v*)((const unsigned short*)res + gbase + coff);
                #pragma unroll
                for (int k = 0; k < 8; ++k)
                    o8[k] = f2bf_bits(bfbits2f(t8[k]) + bfbits2f(r8[k]));
            } else {
                #pragma unroll
                for (int k = 0; k < 8; ++k)
                    o8[k] = f2bf_bits(gelu_exact(bfbits2f(t8[k]) + bv));
            }
            *(ushort8v*)((unsigned short*)Cb + gbase + coff) = o8;
        }
    }
}

// ---------------- depthwise 3x3: 2 rows x 8 px per thread + q/k sumsq --------
// Each thread loads 4 rows (ushort8) to produce 2 output rows: 2x load reuse.
__global__ __launch_bounds__(256) void dw_kernel(
    const bf16* __restrict__ in, const float* __restrict__ wdw,
    bf16* __restrict__ out, float* __restrict__ sqp)
{
    int ch = blockIdx.y, z = blockIdx.z;
    int tid = threadIdx.x;
    int rp = tid >> 4;                          // 16 row-pairs per block
    int xx = (tid & 15) * 8;                    // 16 lanes per image row
    int y0 = blockIdx.x * 32 + rp * 2;          // first output row
    const unsigned short* p =
        (const unsigned short*)(in + ((size_t)z * 3 * CDIM + ch) * HW);
    float w[9];
    #pragma unroll
    for (int t = 0; t < 9; ++t) w[t] = wdw[ch * 9 + t];
    float f[4][8], lf[4], rf[4];
    #pragma unroll
    for (int r = 0; r < 4; ++r){
        int iy = y0 - 1 + r;
        if (iy >= 0 && iy < HImg){
            ushort8v v8 = *(const ushort8v*)(p + iy * WImg + xx);
            #pragma unroll
            for (int j = 0; j < 8; ++j) f[r][j] = bfbits2f(v8[j]);
        } else {
            #pragma unroll
            for (int j = 0; j < 8; ++j) f[r][j] = 0.f;
        }
        float l = __shfl_up(f[r][7], 1);
        float rr_ = __shfl_down(f[r][0], 1);
        lf[r] = (xx == 0) ? 0.f : l;
        rf[r] = (xx + 8 >= WImg) ? 0.f : rr_;
    }
    float sq = 0.f;
    unsigned short* ob = (unsigned short*)(out + ((size_t)z * 3 * CDIM + ch) * HW);
    #pragma unroll
    for (int orow = 0; orow < 2; ++orow){
        ushort8v o8;
        #pragma unroll
        for (int j = 0; j < 8; ++j){
            float a = 0.f;
            #pragma unroll
            for (int dy = 0; dy < 3; ++dy){
                int r = orow + dy;
                float e0 = (j == 0) ? lf[r] : f[r][j - 1];
                float e2 = (j == 7) ? rf[r] : f[r][j + 1];
                a = fmaf(w[dy*3], e0, fmaf(w[dy*3+1], f[r][j], fmaf(w[dy*3+2], e2, a)));
            }
            o8[j] = f2bf_bits(a);
            sq = fmaf(a, a, sq);
        }
        *(ushort8v*)(ob + (y0 + orow) * WImg + xx) = o8;
    }
    if (ch < 2 * CDIM){
        #pragma unroll
        for (int m = 1; m < 64; m <<= 1) sq += __shfl_xor(sq, m, 64);
        __shared__ float red[4];
        if ((tid & 63) == 0) red[tid >> 6] = sq;
        __syncthreads();
        if (tid == 0)
            sqp[((size_t)ch * BATCH + z) * DWCHUNK + blockIdx.x] =
                red[0] + red[1] + red[2] + red[3];
    }
}

// ---------------- attn partials (inline l2-inv from sqp) ---------------------
__global__ __launch_bounds__(256) void attn_qk_kernel(
    const bf16* __restrict__ qkv, const float* __restrict__ sqp,
    const float* __restrict__ temp, float* __restrict__ part)
{
    int chunk = blockIdx.x;
    int h = blockIdx.y, z = blockIdx.z;
    __shared__ unsigned short qs[CP][PCHUNK + 4];
    __shared__ unsigned short ks[CP][PCHUNK + 4];
    __shared__ float invqs[CP], invks[CP];
    int tid = threadIdx.x;
    if (tid < 2 * CP){
        int which = tid >> 5, cc = tid & 31;
        int ch = which * CDIM + h * CP + cc;
        const float* sp = &sqp[((size_t)ch * BATCH + z) * DWCHUNK];
        float s = sp[0] + sp[1] + sp[2] + sp[3];
        float inv = 1.0f / fmaxf(sqrtf(s), 1e-12f);
        (which ? invks : invqs)[cc] = inv;
    }
    int n0 = chunk * PCHUNK;
    const unsigned short* qb = (const unsigned short*)(qkv + ((size_t)z * 3 * CDIM + h * CP) * HW);
    const unsigned short* kb = (const unsigned short*)(qkv + ((size_t)z * 3 * CDIM + CDIM + h * CP) * HW);
    for (int i = tid; i < CP * (PCHUNK / 4); i += 256){
        int r = i >> 6, p4 = i & 63;
        *(ushort4v*)&qs[r][p4 * 4] = *(const ushort4v*)&qb[(size_t)r * HW + n0 + p4 * 4];
        *(ushort4v*)&ks[r][p4 * 4] = *(const ushort4v*)&kb[(size_t)r * HW + n0 + p4 * 4];
    }
    __syncthreads();
    int c  = tid >> 3;
    int d0 = (tid & 7) * 4;
    float acc[4] = {0.f, 0.f, 0.f, 0.f};
    for (int p4 = 0; p4 < PCHUNK / 4; ++p4){
        ushort4v qv = *(const ushort4v*)&qs[c][p4 * 4];
        float qf0 = bfbits2f(qv[0]), qf1 = bfbits2f(qv[1]);
        float qf2 = bfbits2f(qv[2]), qf3 = bfbits2f(qv[3]);
        #pragma unroll
        for (int j = 0; j < 4; ++j){
            ushort4v kv = *(const ushort4v*)&ks[d0 + j][p4 * 4];
            acc[j] = fmaf(qf0, bfbits2f(kv[0]),
                     fmaf(qf1, bfbits2f(kv[1]),
                     fmaf(qf2, bfbits2f(kv[2]),
                     fmaf(qf3, bfbits2f(kv[3]), acc[j]))));
        }
    }
    float sc = invqs[c] * temp[h];
    size_t base = ((size_t)chunk * BATCH * HEADS + (size_t)z * HEADS + h) * CP * CP
                + c * CP + d0;
    #pragma unroll
    for (int j = 0; j < 4; ++j)
        part[base + j] = acc[j] * sc * invks[d0 + j];
}

__global__ __launch_bounds__(256) void attn_reduce_kernel(
    const float* __restrict__ part, float* __restrict__ attn)
{
    int idx = blockIdx.x * 256 + threadIdx.x;
    float s = 0.f;
    for (int ch = 0; ch < HW / PCHUNK; ++ch)
        s += part[(size_t)ch * (BATCH * HEADS * CP * CP) + idx];
    attn[idx] = s;
}

// ---------------- head conv 3x3 + softmax (merged) ---------------------------
__global__ __launch_bounds__(256) void headconv_softmax_kernel(
    const float* __restrict__ attn, const float* __restrict__ wh,
    float* __restrict__ attn2)
{
    int oh = blockIdx.x, z = blockIdx.y;
    __shared__ float wsm[HEADS * 9];
    __shared__ float ain[HEADS][CP * CP];
    __shared__ float aout[CP * CP];
    int tid = threadIdx.x;
    if (tid < HEADS * 9) wsm[tid] = wh[oh * HEADS * 9 + tid];
    for (int i = tid; i < HEADS * CP * CP; i += 256)
        ain[i >> 10][i & 1023] = attn[((size_t)z * HEADS + (i >> 10)) * CP * CP + (i & 1023)];
    __syncthreads();
    for (int idx = tid; idx < CP * CP; idx += 256){
        int i = idx >> 5, j = idx & 31;
        float acc = 0.f;
        #pragma unroll
        for (int ih = 0; ih < HEADS; ++ih){
            #pragma unroll
            for (int dy = 0; dy < 3; ++dy){
                int ii = i + dy - 1;
                if (ii < 0 || ii >= CP) continue;
                #pragma unroll
                for (int dx = 0; dx < 3; ++dx){
                    int jj = j + dx - 1;
                    if (jj < 0 || jj >= CP) continue;
                    acc += wsm[ih * 9 + dy * 3 + dx] * ain[ih][ii * CP + jj];
                }
            }
        }
        aout[idx] = acc;
    }
    __syncthreads();
    int r = tid >> 3, l8 = tid & 7;
    float v[4];
    #pragma unroll
    for (int k = 0; k < 4; ++k) v[k] = aout[r * CP + l8 * 4 + k];
    float mx = fmaxf(fmaxf(v[0], v[1]), fmaxf(v[2], v[3]));
    #pragma unroll
    for (int m = 1; m < 8; m <<= 1) mx = fmaxf(mx, __shfl_xor(mx, m, 64));
    float sum = 0.f;
    #pragma unroll
    for (int k = 0; k < 4; ++k){ v[k] = expf(v[k] - mx); sum += v[k]; }
    #pragma unroll
    for (int m = 1; m < 8; m <<= 1) sum += __shfl_xor(sum, m, 64);
    float rs = 1.0f / sum;
    float* o = attn2 + ((size_t)z * HEADS + oh) * CP * CP + r * CP + l8 * 4;
    #pragma unroll
    for (int k = 0; k < 4; ++k) o[k] = v[k] * rs;
}

// ---------------- out = attn2 @ v -> transposed bf16 [HW][C] -----------------
__global__ __launch_bounds__(256) void av_kernel(
    const float* __restrict__ attn2, const bf16* __restrict__ qkv, bf16* __restrict__ outT)
{
    int h = blockIdx.y, z = blockIdx.z;
    int tid = threadIdx.x;
    __shared__ float As[CP][CP];
    __shared__ unsigned short Vs[CP][PCHUNK];
    __shared__ unsigned short ot[256][36];
    for (int i = tid; i < CP * CP; i += 256)
        As[i >> 5][i & 31] = attn2[((size_t)(z * HEADS + h)) * CP * CP + i];
    int n0 = blockIdx.x * 256;
    const unsigned short* vb =
        (const unsigned short*)(qkv + ((size_t)z * 3 * CDIM + 2 * CDIM + h * CP) * HW) + n0;
    for (int i = tid; i < CP * 64; i += 256){
        int d = i >> 6, p4 = (i & 63) * 4;
        *(ushort4v*)&Vs[d][p4] = *(const ushort4v*)(vb + (size_t)d * HW + p4);
    }
    __syncthreads();
    float vreg[CP];
    #pragma unroll
    for (int d = 0; d < CP; ++d) vreg[d] = bfbits2f(Vs[d][tid]);
    for (int c = 0; c < CP; ++c){
        float acc = 0.f;
        #pragma unroll
        for (int d = 0; d < CP; ++d) acc = fmaf(As[c][d], vreg[d], acc);
        ot[tid][c] = f2bf_bits(acc);
    }
    __syncthreads();
    unsigned short* ob = (unsigned short*)outT
        + ((size_t)z * HW + (size_t)n0) * CDIM + h * CP;
    for (int j = tid; j < 256 * 8; j += 256){
        int row = j >> 3, q4 = (j & 7) * 4;
        *(ushort4v*)&ob[(size_t)row * CDIM + q4] = *(ushort4v*)&ot[row][q4];
    }
}

// ---------------- spatial gate partials (16 ch/block, 8 px/thread, bf16 in) --
__global__ __launch_bounds__(256) void gate_partial_kernel(
    const bf16* __restrict__ y, const float* __restrict__ wsa,
    float* __restrict__ part_g)
{
    int cs = blockIdx.y, z = blockIdx.z;
    __shared__ float wsm[16 * 9];
    if (threadIdx.x < 144) wsm[threadIdx.x] = wsa[cs * 144 + threadIdx.x];
    __syncthreads();
    int idx = blockIdx.x * 2048 + threadIdx.x * 8;
    int yy = idx >> 7, xx = idx & 127;
    const unsigned short* yb =
        (const unsigned short*)(y + (size_t)z * CDIM * HW + (size_t)cs * 16 * HW);
    float acc[8] = {0.f,0.f,0.f,0.f,0.f,0.f,0.f,0.f};
    for (int c = 0; c < 16; ++c){
        const unsigned short* pc = yb + (size_t)c * HW;
        #pragma unroll
        for (int dy = 0; dy < 3; ++dy){
            int iy = yy + dy - 1;
            float f[8], lf, rf;
            if (iy >= 0 && iy < HImg){
                ushort8v v8 = *(const ushort8v*)(pc + iy * WImg + xx);
                #pragma unroll
                for (int j = 0; j < 8; ++j) f[j] = bfbits2f(v8[j]);
            } else {
                #pragma unroll
                for (int j = 0; j < 8; ++j) f[j] = 0.f;
            }
            float l = __shfl_up(f[7], 1);
            float r = __shfl_down(f[0], 1);
            lf = (xx == 0) ? 0.f : l;
            rf = (xx + 8 >= WImg) ? 0.f : r;
            const float* wr = &wsm[c * 9 + dy * 3];
            #pragma unroll
            for (int j = 0; j < 8; ++j){
                float e0 = (j == 0) ? lf : f[j - 1];
                float e2 = (j == 7) ? rf : f[j + 1];
                acc[j] = fmaf(wr[0], e0, fmaf(wr[1], f[j], fmaf(wr[2], e2, acc[j])));
            }
        }
    }
    float* og = &part_g[((size_t)cs * BATCH + z) * HW + idx];
    f32x4 o0 = {acc[0], acc[1], acc[2], acc[3]};
    f32x4 o1 = {acc[4], acc[5], acc[6], acc[7]};
    *(f32x4*)og = o0;
    *(f32x4*)(og + 4) = o1;
}

__global__ __launch_bounds__(256) void gate_finish_kernel(
    const float* __restrict__ part_g, const float* __restrict__ bsa,
    float* __restrict__ gate)
{
    int i4 = (blockIdx.x * 256 + threadIdx.x) * 4;   // < BATCH*HW
    float b0 = bsa[0];
    f32x4 acc = {b0, b0, b0, b0};
    #pragma unroll
    for (int cs = 0; cs < CSPLIT; ++cs){
        f32x4 v = *(const f32x4*)&part_g[(size_t)cs * BATCH * HW + i4];
        #pragma unroll
        for (int j = 0; j < 4; ++j) acc[j] += v[j];
    }
    f32x4 o;
    #pragma unroll
    for (int j = 0; j < 4; ++j) o[j] = 1.0f / (1.0f + expf(-acc[j]));
    *(f32x4*)&gate[i4] = o;
}

// ---------------- final: out = x2 + y2 * gate (8 px/thread, bf16 ins) --------
__global__ __launch_bounds__(256) void final_kernel(
    const bf16* __restrict__ x2, const bf16* __restrict__ y2,
    const float* __restrict__ gate, float* __restrict__ out)
{
    size_t i8 = ((size_t)blockIdx.x * 256 + threadIdx.x) * 8;
    int n = (int)(i8 % HW);
    int z = (int)(i8 / ((size_t)CDIM * HW));
    ushort8v a8 = *(const ushort8v*)((const unsigned short*)x2 + i8);
    ushort8v b8 = *(const ushort8v*)((const unsigned short*)y2 + i8);
    const float* gp = gate + (size_t)z * HW + n;
    f32x4 g0 = *(const f32x4*)gp;
    f32x4 g1 = *(const f32x4*)(gp + 4);
    f32x4 o0, o1;
    #pragma unroll
    for (int j = 0; j < 4; ++j){
        o0[j] = bfbits2f(a8[j])     + bfbits2f(b8[j])     * g0[j];
        o1[j] = bfbits2f(a8[j + 4]) + bfbits2f(b8[j + 4]) * g1[j];
    }
    *(f32x4*)(out + i8) = o0;
    *(f32x4*)(out + i8 + 4) = o1;
}

extern "C" void kernel_launch(void* const* d_in, const int* in_sizes, int n_in,
                              void* d_out, int out_size, void* d_ws, size_t ws_size,
                              hipStream_t stream)
{
    const float* x      = (const float*)d_in[0];
    const float* g1     = (const float*)d_in[1];
    const float* b1     = (const float*)d_in[2];
    const float* w_qkv  = (const float*)d_in[3];
    const float* w_dw   = (const float*)d_in[4];
    const float* temp   = (const float*)d_in[5];
    const float* w_head = (const float*)d_in[6];
    const float* w_proj = (const float*)d_in[7];
    const float* g2     = (const float*)d_in[8];
    const float* b2     = (const float*)d_in[9];
    const float* w_fc1  = (const float*)d_in[10];
    const float* b_fc1  = (const float*)d_in[11];
    const float* w_fc2  = (const float*)d_in[12];
    const float* b_fc2  = (const float*)d_in[13];
    const float* w_sa   = (const float*)d_in[14];
    const float* b_sa   = (const float*)d_in[15];
    float* out = (float*)d_out;

    char* ws = (char*)d_ws;
    const size_t FULL = (size_t)BATCH * CDIM * HW;      // 12.58M elems

    // R0 (FULL*2 B): x1 bf16 [C][HW] -> y2 bf16 [C][HW]
    bf16* x1 = (bf16*)ws;
    bf16* y2 = x1;
    // R1 (3*FULL*2 B): qkvA bf16 -> attn_outT bf16 / ln2T bf16 / y1T bf16
    char* R1 = ws + FULL * 2;
    bf16*  qkvA      = (bf16*)R1;
    bf16*  attn_outT = (bf16*)R1;
    bf16*  ln2T      = (bf16*)R1;
    bf16*  y1T       = (bf16*)(R1 + FULL * 2);
    // R2 (3*FULL*2 B): x1T bf16 -> dwB bf16 -> x2 bf16
    char* R2 = R1 + FULL * 3 * 2;
    bf16*  x1T = (bf16*)R2;
    bf16*  dwB = (bf16*)R2;
    bf16*  x2  = (bf16*)R2;
    // small region
    char* SM = R2 + FULL * 3 * 2;
    float* attn   = (float*)SM;                             // B*HEADS*CP*CP
    float* attn2  = attn + BATCH * HEADS * CP * CP;
    float* gate   = attn2 + BATCH * HEADS * CP * CP;        // B*HW
    float* sqp    = gate + BATCH * HW;                      // 2*CDIM*B*DWCHUNK
    float* part   = sqp + 2 * CDIM * BATCH * DWCHUNK;       // 64*B*H*CP*CP (6.3MB)
    float* part_g = part;                                   // aliases part (dead)
    bf16* wq_b  = (bf16*)(part + (HW / PCHUNK) * BATCH * HEADS * CP * CP);
    bf16* wp_b  = wq_b  + 576 * 192;
    bf16* wf1_b = wp_b  + 192 * 192;
    bf16* wf2_b = wf1_b + 384 * 192;

    dim3 blk(256);

    // 0. merged weight conversion to bf16
    convw_kernel<<<dim3((294912 + 255) / 256), blk, 0, stream>>>(
        w_qkv, w_proj, w_fc1, w_fc2, wq_b, wp_b, wf1_b, wf2_b);
    // 1. LayerNorm1 fused: x -> x1 (bf16 [C][HW] residual) + x1T (bf16 [HW][C])
    ln_fused_kernel<float, true><<<dim3(HW / 64, BATCH), blk, 0, stream>>>(
        x, g1, b1, x1, x1T);
    // 2. qkv GEMM -> bf16 [3C][HW]
    gemm_mfma_kernel<0><<<dim3(HW / 256, (3 * CDIM) / 64, BATCH), blk, 0, stream>>>(
        wq_b, x1T, qkvA, nullptr, nullptr, 3 * CDIM, CDIM);
    // 3. depthwise 3x3 (2 rows x 8 px per thread) + q/k sumsq partials
    dw_kernel<<<dim3(DWCHUNK, 3 * CDIM, BATCH), blk, 0, stream>>>(qkvA, w_dw, dwB, sqp);
    // 4. attn partial dot-products (inline l2-inv)
    attn_qk_kernel<<<dim3(HW / PCHUNK, HEADS, BATCH), blk, 0, stream>>>(
        dwB, sqp, temp, part);
    // 5. deterministic reduction of partials
    attn_reduce_kernel<<<dim3((BATCH * HEADS * CP * CP) / 256), blk, 0, stream>>>(part, attn);
    // 6. head conv + softmax (merged)
    headconv_softmax_kernel<<<dim3(HEADS, BATCH), blk, 0, stream>>>(attn, w_head, attn2);
    // 7. out = attn @ v -> bf16 [HW][C] (pre-transposed for proj)
    av_kernel<<<dim3(HW / 256, HEADS, BATCH), blk, 0, stream>>>(attn2, dwB, attn_outT);
    // 8. proj GEMM + residual(x1 bf16) -> x2 bf16 [C][HW]
    gemm_mfma_kernel<1><<<dim3(HW / 256, CDIM / 64, BATCH), blk, 0, stream>>>(
        wp_b, attn_outT, x2, nullptr, x1, CDIM, CDIM);
    // 9. LayerNorm2 fused (bf16 in) -> ln2T bf16 [HW][C]
    ln_fused_kernel<bf16, false><<<dim3(HW / 64, BATCH), blk, 0, stream>>>(
        x2, g2, b2, nullptr, ln2T);
    // 10. fc1 GEMM + bias + gelu -> y1T bf16 [HW][HIDDEN]
    gemm_mfma_kernel<3><<<dim3(HW / 256, HIDDEN / 64, BATCH), blk, 0, stream>>>(
        wf1_b, ln2T, y1T, b_fc1, nullptr, HIDDEN, CDIM);
    // 11. fc2 GEMM + bias + gelu -> y2 bf16 [C][HW]
    gemm_mfma_kernel<2><<<dim3(HW / 256, CDIM / 64, BATCH), blk, 0, stream>>>(
        wf2_b, y1T, y2, b_fc2, nullptr, CDIM, HIDDEN);
    // 12. spatial gate: channel-split partials (8 px/thread) + finish
    gate_partial_kernel<<<dim3(HW / 2048, CSPLIT, BATCH), blk, 0, stream>>>(
        y2, w_sa, part_g);
    gate_finish_kernel<<<dim3(BATCH * HW / 1024), blk, 0, stream>>>(part_g, b_sa, gate);
    // 13. final: out = x2 + y2*gate (8 px/thread)
    final_kernel<<<dim3((int)(FULL / 2048)), blk, 0, stream>>>(x2, y2, gate, out);
}

// Round 11
// 289.515 us; speedup vs baseline: 1.0750x; 1.0265x over previous
//
#include <hip/hip_runtime.h>
#include <hip/hip_bf16.h>
#include <math.h>

using bf16 = __hip_bfloat16;

static constexpr int CDIM   = 192;
static constexpr int HEADS  = 6;
static constexpr int CP     = 32;     // CDIM / HEADS
static constexpr int HIDDEN = 384;
static constexpr int HImg   = 128;
static constexpr int WImg   = 128;
static constexpr int HW     = HImg * WImg;   // 16384
static constexpr int BATCH  = 4;
static constexpr int PCHUNK = 256;    // attn contraction chunk
static constexpr int CSPLIT = 12;     // gate conv channel splits (16 ch each)
static constexpr int DWCHUNK = 4;     // dw y-blocks per channel image (32 rows each)

typedef __attribute__((ext_vector_type(8))) short short8;
typedef __attribute__((ext_vector_type(4))) float f32x4;
typedef __attribute__((ext_vector_type(4))) unsigned short ushort4v;
typedef __attribute__((ext_vector_type(8))) unsigned short ushort8v;

template<typename T> __device__ inline float tof(T v);
template<> __device__ inline float tof<float>(float v){ return v; }
template<> __device__ inline float tof<bf16>(bf16 v){ return __bfloat162float(v); }

template<typename T> __device__ inline T fromf(float v);
template<> __device__ inline float fromf<float>(float v){ return v; }
template<> __device__ inline bf16  fromf<bf16>(float v){ return __float2bfloat16(v); }

__device__ inline unsigned short f2bf_bits(float f){
    bf16 h = __float2bfloat16(f);
    return *reinterpret_cast<unsigned short*>(&h);
}
__device__ inline float bfbits2f(unsigned short u){
    union { unsigned int i; float f; } c; c.i = ((unsigned int)u) << 16; return c.f;
}

__device__ inline float gelu_exact(float x){
    return 0.5f * x * (1.0f + erff(x * 0.70710678118654752440f));
}

// load 4 consecutive elems as float
__device__ inline void load4f(const float* p, float* f){
    f32x4 v = *reinterpret_cast<const f32x4*>(p);
    f[0]=v[0]; f[1]=v[1]; f[2]=v[2]; f[3]=v[3];
}
__device__ inline void load4f(const bf16* p, float* f){
    ushort4v v = *reinterpret_cast<const ushort4v*>(p);
    f[0]=bfbits2f(v[0]); f[1]=bfbits2f(v[1]); f[2]=bfbits2f(v[2]); f[3]=bfbits2f(v[3]);
}

// async global(16B) -> LDS
__device__ __forceinline__ void gload16(const bf16* g, bf16* l){
    __builtin_amdgcn_global_load_lds(
        (const __attribute__((address_space(1))) void*)g,
        (__attribute__((address_space(3))) void*)l, 16, 0, 0);
}

// ---------------- merged f32 -> bf16 weight convert --------------------------
__global__ __launch_bounds__(256) void convw_kernel(
    const float* __restrict__ w_qkv, const float* __restrict__ w_proj,
    const float* __restrict__ w_fc1, const float* __restrict__ w_fc2,
    bf16* __restrict__ wq, bf16* __restrict__ wp,
    bf16* __restrict__ wf1, bf16* __restrict__ wf2)
{
    int i = blockIdx.x * 256 + threadIdx.x;
    const int n0 = 576*192, n1 = n0 + 192*192, n2 = n1 + 384*192, n3 = n2 + 192*384;
    if (i < n0)      wq[i]       = fromf<bf16>(w_qkv[i]);
    else if (i < n1) wp[i - n0]  = fromf<bf16>(w_proj[i - n0]);
    else if (i < n2) wf1[i - n1] = fromf<bf16>(w_fc1[i - n1]);
    else if (i < n3) wf2[i - n2] = fromf<bf16>(w_fc2[i - n2]);
}

// ---------------- fused LayerNorm (+optional bf16 [C][HW] copy) + transpose --
template<typename T, bool WRES>
__global__ __launch_bounds__(256) void ln_fused_kernel(
    const T* __restrict__ in, const float* __restrict__ g,
    const float* __restrict__ b, bf16* __restrict__ resF, bf16* __restrict__ outT)
{
    int z = blockIdx.y, p0 = blockIdx.x * 64;
    __shared__ float tile[CDIM][65];
    __shared__ float sred[4][64], s2red[4][64];
    __shared__ float mrow[64], rrow[64];
    const T* ib = in + (size_t)z * CDIM * HW + p0;
    int tid = threadIdx.x;
    for (int j = tid; j < CDIM * 16; j += 256){
        int c = j >> 4, p4 = (j & 15) * 4;
        float f[4];
        load4f(ib + (size_t)c * HW + p4, f);
        tile[c][p4]   = f[0]; tile[c][p4+1] = f[1];
        tile[c][p4+2] = f[2]; tile[c][p4+3] = f[3];
    }
    __syncthreads();
    int p = tid & 63, q = tid >> 6;
    float s = 0.f, s2 = 0.f;
    #pragma unroll 4
    for (int c = q * 48; c < q * 48 + 48; ++c){
        float v = tile[c][p]; s += v; s2 += v * v;
    }
    sred[q][p] = s; s2red[q][p] = s2;
    __syncthreads();
    if (tid < 64){
        float ts = sred[0][tid] + sred[1][tid] + sred[2][tid] + sred[3][tid];
        float t2 = s2red[0][tid] + s2red[1][tid] + s2red[2][tid] + s2red[3][tid];
        float mean = ts * (1.0f / CDIM);
        float var  = t2 * (1.0f / CDIM) - mean * mean;
        mrow[tid] = mean;
        rrow[tid] = rsqrtf(var + 1e-5f);
    }
    __syncthreads();
    unsigned short* oT = (unsigned short*)(outT + ((size_t)z * HW + p0) * CDIM);
    for (int j = tid; j < 64 * 48; j += 256){
        int pr = j / 48, c4 = (j % 48) * 4;
        float m = mrow[pr], r = rrow[pr];
        ushort4v o;
        #pragma unroll
        for (int k = 0; k < 4; ++k){
            int c = c4 + k;
            o[k] = f2bf_bits((tile[c][pr] - m) * r * g[c] + b[c]);
        }
        *(ushort4v*)&oT[(size_t)pr * CDIM + c4] = o;
    }
    if (WRES){
        unsigned short* oF = (unsigned short*)resF + (size_t)z * CDIM * HW + p0;
        for (int j = tid; j < CDIM * 16; j += 256){
            int c = j >> 4, p4 = (j & 15) * 4;
            float gg = g[c], bb = b[c];
            ushort4v v;
            #pragma unroll
            for (int k = 0; k < 4; ++k)
                v[k] = f2bf_bits((tile[c][p4 + k] - mrow[p4 + k]) * rrow[p4 + k] * gg + bb);
            *(ushort4v*)&oF[(size_t)c * HW + p4] = v;
        }
    }
}

// ---------------- MFMA GEMM: C[M,N] = Wb[M,K] @ XT[N,K]^T, batched -----------
// Round-8 geometry (64m x 128n, 2x2 waves of 32m x 64n — proven fastest) with
// a counted-vmcnt double-buffer K-loop: STAGE(t+1) issues before computing t;
// s_waitcnt vmcnt(6) keeps 6 prefetch loads in flight across the barrier
// (T3/T4 minimum). LDS dbuf 48 KB -> still 3 blocks/CU (same waves as r8).
// EPI: 0 = bf16 out [M][HW]; 1 = bf16 out + bf16 residual; 2 = bias+gelu bf16;
//      3 = bias+gelu -> transposed bf16 out [HW][M]
template<int EPI>
__global__ __launch_bounds__(256) void gemm_mfma_kernel(
    const bf16* __restrict__ Wb, const bf16* __restrict__ XT,
    void* __restrict__ Cout, const float* __restrict__ bias,
    const bf16* __restrict__ res, int M, int K)
{
    __shared__ bf16 smem[24576];              // 48 KB: 2 x (A 64x64 + B 128x64)
    int z  = blockIdx.z;
    int n0 = blockIdx.x * 128;
    int m0 = blockIdx.y * 64;
    const bf16* Xb = XT + (size_t)z * (size_t)HW * K;
    int tid  = threadIdx.x;
    int lane = tid & 63, wid = tid >> 6;
    int wm = wid & 1, wn = wid >> 1;          // 2x2 waves, each 32m x 64n
    int r16 = lane & 15, grp = lane >> 4;

    f32x4 acc[2][4];
    #pragma unroll
    for (int i = 0; i < 2; ++i)
        #pragma unroll
        for (int j = 0; j < 4; ++j){ f32x4 zz = {0.f,0.f,0.f,0.f}; acc[i][j] = zz; }

    auto STAGE = [&](int kt, int buf){
        bf16* Al = smem + buf * 12288;
        bf16* Bl = Al + 4096;
        #pragma unroll
        for (int i = 0; i < 2; ++i){          // A: 512 x 16B slots
            int s = i * 256 + tid;
            int row = s >> 3, ch = s & 7;
            gload16(Wb + (size_t)(m0 + row) * K + kt * 64 + ((ch ^ (row & 7)) * 8),
                    Al + s * 8);
        }
        #pragma unroll
        for (int i = 0; i < 4; ++i){          // B: 1024 x 16B slots
            int s = i * 256 + tid;
            int row = s >> 3, ch = s & 7;
            gload16(Xb + (size_t)(n0 + row) * K + kt * 64 + ((ch ^ (row & 7)) * 8),
                    Bl + s * 8);
        }
    };

    int nkt = K >> 6;
    STAGE(0, 0);
    int cur = 0;
    for (int kt = 0; kt < nkt; ++kt){
        if (kt + 1 < nkt){
            STAGE(kt + 1, cur ^ 1);
            asm volatile("s_waitcnt vmcnt(6)" ::: "memory");  // kt's 6 loads done; 6 stay in flight
        } else {
            asm volatile("s_waitcnt vmcnt(0)" ::: "memory");
        }
        __builtin_amdgcn_s_barrier();
        bf16* Al = smem + cur * 12288;
        bf16* Bl = Al + 4096;
        #pragma unroll
        for (int ks = 0; ks < 2; ++ks){
            int kel = ks * 32 + grp * 8;
            short8 a[2], b[4];
            #pragma unroll
            for (int fi = 0; fi < 2; ++fi){
                int row = wm * 32 + fi * 16 + r16;
                a[fi] = *reinterpret_cast<const short8*>(Al + row * 64 + (kel ^ ((row & 7) * 8)));
            }
            #pragma unroll
            for (int fj = 0; fj < 4; ++fj){
                int row = wn * 64 + fj * 16 + r16;
                b[fj] = *reinterpret_cast<const short8*>(Bl + row * 64 + (kel ^ ((row & 7) * 8)));
            }
            #pragma unroll
            for (int fi = 0; fi < 2; ++fi)
                #pragma unroll
                for (int fj = 0; fj < 4; ++fj)
                    acc[fi][fj] = __builtin_amdgcn_mfma_f32_16x16x32_bf16(
                        a[fi], b[fj], acc[fi][fj], 0, 0, 0);
        }
        // all my ds_reads of buf `cur` done before any wave re-stages over it
        asm volatile("s_waitcnt lgkmcnt(0)" ::: "memory");
        __builtin_amdgcn_sched_barrier(0);
        __builtin_amdgcn_s_barrier();
        cur ^= 1;
    }

    if (EPI == 3){
        // transposed bf16 out via LDS T[n(128)][m(64)] stride 72
        unsigned short* T = (unsigned short*)smem;
        #pragma unroll
        for (int fi = 0; fi < 2; ++fi)
            #pragma unroll
            for (int fj = 0; fj < 4; ++fj){
                int nl = wn * 64 + fj * 16 + r16;
                int mb = wm * 32 + fi * 16 + grp * 4;
                #pragma unroll
                for (int rr = 0; rr < 4; ++rr){
                    float v = gelu_exact(acc[fi][fj][rr] + bias[m0 + mb + rr]);
                    T[nl * 72 + mb + rr] = f2bf_bits(v);
                }
            }
        __syncthreads();
        bf16* Y = (bf16*)Cout;
        int rrow = tid >> 1, half = tid & 1;
        const short8* srcv = reinterpret_cast<const short8*>(T + rrow * 72 + half * 32);
        short8* dstv = reinterpret_cast<short8*>(
            Y + ((size_t)z * HW + n0 + rrow) * M + m0 + half * 32);
        #pragma unroll
        for (int i = 0; i < 4; ++i) dstv[i] = srcv[i];
        return;
    }

    // [M][HW] epilogues via LDS T[m(64)][n(128)] stride 136, 16B stores
    {
        unsigned short* T = (unsigned short*)smem;
        #pragma unroll
        for (int fi = 0; fi < 2; ++fi)
            #pragma unroll
            for (int fj = 0; fj < 4; ++fj){
                int m = wm * 32 + fi * 16 + grp * 4;
                int n = wn * 64 + fj * 16 + r16;
                #pragma unroll
                for (int rr = 0; rr < 4; ++rr)
                    T[(m + rr) * 136 + n] = f2bf_bits(acc[fi][fj][rr]);
            }
        __syncthreads();
        int row = tid >> 2, c8 = (tid & 3) * 8;      // 64 rows x 4 chunk-slots
        bf16* Cb = (bf16*)Cout;
        size_t gbase = (size_t)z * M * HW + (size_t)(m0 + row) * HW + n0 + c8;
        float bv = (EPI == 2) ? bias[m0 + row] : 0.f;
        #pragma unroll
        for (int j = 0; j < 4; ++j){
            int coff = j * 32;
            ushort8v t8 = *(const ushort8v*)&T[row * 136 + c8 + coff];
            ushort8v o8;
            if (EPI == 0){
                o8 = t8;
            } else if (EPI == 1){
                ushort8v r8 = *(const ushort8v*)((const unsigned short*)res + gbase + coff);
                #pragma unroll
                for (int k = 0; k < 8; ++k)
                    o8[k] = f2bf_bits(bfbits2f(t8[k]) + bfbits2f(r8[k]));
            } else {
                #pragma unroll
                for (int k = 0; k < 8; ++k)
                    o8[k] = f2bf_bits(gelu_exact(bfbits2f(t8[k]) + bv));
            }
            *(ushort8v*)((unsigned short*)Cb + gbase + coff) = o8;
        }
    }
}

// ---------------- depthwise 3x3: 2 rows x 8 px per thread + q/k sumsq --------
__global__ __launch_bounds__(256) void dw_kernel(
    const bf16* __restrict__ in, const float* __restrict__ wdw,
    bf16* __restrict__ out, float* __restrict__ sqp)
{
    int ch = blockIdx.y, z = blockIdx.z;
    int tid = threadIdx.x;
    int rp = tid >> 4;                          // 16 row-pairs per block
    int xx = (tid & 15) * 8;                    // 16 lanes per image row
    int y0 = blockIdx.x * 32 + rp * 2;          // first output row
    const unsigned short* p =
        (const unsigned short*)(in + ((size_t)z * 3 * CDIM + ch) * HW);
    float w[9];
    #pragma unroll
    for (int t = 0; t < 9; ++t) w[t] = wdw[ch * 9 + t];
    float f[4][8], lf[4], rf[4];
    #pragma unroll
    for (int r = 0; r < 4; ++r){
        int iy = y0 - 1 + r;
        if (iy >= 0 && iy < HImg){
            ushort8v v8 = *(const ushort8v*)(p + iy * WImg + xx);
            #pragma unroll
            for (int j = 0; j < 8; ++j) f[r][j] = bfbits2f(v8[j]);
        } else {
            #pragma unroll
            for (int j = 0; j < 8; ++j) f[r][j] = 0.f;
        }
        float l = __shfl_up(f[r][7], 1);
        float rr_ = __shfl_down(f[r][0], 1);
        lf[r] = (xx == 0) ? 0.f : l;
        rf[r] = (xx + 8 >= WImg) ? 0.f : rr_;
    }
    float sq = 0.f;
    unsigned short* ob = (unsigned short*)(out + ((size_t)z * 3 * CDIM + ch) * HW);
    #pragma unroll
    for (int orow = 0; orow < 2; ++orow){
        ushort8v o8;
        #pragma unroll
        for (int j = 0; j < 8; ++j){
            float a = 0.f;
            #pragma unroll
            for (int dy = 0; dy < 3; ++dy){
                int r = orow + dy;
                float e0 = (j == 0) ? lf[r] : f[r][j - 1];
                float e2 = (j == 7) ? rf[r] : f[r][j + 1];
                a = fmaf(w[dy*3], e0, fmaf(w[dy*3+1], f[r][j], fmaf(w[dy*3+2], e2, a)));
            }
            o8[j] = f2bf_bits(a);
            sq = fmaf(a, a, sq);
        }
        *(ushort8v*)(ob + (y0 + orow) * WImg + xx) = o8;
    }
    if (ch < 2 * CDIM){
        #pragma unroll
        for (int m = 1; m < 64; m <<= 1) sq += __shfl_xor(sq, m, 64);
        __shared__ float red[4];
        if ((tid & 63) == 0) red[tid >> 6] = sq;
        __syncthreads();
        if (tid == 0)
            sqp[((size_t)ch * BATCH + z) * DWCHUNK + blockIdx.x] =
                red[0] + red[1] + red[2] + red[3];
    }
}

// ---------------- attn partials (inline l2-inv from sqp) ---------------------
__global__ __launch_bounds__(256) void attn_qk_kernel(
    const bf16* __restrict__ qkv, const float* __restrict__ sqp,
    const float* __restrict__ temp, float* __restrict__ part)
{
    int chunk = blockIdx.x;
    int h = blockIdx.y, z = blockIdx.z;
    __shared__ unsigned short qs[CP][PCHUNK + 4];
    __shared__ unsigned short ks[CP][PCHUNK + 4];
    __shared__ float invqs[CP], invks[CP];
    int tid = threadIdx.x;
    if (tid < 2 * CP){
        int which = tid >> 5, cc = tid & 31;
        int ch = which * CDIM + h * CP + cc;
        const float* sp = &sqp[((size_t)ch * BATCH + z) * DWCHUNK];
        float s = sp[0] + sp[1] + sp[2] + sp[3];
        float inv = 1.0f / fmaxf(sqrtf(s), 1e-12f);
        (which ? invks : invqs)[cc] = inv;
    }
    int n0 = chunk * PCHUNK;
    const unsigned short* qb = (const unsigned short*)(qkv + ((size_t)z * 3 * CDIM + h * CP) * HW);
    const unsigned short* kb = (const unsigned short*)(qkv + ((size_t)z * 3 * CDIM + CDIM + h * CP) * HW);
    for (int i = tid; i < CP * (PCHUNK / 4); i += 256){
        int r = i >> 6, p4 = i & 63;
        *(ushort4v*)&qs[r][p4 * 4] = *(const ushort4v*)&qb[(size_t)r * HW + n0 + p4 * 4];
        *(ushort4v*)&ks[r][p4 * 4] = *(const ushort4v*)&kb[(size_t)r * HW + n0 + p4 * 4];
    }
    __syncthreads();
    int c  = tid >> 3;
    int d0 = (tid & 7) * 4;
    float acc[4] = {0.f, 0.f, 0.f, 0.f};
    for (int p4 = 0; p4 < PCHUNK / 4; ++p4){
        ushort4v qv = *(const ushort4v*)&qs[c][p4 * 4];
        float qf0 = bfbits2f(qv[0]), qf1 = bfbits2f(qv[1]);
        float qf2 = bfbits2f(qv[2]), qf3 = bfbits2f(qv[3]);
        #pragma unroll
        for (int j = 0; j < 4; ++j){
            ushort4v kv = *(const ushort4v*)&ks[d0 + j][p4 * 4];
            acc[j] = fmaf(qf0, bfbits2f(kv[0]),
                     fmaf(qf1, bfbits2f(kv[1]),
                     fmaf(qf2, bfbits2f(kv[2]),
                     fmaf(qf3, bfbits2f(kv[3]), acc[j]))));
        }
    }
    float sc = invqs[c] * temp[h];
    size_t base = ((size_t)chunk * BATCH * HEADS + (size_t)z * HEADS + h) * CP * CP
                + c * CP + d0;
    #pragma unroll
    for (int j = 0; j < 4; ++j)
        part[base + j] = acc[j] * sc * invks[d0 + j];
}

__global__ __launch_bounds__(256) void attn_reduce_kernel(
    const float* __restrict__ part, float* __restrict__ attn)
{
    int idx = blockIdx.x * 256 + threadIdx.x;
    float s = 0.f;
    for (int ch = 0; ch < HW / PCHUNK; ++ch)
        s += part[(size_t)ch * (BATCH * HEADS * CP * CP) + idx];
    attn[idx] = s;
}

// ---------------- head conv 3x3 + softmax (merged) ---------------------------
__global__ __launch_bounds__(256) void headconv_softmax_kernel(
    const float* __restrict__ attn, const float* __restrict__ wh,
    float* __restrict__ attn2)
{
    int oh = blockIdx.x, z = blockIdx.y;
    __shared__ float wsm[HEADS * 9];
    __shared__ float ain[HEADS][CP * CP];
    __shared__ float aout[CP * CP];
    int tid = threadIdx.x;
    if (tid < HEADS * 9) wsm[tid] = wh[oh * HEADS * 9 + tid];
    for (int i = tid; i < HEADS * CP * CP; i += 256)
        ain[i >> 10][i & 1023] = attn[((size_t)z * HEADS + (i >> 10)) * CP * CP + (i & 1023)];
    __syncthreads();
    for (int idx = tid; idx < CP * CP; idx += 256){
        int i = idx >> 5, j = idx & 31;
        float acc = 0.f;
        #pragma unroll
        for (int ih = 0; ih < HEADS; ++ih){
            #pragma unroll
            for (int dy = 0; dy < 3; ++dy){
                int ii = i + dy - 1;
                if (ii < 0 || ii >= CP) continue;
                #pragma unroll
                for (int dx = 0; dx < 3; ++dx){
                    int jj = j + dx - 1;
                    if (jj < 0 || jj >= CP) continue;
                    acc += wsm[ih * 9 + dy * 3 + dx] * ain[ih][ii * CP + jj];
                }
            }
        }
        aout[idx] = acc;
    }
    __syncthreads();
    int r = tid >> 3, l8 = tid & 7;
    float v[4];
    #pragma unroll
    for (int k = 0; k < 4; ++k) v[k] = aout[r * CP + l8 * 4 + k];
    float mx = fmaxf(fmaxf(v[0], v[1]), fmaxf(v[2], v[3]));
    #pragma unroll
    for (int m = 1; m < 8; m <<= 1) mx = fmaxf(mx, __shfl_xor(mx, m, 64));
    float sum = 0.f;
    #pragma unroll
    for (int k = 0; k < 4; ++k){ v[k] = expf(v[k] - mx); sum += v[k]; }
    #pragma unroll
    for (int m = 1; m < 8; m <<= 1) sum += __shfl_xor(sum, m, 64);
    float rs = 1.0f / sum;
    float* o = attn2 + ((size_t)z * HEADS + oh) * CP * CP + r * CP + l8 * 4;
    #pragma unroll
    for (int k = 0; k < 4; ++k) o[k] = v[k] * rs;
}

// ---------------- out = attn2 @ v -> transposed bf16 [HW][C] -----------------
__global__ __launch_bounds__(256) void av_kernel(
    const float* __restrict__ attn2, const bf16* __restrict__ qkv, bf16* __restrict__ outT)
{
    int h = blockIdx.y, z = blockIdx.z;
    int tid = threadIdx.x;
    __shared__ float As[CP][CP];
    __shared__ unsigned short Vs[CP][PCHUNK];
    __shared__ unsigned short ot[256][36];
    for (int i = tid; i < CP * CP; i += 256)
        As[i >> 5][i & 31] = attn2[((size_t)(z * HEADS + h)) * CP * CP + i];
    int n0 = blockIdx.x * 256;
    const unsigned short* vb =
        (const unsigned short*)(qkv + ((size_t)z * 3 * CDIM + 2 * CDIM + h * CP) * HW) + n0;
    for (int i = tid; i < CP * 64; i += 256){
        int d = i >> 6, p4 = (i & 63) * 4;
        *(ushort4v*)&Vs[d][p4] = *(const ushort4v*)(vb + (size_t)d * HW + p4);
    }
    __syncthreads();
    float vreg[CP];
    #pragma unroll
    for (int d = 0; d < CP; ++d) vreg[d] = bfbits2f(Vs[d][tid]);
    for (int c = 0; c < CP; ++c){
        float acc = 0.f;
        #pragma unroll
        for (int d = 0; d < CP; ++d) acc = fmaf(As[c][d], vreg[d], acc);
        ot[tid][c] = f2bf_bits(acc);
    }
    __syncthreads();
    unsigned short* ob = (unsigned short*)outT
        + ((size_t)z * HW + (size_t)n0) * CDIM + h * CP;
    for (int j = tid; j < 256 * 8; j += 256){
        int row = j >> 3, q4 = (j & 7) * 4;
        *(ushort4v*)&ob[(size_t)row * CDIM + q4] = *(ushort4v*)&ot[row][q4];
    }
}

// ---------------- spatial gate partials (16 ch/block, 8 px/thread, bf16 in) --
__global__ __launch_bounds__(256) void gate_partial_kernel(
    const bf16* __restrict__ y, const float* __restrict__ wsa,
    float* __restrict__ part_g)
{
    int cs = blockIdx.y, z = blockIdx.z;
    __shared__ float wsm[16 * 9];
    if (threadIdx.x < 144) wsm[threadIdx.x] = wsa[cs * 144 + threadIdx.x];
    __syncthreads();
    int idx = blockIdx.x * 2048 + threadIdx.x * 8;
    int yy = idx >> 7, xx = idx & 127;
    const unsigned short* yb =
        (const unsigned short*)(y + (size_t)z * CDIM * HW + (size_t)cs * 16 * HW);
    float acc[8] = {0.f,0.f,0.f,0.f,0.f,0.f,0.f,0.f};
    for (int c = 0; c < 16; ++c){
        const unsigned short* pc = yb + (size_t)c * HW;
        #pragma unroll
        for (int dy = 0; dy < 3; ++dy){
            int iy = yy + dy - 1;
            float f[8], lf, rf;
            if (iy >= 0 && iy < HImg){
                ushort8v v8 = *(const ushort8v*)(pc + iy * WImg + xx);
                #pragma unroll
                for (int j = 0; j < 8; ++j) f[j] = bfbits2f(v8[j]);
            } else {
                #pragma unroll
                for (int j = 0; j < 8; ++j) f[j] = 0.f;
            }
            float l = __shfl_up(f[7], 1);
            float r = __shfl_down(f[0], 1);
            lf = (xx == 0) ? 0.f : l;
            rf = (xx + 8 >= WImg) ? 0.f : r;
            const float* wr = &wsm[c * 9 + dy * 3];
            #pragma unroll
            for (int j = 0; j < 8; ++j){
                float e0 = (j == 0) ? lf : f[j - 1];
                float e2 = (j == 7) ? rf : f[j + 1];
                acc[j] = fmaf(wr[0], e0, fmaf(wr[1], f[j], fmaf(wr[2], e2, acc[j])));
            }
        }
    }
    float* og = &part_g[((size_t)cs * BATCH + z) * HW + idx];
    f32x4 o0 = {acc[0], acc[1], acc[2], acc[3]};
    f32x4 o1 = {acc[4], acc[5], acc[6], acc[7]};
    *(f32x4*)og = o0;
    *(f32x4*)(og + 4) = o1;
}

__global__ __launch_bounds__(256) void gate_finish_kernel(
    const float* __restrict__ part_g, const float* __restrict__ bsa,
    float* __restrict__ gate)
{
    int i4 = (blockIdx.x * 256 + threadIdx.x) * 4;   // < BATCH*HW
    float b0 = bsa[0];
    f32x4 acc = {b0, b0, b0, b0};
    #pragma unroll
    for (int cs = 0; cs < CSPLIT; ++cs){
        f32x4 v = *(const f32x4*)&part_g[(size_t)cs * BATCH * HW + i4];
        #pragma unroll
        for (int j = 0; j < 4; ++j) acc[j] += v[j];
    }
    f32x4 o;
    #pragma unroll
    for (int j = 0; j < 4; ++j) o[j] = 1.0f / (1.0f + expf(-acc[j]));
    *(f32x4*)&gate[i4] = o;
}

// ---------------- final: out = x2 + y2 * gate (8 px/thread, bf16 ins) --------
__global__ __launch_bounds__(256) void final_kernel(
    const bf16* __restrict__ x2, const bf16* __restrict__ y2,
    const float* __restrict__ gate, float* __restrict__ out)
{
    size_t i8 = ((size_t)blockIdx.x * 256 + threadIdx.x) * 8;
    int n = (int)(i8 % HW);
    int z = (int)(i8 / ((size_t)CDIM * HW));
    ushort8v a8 = *(const ushort8v*)((const unsigned short*)x2 + i8);
    ushort8v b8 = *(const ushort8v*)((const unsigned short*)y2 + i8);
    const float* gp = gate + (size_t)z * HW + n;
    f32x4 g0 = *(const f32x4*)gp;
    f32x4 g1 = *(const f32x4*)(gp + 4);
    f32x4 o0, o1;
    #pragma unroll
    for (int j = 0; j < 4; ++j){
        o0[j] = bfbits2f(a8[j])     + bfbits2f(b8[j])     * g0[j];
        o1[j] = bfbits2f(a8[j + 4]) + bfbits2f(b8[j + 4]) * g1[j];
    }
    *(f32x4*)(out + i8) = o0;
    *(f32x4*)(out + i8 + 4) = o1;
}

extern "C" void kernel_launch(void* const* d_in, const int* in_sizes, int n_in,
                              void* d_out, int out_size, void* d_ws, size_t ws_size,
                              hipStream_t stream)
{
    const float* x      = (const float*)d_in[0];
    const float* g1     = (const float*)d_in[1];
    const float* b1     = (const float*)d_in[2];
    const float* w_qkv  = (const float*)d_in[3];
    const float* w_dw   = (const float*)d_in[4];
    const float* temp   = (const float*)d_in[5];
    const float* w_head = (const float*)d_in[6];
    const float* w_proj = (const float*)d_in[7];
    const float* g2     = (const float*)d_in[8];
    const float* b2     = (const float*)d_in[9];
    const float* w_fc1  = (const float*)d_in[10];
    const float* b_fc1  = (const float*)d_in[11];
    const float* w_fc2  = (const float*)d_in[12];
    const float* b_fc2  = (const float*)d_in[13];
    const float* w_sa   = (const float*)d_in[14];
    const float* b_sa   = (const float*)d_in[15];
    float* out = (float*)d_out;

    char* ws = (char*)d_ws;
    const size_t FULL = (size_t)BATCH * CDIM * HW;      // 12.58M elems

    // R0 (FULL*2 B): x1 bf16 [C][HW] -> y2 bf16 [C][HW]
    bf16* x1 = (bf16*)ws;
    bf16* y2 = x1;
    // R1 (3*FULL*2 B): qkvA bf16 -> attn_outT bf16 / ln2T bf16 / y1T bf16
    char* R1 = ws + FULL * 2;
    bf16*  qkvA      = (bf16*)R1;
    bf16*  attn_outT = (bf16*)R1;
    bf16*  ln2T      = (bf16*)R1;
    bf16*  y1T       = (bf16*)(R1 + FULL * 2);
    // R2 (3*FULL*2 B): x1T bf16 -> dwB bf16 -> x2 bf16
    char* R2 = R1 + FULL * 3 * 2;
    bf16*  x1T = (bf16*)R2;
    bf16*  dwB = (bf16*)R2;
    bf16*  x2  = (bf16*)R2;
    // small region
    char* SM = R2 + FULL * 3 * 2;
    float* attn   = (float*)SM;                             // B*HEADS*CP*CP
    float* attn2  = attn + BATCH * HEADS * CP * CP;
    float* gate   = attn2 + BATCH * HEADS * CP * CP;        // B*HW
    float* sqp    = gate + BATCH * HW;                      // 2*CDIM*B*DWCHUNK
    float* part   = sqp + 2 * CDIM * BATCH * DWCHUNK;       // 64*B*H*CP*CP (6.3MB)
    float* part_g = part;                                   // aliases part (dead)
    bf16* wq_b  = (bf16*)(part + (HW / PCHUNK) * BATCH * HEADS * CP * CP);
    bf16* wp_b  = wq_b  + 576 * 192;
    bf16* wf1_b = wp_b  + 192 * 192;
    bf16* wf2_b = wf1_b + 384 * 192;

    dim3 blk(256);

    // 0. merged weight conversion to bf16
    convw_kernel<<<dim3((294912 + 255) / 256), blk, 0, stream>>>(
        w_qkv, w_proj, w_fc1, w_fc2, wq_b, wp_b, wf1_b, wf2_b);
    // 1. LayerNorm1 fused: x -> x1 (bf16 [C][HW] residual) + x1T (bf16 [HW][C])
    ln_fused_kernel<float, true><<<dim3(HW / 64, BATCH), blk, 0, stream>>>(
        x, g1, b1, x1, x1T);
    // 2. qkv GEMM -> bf16 [3C][HW]
    gemm_mfma_kernel<0><<<dim3(HW / 128, (3 * CDIM) / 64, BATCH), blk, 0, stream>>>(
        wq_b, x1T, qkvA, nullptr, nullptr, 3 * CDIM, CDIM);
    // 3. depthwise 3x3 (2 rows x 8 px per thread) + q/k sumsq partials
    dw_kernel<<<dim3(DWCHUNK, 3 * CDIM, BATCH), blk, 0, stream>>>(qkvA, w_dw, dwB, sqp);
    // 4. attn partial dot-products (inline l2-inv)
    attn_qk_kernel<<<dim3(HW / PCHUNK, HEADS, BATCH), blk, 0, stream>>>(
        dwB, sqp, temp, part);
    // 5. deterministic reduction of partials
    attn_reduce_kernel<<<dim3((BATCH * HEADS * CP * CP) / 256), blk, 0, stream>>>(part, attn);
    // 6. head conv + softmax (merged)
    headconv_softmax_kernel<<<dim3(HEADS, BATCH), blk, 0, stream>>>(attn, w_head, attn2);
    // 7. out = attn @ v -> bf16 [HW][C] (pre-transposed for proj)
    av_kernel<<<dim3(HW / 256, HEADS, BATCH), blk, 0, stream>>>(attn2, dwB, attn_outT);
    // 8. proj GEMM + residual(x1 bf16) -> x2 bf16 [C][HW]
    gemm_mfma_kernel<1><<<dim3(HW / 128, CDIM / 64, BATCH), blk, 0, stream>>>(
        wp_b, attn_outT, x2, nullptr, x1, CDIM, CDIM);
    // 9. LayerNorm2 fused (bf16 in) -> ln2T bf16 [HW][C]
    ln_fused_kernel<bf16, false><<<dim3(HW / 64, BATCH), blk, 0, stream>>>(
        x2, g2, b2, nullptr, ln2T);
    // 10. fc1 GEMM + bias + gelu -> y1T bf16 [HW][HIDDEN]
    gemm_mfma_kernel<3><<<dim3(HW / 128, HIDDEN / 64, BATCH), blk, 0, stream>>>(
        wf1_b, ln2T, y1T, b_fc1, nullptr, HIDDEN, CDIM);
    // 11. fc2 GEMM + bias + gelu -> y2 bf16 [C][HW]
    gemm_mfma_kernel<2><<<dim3(HW / 128, CDIM / 64, BATCH), blk, 0, stream>>>(
        wf2_b, y1T, y2, b_fc2, nullptr, CDIM, HIDDEN);
    // 12. spatial gate: channel-split partials (8 px/thread) + finish
    gate_partial_kernel<<<dim3(HW / 2048, CSPLIT, BATCH), blk, 0, stream>>>(
        y2, w_sa, part_g);
    gate_finish_kernel<<<dim3(BATCH * HW / 1024), blk, 0, stream>>>(part_g, b_sa, gate);
    // 13. final: out = x2 + y2*gate (8 px/thread)
    final_kernel<<<dim3((int)(FULL / 2048)), blk, 0, stream>>>(x2, y2, gate, out);
}

// Round 12
// 286.914 us; speedup vs baseline: 1.0847x; 1.0091x over previous
//
#include <hip/hip_runtime.h>
#include <hip/hip_bf16.h>
#include <math.h>

using bf16 = __hip_bfloat16;

static constexpr int CDIM   = 192;
static constexpr int HEADS  = 6;
static constexpr int CP     = 32;     // CDIM / HEADS
static constexpr int HIDDEN = 384;
static constexpr int HImg   = 128;
static constexpr int WImg   = 128;
static constexpr int HW     = HImg * WImg;   // 16384
static constexpr int BATCH  = 4;
static constexpr int PCHUNK = 256;    // attn contraction chunk
static constexpr int CSPLIT = 12;     // gate conv channel splits (16 ch each)
static constexpr int DWCHUNK = 4;     // dw y-blocks per channel image (32 rows each)

typedef __attribute__((ext_vector_type(8))) short short8;
typedef __attribute__((ext_vector_type(4))) float f32x4;
typedef __attribute__((ext_vector_type(4))) unsigned short ushort4v;
typedef __attribute__((ext_vector_type(8))) unsigned short ushort8v;

template<typename T> __device__ inline float tof(T v);
template<> __device__ inline float tof<float>(float v){ return v; }
template<> __device__ inline float tof<bf16>(bf16 v){ return __bfloat162float(v); }

template<typename T> __device__ inline T fromf(float v);
template<> __device__ inline float fromf<float>(float v){ return v; }
template<> __device__ inline bf16  fromf<bf16>(float v){ return __float2bfloat16(v); }

__device__ inline unsigned short f2bf_bits(float f){
    bf16 h = __float2bfloat16(f);
    return *reinterpret_cast<unsigned short*>(&h);
}
__device__ inline float bfbits2f(unsigned short u){
    union { unsigned int i; float f; } c; c.i = ((unsigned int)u) << 16; return c.f;
}

__device__ inline float gelu_exact(float x){
    return 0.5f * x * (1.0f + erff(x * 0.70710678118654752440f));
}

// load 4 consecutive elems as float
__device__ inline void load4f(const float* p, float* f){
    f32x4 v = *reinterpret_cast<const f32x4*>(p);
    f[0]=v[0]; f[1]=v[1]; f[2]=v[2]; f[3]=v[3];
}
__device__ inline void load4f(const bf16* p, float* f){
    ushort4v v = *reinterpret_cast<const ushort4v*>(p);
    f[0]=bfbits2f(v[0]); f[1]=bfbits2f(v[1]); f[2]=bfbits2f(v[2]); f[3]=bfbits2f(v[3]);
}

// async global(16B) -> LDS
__device__ __forceinline__ void gload16(const bf16* g, bf16* l){
    __builtin_amdgcn_global_load_lds(
        (const __attribute__((address_space(1))) void*)g,
        (__attribute__((address_space(3))) void*)l, 16, 0, 0);
}

// ---------------- merged f32 -> bf16 weight convert --------------------------
__global__ __launch_bounds__(256) void convw_kernel(
    const float* __restrict__ w_qkv, const float* __restrict__ w_proj,
    const float* __restrict__ w_fc1, const float* __restrict__ w_fc2,
    bf16* __restrict__ wq, bf16* __restrict__ wp,
    bf16* __restrict__ wf1, bf16* __restrict__ wf2)
{
    int i = blockIdx.x * 256 + threadIdx.x;
    const int n0 = 576*192, n1 = n0 + 192*192, n2 = n1 + 384*192, n3 = n2 + 192*384;
    if (i < n0)      wq[i]       = fromf<bf16>(w_qkv[i]);
    else if (i < n1) wp[i - n0]  = fromf<bf16>(w_proj[i - n0]);
    else if (i < n2) wf1[i - n1] = fromf<bf16>(w_fc1[i - n1]);
    else if (i < n3) wf2[i - n2] = fromf<bf16>(w_fc2[i - n2]);
}

// ---------------- fused LayerNorm (+optional bf16 [C][HW] copy) + transpose --
template<typename T, bool WRES>
__global__ __launch_bounds__(256) void ln_fused_kernel(
    const T* __restrict__ in, const float* __restrict__ g,
    const float* __restrict__ b, bf16* __restrict__ resF, bf16* __restrict__ outT)
{
    int z = blockIdx.y, p0 = blockIdx.x * 64;
    __shared__ float tile[CDIM][65];
    __shared__ float sred[4][64], s2red[4][64];
    __shared__ float mrow[64], rrow[64];
    const T* ib = in + (size_t)z * CDIM * HW + p0;
    int tid = threadIdx.x;
    for (int j = tid; j < CDIM * 16; j += 256){
        int c = j >> 4, p4 = (j & 15) * 4;
        float f[4];
        load4f(ib + (size_t)c * HW + p4, f);
        tile[c][p4]   = f[0]; tile[c][p4+1] = f[1];
        tile[c][p4+2] = f[2]; tile[c][p4+3] = f[3];
    }
    __syncthreads();
    int p = tid & 63, q = tid >> 6;
    float s = 0.f, s2 = 0.f;
    #pragma unroll 4
    for (int c = q * 48; c < q * 48 + 48; ++c){
        float v = tile[c][p]; s += v; s2 += v * v;
    }
    sred[q][p] = s; s2red[q][p] = s2;
    __syncthreads();
    if (tid < 64){
        float ts = sred[0][tid] + sred[1][tid] + sred[2][tid] + sred[3][tid];
        float t2 = s2red[0][tid] + s2red[1][tid] + s2red[2][tid] + s2red[3][tid];
        float mean = ts * (1.0f / CDIM);
        float var  = t2 * (1.0f / CDIM) - mean * mean;
        mrow[tid] = mean;
        rrow[tid] = rsqrtf(var + 1e-5f);
    }
    __syncthreads();
    unsigned short* oT = (unsigned short*)(outT + ((size_t)z * HW + p0) * CDIM);
    for (int j = tid; j < 64 * 48; j += 256){
        int pr = j / 48, c4 = (j % 48) * 4;
        float m = mrow[pr], r = rrow[pr];
        ushort4v o;
        #pragma unroll
        for (int k = 0; k < 4; ++k){
            int c = c4 + k;
            o[k] = f2bf_bits((tile[c][pr] - m) * r * g[c] + b[c]);
        }
        *(ushort4v*)&oT[(size_t)pr * CDIM + c4] = o;
    }
    if (WRES){
        unsigned short* oF = (unsigned short*)resF + (size_t)z * CDIM * HW + p0;
        for (int j = tid; j < CDIM * 16; j += 256){
            int c = j >> 4, p4 = (j & 15) * 4;
            float gg = g[c], bb = b[c];
            ushort4v v;
            #pragma unroll
            for (int k = 0; k < 4; ++k)
                v[k] = f2bf_bits((tile[c][p4 + k] - mrow[p4 + k]) * rrow[p4 + k] * gg + bb);
            *(ushort4v*)&oF[(size_t)c * HW + p4] = v;
        }
    }
}

// ---------------- MFMA GEMM: C[M,N] = Wb[M,K] @ XT[N,K]^T, batched -----------
// Round-8 structure (proven local optimum): 64m x 128n block, 2x2 waves
// (32m x 64n each), single-buffered LDS staging via global_load_lds,
// vmcnt(0)+syncthreads per K-tile. LDS 24 KB -> high occupancy (~35%).
// EPI: 0 = bf16 out [M][HW]; 1 = bf16 out + bf16 residual; 2 = bias+gelu bf16;
//      3 = bias+gelu -> transposed bf16 out [HW][M]
template<int EPI>
__global__ __launch_bounds__(256) void gemm_mfma_kernel(
    const bf16* __restrict__ Wb, const bf16* __restrict__ XT,
    void* __restrict__ Cout, const float* __restrict__ bias,
    const bf16* __restrict__ res, int M, int K)
{
    __shared__ bf16 smem[12288];              // A: 64x64 (4096), B: 128x64 (8192)
    bf16* Als = smem;
    bf16* Bls = smem + 4096;
    int z  = blockIdx.z;
    int n0 = blockIdx.x * 128;
    int m0 = blockIdx.y * 64;
    const bf16* Xb = XT + (size_t)z * (size_t)HW * K;
    int tid  = threadIdx.x;
    int lane = tid & 63, wid = tid >> 6;
    int wm = wid & 1, wn = wid >> 1;          // 2x2 waves, each 32m x 64n
    int r16 = lane & 15, grp = lane >> 4;

    f32x4 acc[2][4];
    #pragma unroll
    for (int i = 0; i < 2; ++i)
        #pragma unroll
        for (int j = 0; j < 4; ++j){ f32x4 zz = {0.f,0.f,0.f,0.f}; acc[i][j] = zz; }

    int nkt = K >> 6;
    for (int kt = 0; kt < nkt; ++kt){
        #pragma unroll
        for (int i = 0; i < 2; ++i){
            int s = i * 256 + tid;
            int row = s >> 3, ch = s & 7;
            gload16(Wb + (size_t)(m0 + row) * K + kt * 64 + ((ch ^ (row & 7)) * 8),
                    Als + s * 8);
        }
        #pragma unroll
        for (int i = 0; i < 4; ++i){
            int s = i * 256 + tid;
            int row = s >> 3, ch = s & 7;
            gload16(Xb + (size_t)(n0 + row) * K + kt * 64 + ((ch ^ (row & 7)) * 8),
                    Bls + s * 8);
        }
        asm volatile("s_waitcnt vmcnt(0)" ::: "memory");
        __syncthreads();
        #pragma unroll
        for (int ks = 0; ks < 2; ++ks){
            int kel = ks * 32 + grp * 8;
            short8 a[2], b[4];
            #pragma unroll
            for (int fi = 0; fi < 2; ++fi){
                int row = wm * 32 + fi * 16 + r16;
                a[fi] = *reinterpret_cast<const short8*>(Als + row * 64 + (kel ^ ((row & 7) * 8)));
            }
            #pragma unroll
            for (int fj = 0; fj < 4; ++fj){
                int row = wn * 64 + fj * 16 + r16;
                b[fj] = *reinterpret_cast<const short8*>(Bls + row * 64 + (kel ^ ((row & 7) * 8)));
            }
            #pragma unroll
            for (int fi = 0; fi < 2; ++fi)
                #pragma unroll
                for (int fj = 0; fj < 4; ++fj)
                    acc[fi][fj] = __builtin_amdgcn_mfma_f32_16x16x32_bf16(
                        a[fi], b[fj], acc[fi][fj], 0, 0, 0);
        }
        __syncthreads();
    }

    if (EPI == 3){
        // transposed bf16 out via LDS T[n(128)][m(64)] stride 72
        unsigned short* T = (unsigned short*)smem;
        #pragma unroll
        for (int fi = 0; fi < 2; ++fi)
            #pragma unroll
            for (int fj = 0; fj < 4; ++fj){
                int nl = wn * 64 + fj * 16 + r16;
                int mb = wm * 32 + fi * 16 + grp * 4;
                #pragma unroll
                for (int rr = 0; rr < 4; ++rr){
                    float v = gelu_exact(acc[fi][fj][rr] + bias[m0 + mb + rr]);
                    T[nl * 72 + mb + rr] = f2bf_bits(v);
                }
            }
        __syncthreads();
        bf16* Y = (bf16*)Cout;
        int rrow = tid >> 1, half = tid & 1;
        const short8* srcv = reinterpret_cast<const short8*>(T + rrow * 72 + half * 32);
        short8* dstv = reinterpret_cast<short8*>(
            Y + ((size_t)z * HW + n0 + rrow) * M + m0 + half * 32);
        #pragma unroll
        for (int i = 0; i < 4; ++i) dstv[i] = srcv[i];
        return;
    }

    // [M][HW] epilogues via LDS T[m(64)][n(128)] stride 136, 16B stores
    {
        unsigned short* T = (unsigned short*)smem;
        #pragma unroll
        for (int fi = 0; fi < 2; ++fi)
            #pragma unroll
            for (int fj = 0; fj < 4; ++fj){
                int m = wm * 32 + fi * 16 + grp * 4;
                int n = wn * 64 + fj * 16 + r16;
                #pragma unroll
                for (int rr = 0; rr < 4; ++rr)
                    T[(m + rr) * 136 + n] = f2bf_bits(acc[fi][fj][rr]);
            }
        __syncthreads();
        int row = tid >> 2, c8 = (tid & 3) * 8;      // 64 rows x 4 chunk-slots
        bf16* Cb = (bf16*)Cout;
        size_t gbase = (size_t)z * M * HW + (size_t)(m0 + row) * HW + n0 + c8;
        float bv = (EPI == 2) ? bias[m0 + row] : 0.f;
        #pragma unroll
        for (int j = 0; j < 4; ++j){
            int coff = j * 32;
            ushort8v t8 = *(const ushort8v*)&T[row * 136 + c8 + coff];
            ushort8v o8;
            if (EPI == 0){
                o8 = t8;
            } else if (EPI == 1){
                ushort8v r8 = *(const ushort8v*)((const unsigned short*)res + gbase + coff);
                #pragma unroll
                for (int k = 0; k < 8; ++k)
                    o8[k] = f2bf_bits(bfbits2f(t8[k]) + bfbits2f(r8[k]));
            } else {
                #pragma unroll
                for (int k = 0; k < 8; ++k)
                    o8[k] = f2bf_bits(gelu_exact(bfbits2f(t8[k]) + bv));
            }
            *(ushort8v*)((unsigned short*)Cb + gbase + coff) = o8;
        }
    }
}

// ---------------- depthwise 3x3: 2 rows x 8 px per thread + q/k sumsq --------
__global__ __launch_bounds__(256) void dw_kernel(
    const bf16* __restrict__ in, const float* __restrict__ wdw,
    bf16* __restrict__ out, float* __restrict__ sqp)
{
    int ch = blockIdx.y, z = blockIdx.z;
    int tid = threadIdx.x;
    int rp = tid >> 4;                          // 16 row-pairs per block
    int xx = (tid & 15) * 8;                    // 16 lanes per image row
    int y0 = blockIdx.x * 32 + rp * 2;          // first output row
    const unsigned short* p =
        (const unsigned short*)(in + ((size_t)z * 3 * CDIM + ch) * HW);
    float w[9];
    #pragma unroll
    for (int t = 0; t < 9; ++t) w[t] = wdw[ch * 9 + t];
    float f[4][8], lf[4], rf[4];
    #pragma unroll
    for (int r = 0; r < 4; ++r){
        int iy = y0 - 1 + r;
        if (iy >= 0 && iy < HImg){
            ushort8v v8 = *(const ushort8v*)(p + iy * WImg + xx);
            #pragma unroll
            for (int j = 0; j < 8; ++j) f[r][j] = bfbits2f(v8[j]);
        } else {
            #pragma unroll
            for (int j = 0; j < 8; ++j) f[r][j] = 0.f;
        }
        float l = __shfl_up(f[r][7], 1);
        float rr_ = __shfl_down(f[r][0], 1);
        lf[r] = (xx == 0) ? 0.f : l;
        rf[r] = (xx + 8 >= WImg) ? 0.f : rr_;
    }
    float sq = 0.f;
    unsigned short* ob = (unsigned short*)(out + ((size_t)z * 3 * CDIM + ch) * HW);
    #pragma unroll
    for (int orow = 0; orow < 2; ++orow){
        ushort8v o8;
        #pragma unroll
        for (int j = 0; j < 8; ++j){
            float a = 0.f;
            #pragma unroll
            for (int dy = 0; dy < 3; ++dy){
                int r = orow + dy;
                float e0 = (j == 0) ? lf[r] : f[r][j - 1];
                float e2 = (j == 7) ? rf[r] : f[r][j + 1];
                a = fmaf(w[dy*3], e0, fmaf(w[dy*3+1], f[r][j], fmaf(w[dy*3+2], e2, a)));
            }
            o8[j] = f2bf_bits(a);
            sq = fmaf(a, a, sq);
        }
        *(ushort8v*)(ob + (y0 + orow) * WImg + xx) = o8;
    }
    if (ch < 2 * CDIM){
        #pragma unroll
        for (int m = 1; m < 64; m <<= 1) sq += __shfl_xor(sq, m, 64);
        __shared__ float red[4];
        if ((tid & 63) == 0) red[tid >> 6] = sq;
        __syncthreads();
        if (tid == 0)
            sqp[((size_t)ch * BATCH + z) * DWCHUNK + blockIdx.x] =
                red[0] + red[1] + red[2] + red[3];
    }
}

// ---------------- attn partials (inline l2-inv from sqp) ---------------------
__global__ __launch_bounds__(256) void attn_qk_kernel(
    const bf16* __restrict__ qkv, const float* __restrict__ sqp,
    const float* __restrict__ temp, float* __restrict__ part)
{
    int chunk = blockIdx.x;
    int h = blockIdx.y, z = blockIdx.z;
    __shared__ unsigned short qs[CP][PCHUNK + 4];
    __shared__ unsigned short ks[CP][PCHUNK + 4];
    __shared__ float invqs[CP], invks[CP];
    int tid = threadIdx.x;
    if (tid < 2 * CP){
        int which = tid >> 5, cc = tid & 31;
        int ch = which * CDIM + h * CP + cc;
        const float* sp = &sqp[((size_t)ch * BATCH + z) * DWCHUNK];
        float s = sp[0] + sp[1] + sp[2] + sp[3];
        float inv = 1.0f / fmaxf(sqrtf(s), 1e-12f);
        (which ? invks : invqs)[cc] = inv;
    }
    int n0 = chunk * PCHUNK;
    const unsigned short* qb = (const unsigned short*)(qkv + ((size_t)z * 3 * CDIM + h * CP) * HW);
    const unsigned short* kb = (const unsigned short*)(qkv + ((size_t)z * 3 * CDIM + CDIM + h * CP) * HW);
    for (int i = tid; i < CP * (PCHUNK / 4); i += 256){
        int r = i >> 6, p4 = i & 63;
        *(ushort4v*)&qs[r][p4 * 4] = *(const ushort4v*)&qb[(size_t)r * HW + n0 + p4 * 4];
        *(ushort4v*)&ks[r][p4 * 4] = *(const ushort4v*)&kb[(size_t)r * HW + n0 + p4 * 4];
    }
    __syncthreads();
    int c  = tid >> 3;
    int d0 = (tid & 7) * 4;
    float acc[4] = {0.f, 0.f, 0.f, 0.f};
    for (int p4 = 0; p4 < PCHUNK / 4; ++p4){
        ushort4v qv = *(const ushort4v*)&qs[c][p4 * 4];
        float qf0 = bfbits2f(qv[0]), qf1 = bfbits2f(qv[1]);
        float qf2 = bfbits2f(qv[2]), qf3 = bfbits2f(qv[3]);
        #pragma unroll
        for (int j = 0; j < 4; ++j){
            ushort4v kv = *(const ushort4v*)&ks[d0 + j][p4 * 4];
            acc[j] = fmaf(qf0, bfbits2f(kv[0]),
                     fmaf(qf1, bfbits2f(kv[1]),
                     fmaf(qf2, bfbits2f(kv[2]),
                     fmaf(qf3, bfbits2f(kv[3]), acc[j]))));
        }
    }
    float sc = invqs[c] * temp[h];
    size_t base = ((size_t)chunk * BATCH * HEADS + (size_t)z * HEADS + h) * CP * CP
                + c * CP + d0;
    #pragma unroll
    for (int j = 0; j < 4; ++j)
        part[base + j] = acc[j] * sc * invks[d0 + j];
}

__global__ __launch_bounds__(256) void attn_reduce_kernel(
    const float* __restrict__ part, float* __restrict__ attn)
{
    int idx = blockIdx.x * 256 + threadIdx.x;
    float s = 0.f;
    for (int ch = 0; ch < HW / PCHUNK; ++ch)
        s += part[(size_t)ch * (BATCH * HEADS * CP * CP) + idx];
    attn[idx] = s;
}

// ---------------- head conv 3x3 + softmax (merged) ---------------------------
__global__ __launch_bounds__(256) void headconv_softmax_kernel(
    const float* __restrict__ attn, const float* __restrict__ wh,
    float* __restrict__ attn2)
{
    int oh = blockIdx.x, z = blockIdx.y;
    __shared__ float wsm[HEADS * 9];
    __shared__ float ain[HEADS][CP * CP];
    __shared__ float aout[CP * CP];
    int tid = threadIdx.x;
    if (tid < HEADS * 9) wsm[tid] = wh[oh * HEADS * 9 + tid];
    for (int i = tid; i < HEADS * CP * CP; i += 256)
        ain[i >> 10][i & 1023] = attn[((size_t)z * HEADS + (i >> 10)) * CP * CP + (i & 1023)];
    __syncthreads();
    for (int idx = tid; idx < CP * CP; idx += 256){
        int i = idx >> 5, j = idx & 31;
        float acc = 0.f;
        #pragma unroll
        for (int ih = 0; ih < HEADS; ++ih){
            #pragma unroll
            for (int dy = 0; dy < 3; ++dy){
                int ii = i + dy - 1;
                if (ii < 0 || ii >= CP) continue;
                #pragma unroll
                for (int dx = 0; dx < 3; ++dx){
                    int jj = j + dx - 1;
                    if (jj < 0 || jj >= CP) continue;
                    acc += wsm[ih * 9 + dy * 3 + dx] * ain[ih][ii * CP + jj];
                }
            }
        }
        aout[idx] = acc;
    }
    __syncthreads();
    int r = tid >> 3, l8 = tid & 7;
    float v[4];
    #pragma unroll
    for (int k = 0; k < 4; ++k) v[k] = aout[r * CP + l8 * 4 + k];
    float mx = fmaxf(fmaxf(v[0], v[1]), fmaxf(v[2], v[3]));
    #pragma unroll
    for (int m = 1; m < 8; m <<= 1) mx = fmaxf(mx, __shfl_xor(mx, m, 64));
    float sum = 0.f;
    #pragma unroll
    for (int k = 0; k < 4; ++k){ v[k] = expf(v[k] - mx); sum += v[k]; }
    #pragma unroll
    for (int m = 1; m < 8; m <<= 1) sum += __shfl_xor(sum, m, 64);
    float rs = 1.0f / sum;
    float* o = attn2 + ((size_t)z * HEADS + oh) * CP * CP + r * CP + l8 * 4;
    #pragma unroll
    for (int k = 0; k < 4; ++k) o[k] = v[k] * rs;
}

// ---------------- out = attn2 @ v -> transposed bf16 [HW][C] -----------------
__global__ __launch_bounds__(256) void av_kernel(
    const float* __restrict__ attn2, const bf16* __restrict__ qkv, bf16* __restrict__ outT)
{
    int h = blockIdx.y, z = blockIdx.z;
    int tid = threadIdx.x;
    __shared__ float As[CP][CP];
    __shared__ unsigned short Vs[CP][PCHUNK];
    __shared__ unsigned short ot[256][36];
    for (int i = tid; i < CP * CP; i += 256)
        As[i >> 5][i & 31] = attn2[((size_t)(z * HEADS + h)) * CP * CP + i];
    int n0 = blockIdx.x * 256;
    const unsigned short* vb =
        (const unsigned short*)(qkv + ((size_t)z * 3 * CDIM + 2 * CDIM + h * CP) * HW) + n0;
    for (int i = tid; i < CP * 64; i += 256){
        int d = i >> 6, p4 = (i & 63) * 4;
        *(ushort4v*)&Vs[d][p4] = *(const ushort4v*)(vb + (size_t)d * HW + p4);
    }
    __syncthreads();
    float vreg[CP];
    #pragma unroll
    for (int d = 0; d < CP; ++d) vreg[d] = bfbits2f(Vs[d][tid]);
    for (int c = 0; c < CP; ++c){
        float acc = 0.f;
        #pragma unroll
        for (int d = 0; d < CP; ++d) acc = fmaf(As[c][d], vreg[d], acc);
        ot[tid][c] = f2bf_bits(acc);
    }
    __syncthreads();
    unsigned short* ob = (unsigned short*)outT
        + ((size_t)z * HW + (size_t)n0) * CDIM + h * CP;
    for (int j = tid; j < 256 * 8; j += 256){
        int row = j >> 3, q4 = (j & 7) * 4;
        *(ushort4v*)&ob[(size_t)row * CDIM + q4] = *(ushort4v*)&ot[row][q4];
    }
}

// ---------------- spatial gate partials (16 ch/block, 8 px/thread, bf16 out) -
__global__ __launch_bounds__(256) void gate_partial_kernel(
    const bf16* __restrict__ y, const float* __restrict__ wsa,
    bf16* __restrict__ part_g)
{
    int cs = blockIdx.y, z = blockIdx.z;
    __shared__ float wsm[16 * 9];
    if (threadIdx.x < 144) wsm[threadIdx.x] = wsa[cs * 144 + threadIdx.x];
    __syncthreads();
    int idx = blockIdx.x * 2048 + threadIdx.x * 8;
    int yy = idx >> 7, xx = idx & 127;
    const unsigned short* yb =
        (const unsigned short*)(y + (size_t)z * CDIM * HW + (size_t)cs * 16 * HW);
    float acc[8] = {0.f,0.f,0.f,0.f,0.f,0.f,0.f,0.f};
    for (int c = 0; c < 16; ++c){
        const unsigned short* pc = yb + (size_t)c * HW;
        #pragma unroll
        for (int dy = 0; dy < 3; ++dy){
            int iy = yy + dy - 1;
            float f[8], lf, rf;
            if (iy >= 0 && iy < HImg){
                ushort8v v8 = *(const ushort8v*)(pc + iy * WImg + xx);
                #pragma unroll
                for (int j = 0; j < 8; ++j) f[j] = bfbits2f(v8[j]);
            } else {
                #pragma unroll
                for (int j = 0; j < 8; ++j) f[j] = 0.f;
            }
            float l = __shfl_up(f[7], 1);
            float r = __shfl_down(f[0], 1);
            lf = (xx == 0) ? 0.f : l;
            rf = (xx + 8 >= WImg) ? 0.f : r;
            const float* wr = &wsm[c * 9 + dy * 3];
            #pragma unroll
            for (int j = 0; j < 8; ++j){
                float e0 = (j == 0) ? lf : f[j - 1];
                float e2 = (j == 7) ? rf : f[j + 1];
                acc[j] = fmaf(wr[0], e0, fmaf(wr[1], f[j], fmaf(wr[2], e2, acc[j])));
            }
        }
    }
    ushort8v o8;
    #pragma unroll
    for (int j = 0; j < 8; ++j) o8[j] = f2bf_bits(acc[j]);
    *(ushort8v*)((unsigned short*)part_g + ((size_t)cs * BATCH + z) * HW + idx) = o8;
}

__global__ __launch_bounds__(256) void gate_finish_kernel(
    const bf16* __restrict__ part_g, const float* __restrict__ bsa,
    float* __restrict__ gate)
{
    int i4 = (blockIdx.x * 256 + threadIdx.x) * 4;   // < BATCH*HW
    float b0 = bsa[0];
    f32x4 acc = {b0, b0, b0, b0};
    #pragma unroll
    for (int cs = 0; cs < CSPLIT; ++cs){
        ushort4v v = *(const ushort4v*)((const unsigned short*)part_g
                                        + (size_t)cs * BATCH * HW + i4);
        #pragma unroll
        for (int j = 0; j < 4; ++j) acc[j] += bfbits2f(v[j]);
    }
    f32x4 o;
    #pragma unroll
    for (int j = 0; j < 4; ++j) o[j] = 1.0f / (1.0f + expf(-acc[j]));
    *(f32x4*)&gate[i4] = o;
}

// ---------------- final: out = x2 + y2 * gate (8 px/thread, bf16 ins) --------
__global__ __launch_bounds__(256) void final_kernel(
    const bf16* __restrict__ x2, const bf16* __restrict__ y2,
    const float* __restrict__ gate, float* __restrict__ out)
{
    size_t i8 = ((size_t)blockIdx.x * 256 + threadIdx.x) * 8;
    int n = (int)(i8 % HW);
    int z = (int)(i8 / ((size_t)CDIM * HW));
    ushort8v a8 = *(const ushort8v*)((const unsigned short*)x2 + i8);
    ushort8v b8 = *(const ushort8v*)((const unsigned short*)y2 + i8);
    const float* gp = gate + (size_t)z * HW + n;
    f32x4 g0 = *(const f32x4*)gp;
    f32x4 g1 = *(const f32x4*)(gp + 4);
    f32x4 o0, o1;
    #pragma unroll
    for (int j = 0; j < 4; ++j){
        o0[j] = bfbits2f(a8[j])     + bfbits2f(b8[j])     * g0[j];
        o1[j] = bfbits2f(a8[j + 4]) + bfbits2f(b8[j + 4]) * g1[j];
    }
    *(f32x4*)(out + i8) = o0;
    *(f32x4*)(out + i8 + 4) = o1;
}

extern "C" void kernel_launch(void* const* d_in, const int* in_sizes, int n_in,
                              void* d_out, int out_size, void* d_ws, size_t ws_size,
                              hipStream_t stream)
{
    const float* x      = (const float*)d_in[0];
    const float* g1     = (const float*)d_in[1];
    const float* b1     = (const float*)d_in[2];
    const float* w_qkv  = (const float*)d_in[3];
    const float* w_dw   = (const float*)d_in[4];
    const float* temp   = (const float*)d_in[5];
    const float* w_head = (const float*)d_in[6];
    const float* w_proj = (const float*)d_in[7];
    const float* g2     = (const float*)d_in[8];
    const float* b2     = (const float*)d_in[9];
    const float* w_fc1  = (const float*)d_in[10];
    const float* b_fc1  = (const float*)d_in[11];
    const float* w_fc2  = (const float*)d_in[12];
    const float* b_fc2  = (const float*)d_in[13];
    const float* w_sa   = (const float*)d_in[14];
    const float* b_sa   = (const float*)d_in[15];
    float* out = (float*)d_out;

    char* ws = (char*)d_ws;
    const size_t FULL = (size_t)BATCH * CDIM * HW;      // 12.58M elems

    // R0 (FULL*2 B): x1 bf16 [C][HW] -> y2 bf16 [C][HW]
    bf16* x1 = (bf16*)ws;
    bf16* y2 = x1;
    // R1 (3*FULL*2 B): qkvA bf16 -> attn_outT bf16 / ln2T bf16 / y1T bf16
    char* R1 = ws + FULL * 2;
    bf16*  qkvA      = (bf16*)R1;
    bf16*  attn_outT = (bf16*)R1;
    bf16*  ln2T      = (bf16*)R1;
    bf16*  y1T       = (bf16*)(R1 + FULL * 2);
    // R2 (3*FULL*2 B): x1T bf16 -> dwB bf16 -> x2 bf16
    char* R2 = R1 + FULL * 3 * 2;
    bf16*  x1T = (bf16*)R2;
    bf16*  dwB = (bf16*)R2;
    bf16*  x2  = (bf16*)R2;
    // small region
    char* SM = R2 + FULL * 3 * 2;
    float* attn   = (float*)SM;                             // B*HEADS*CP*CP
    float* attn2  = attn + BATCH * HEADS * CP * CP;
    float* gate   = attn2 + BATCH * HEADS * CP * CP;        // B*HW
    float* sqp    = gate + BATCH * HW;                      // 2*CDIM*B*DWCHUNK
    float* part   = sqp + 2 * CDIM * BATCH * DWCHUNK;       // 64*B*H*CP*CP (6.3MB)
    bf16*  part_g = (bf16*)part;                            // aliases part (dead)
    bf16* wq_b  = (bf16*)(part + (HW / PCHUNK) * BATCH * HEADS * CP * CP);
    bf16* wp_b  = wq_b  + 576 * 192;
    bf16* wf1_b = wp_b  + 192 * 192;
    bf16* wf2_b = wf1_b + 384 * 192;

    dim3 blk(256);

    // 0. merged weight conversion to bf16
    convw_kernel<<<dim3((294912 + 255) / 256), blk, 0, stream>>>(
        w_qkv, w_proj, w_fc1, w_fc2, wq_b, wp_b, wf1_b, wf2_b);
    // 1. LayerNorm1 fused: x -> x1 (bf16 [C][HW] residual) + x1T (bf16 [HW][C])
    ln_fused_kernel<float, true><<<dim3(HW / 64, BATCH), blk, 0, stream>>>(
        x, g1, b1, x1, x1T);
    // 2. qkv GEMM -> bf16 [3C][HW]
    gemm_mfma_kernel<0><<<dim3(HW / 128, (3 * CDIM) / 64, BATCH), blk, 0, stream>>>(
        wq_b, x1T, qkvA, nullptr, nullptr, 3 * CDIM, CDIM);
    // 3. depthwise 3x3 (2 rows x 8 px per thread) + q/k sumsq partials
    dw_kernel<<<dim3(DWCHUNK, 3 * CDIM, BATCH), blk, 0, stream>>>(qkvA, w_dw, dwB, sqp);
    // 4. attn partial dot-products (inline l2-inv)
    attn_qk_kernel<<<dim3(HW / PCHUNK, HEADS, BATCH), blk, 0, stream>>>(
        dwB, sqp, temp, part);
    // 5. deterministic reduction of partials
    attn_reduce_kernel<<<dim3((BATCH * HEADS * CP * CP) / 256), blk, 0, stream>>>(part, attn);
    // 6. head conv + softmax (merged)
    headconv_softmax_kernel<<<dim3(HEADS, BATCH), blk, 0, stream>>>(attn, w_head, attn2);
    // 7. out = attn @ v -> bf16 [HW][C] (pre-transposed for proj)
    av_kernel<<<dim3(HW / 256, HEADS, BATCH), blk, 0, stream>>>(attn2, dwB, attn_outT);
    // 8. proj GEMM + residual(x1 bf16) -> x2 bf16 [C][HW]
    gemm_mfma_kernel<1><<<dim3(HW / 128, CDIM / 64, BATCH), blk, 0, stream>>>(
        wp_b, attn_outT, x2, nullptr, x1, CDIM, CDIM);
    // 9. LayerNorm2 fused (bf16 in) -> ln2T bf16 [HW][C]
    ln_fused_kernel<bf16, false><<<dim3(HW / 64, BATCH), blk, 0, stream>>>(
        x2, g2, b2, nullptr, ln2T);
    // 10. fc1 GEMM + bias + gelu -> y1T bf16 [HW][HIDDEN]
    gemm_mfma_kernel<3><<<dim3(HW / 128, HIDDEN / 64, BATCH), blk, 0, stream>>>(
        wf1_b, ln2T, y1T, b_fc1, nullptr, HIDDEN, CDIM);
    // 11. fc2 GEMM + bias + gelu -> y2 bf16 [C][HW]
    gemm_mfma_kernel<2><<<dim3(HW / 128, CDIM / 64, BATCH), blk, 0, stream>>>(
        wf2_b, y1T, y2, b_fc2, nullptr, CDIM, HIDDEN);
    // 12. spatial gate: channel-split partials (bf16 out) + finish
    gate_partial_kernel<<<dim3(HW / 2048, CSPLIT, BATCH), blk, 0, stream>>>(
        y2, w_sa, part_g);
    gate_finish_kernel<<<dim3(BATCH * HW / 1024), blk, 0, stream>>>(part_g, b_sa, gate);
    // 13. final: out = x2 + y2*gate (8 px/thread)
    final_kernel<<<dim3((int)(FULL / 2048)), blk, 0, stream>>>(x2, y2, gate, out);
}

// Round 13
// 284.256 us; speedup vs baseline: 1.0948x; 1.0093x over previous
//
#include <hip/hip_runtime.h>
#include <hip/hip_bf16.h>
#include <math.h>

using bf16 = __hip_bfloat16;

static constexpr int CDIM   = 192;
static constexpr int HEADS  = 6;
static constexpr int CP     = 32;     // CDIM / HEADS
static constexpr int HIDDEN = 384;
static constexpr int HImg   = 128;
static constexpr int WImg   = 128;
static constexpr int HW     = HImg * WImg;   // 16384
static constexpr int BATCH  = 4;
static constexpr int PCHUNK = 256;    // attn contraction chunk
static constexpr int CSPLIT = 12;     // gate conv channel splits (16 ch each)
static constexpr int DWCHUNK = 4;     // dw y-blocks per channel image (32 rows each)

typedef __attribute__((ext_vector_type(8))) short short8;
typedef __attribute__((ext_vector_type(4))) float f32x4;
typedef __attribute__((ext_vector_type(4))) unsigned short ushort4v;
typedef __attribute__((ext_vector_type(8))) unsigned short ushort8v;

template<typename T> __device__ inline float tof(T v);
template<> __device__ inline float tof<float>(float v){ return v; }
template<> __device__ inline float tof<bf16>(bf16 v){ return __bfloat162float(v); }

template<typename T> __device__ inline T fromf(float v);
template<> __device__ inline float fromf<float>(float v){ return v; }
template<> __device__ inline bf16  fromf<bf16>(float v){ return __float2bfloat16(v); }

__device__ inline unsigned short f2bf_bits(float f){
    bf16 h = __float2bfloat16(f);
    return *reinterpret_cast<unsigned short*>(&h);
}
__device__ inline float bfbits2f(unsigned short u){
    union { unsigned int i; float f; } c; c.i = ((unsigned int)u) << 16; return c.f;
}

__device__ inline float gelu_exact(float x){
    return 0.5f * x * (1.0f + erff(x * 0.70710678118654752440f));
}

// load 4 consecutive elems as float
__device__ inline void load4f(const float* p, float* f){
    f32x4 v = *reinterpret_cast<const f32x4*>(p);
    f[0]=v[0]; f[1]=v[1]; f[2]=v[2]; f[3]=v[3];
}
__device__ inline void load4f(const bf16* p, float* f){
    ushort4v v = *reinterpret_cast<const ushort4v*>(p);
    f[0]=bfbits2f(v[0]); f[1]=bfbits2f(v[1]); f[2]=bfbits2f(v[2]); f[3]=bfbits2f(v[3]);
}

// async global(16B) -> LDS
__device__ __forceinline__ void gload16(const bf16* g, bf16* l){
    __builtin_amdgcn_global_load_lds(
        (const __attribute__((address_space(1))) void*)g,
        (__attribute__((address_space(3))) void*)l, 16, 0, 0);
}

// ---------------- merged f32 -> bf16 weight convert --------------------------
__global__ __launch_bounds__(256) void convw_kernel(
    const float* __restrict__ w_qkv, const float* __restrict__ w_proj,
    const float* __restrict__ w_fc1, const float* __restrict__ w_fc2,
    bf16* __restrict__ wq, bf16* __restrict__ wp,
    bf16* __restrict__ wf1, bf16* __restrict__ wf2)
{
    int i = blockIdx.x * 256 + threadIdx.x;
    const int n0 = 576*192, n1 = n0 + 192*192, n2 = n1 + 384*192, n3 = n2 + 192*384;
    if (i < n0)      wq[i]       = fromf<bf16>(w_qkv[i]);
    else if (i < n1) wp[i - n0]  = fromf<bf16>(w_proj[i - n0]);
    else if (i < n2) wf1[i - n1] = fromf<bf16>(w_fc1[i - n1]);
    else if (i < n3) wf2[i - n2] = fromf<bf16>(w_fc2[i - n2]);
}

// ---------------- fused LayerNorm (+optional bf16 [C][HW] copy) + transpose --
template<typename T, bool WRES>
__global__ __launch_bounds__(256) void ln_fused_kernel(
    const T* __restrict__ in, const float* __restrict__ g,
    const float* __restrict__ b, bf16* __restrict__ resF, bf16* __restrict__ outT)
{
    int z = blockIdx.y, p0 = blockIdx.x * 64;
    __shared__ float tile[CDIM][65];
    __shared__ float sred[4][64], s2red[4][64];
    __shared__ float mrow[64], rrow[64];
    const T* ib = in + (size_t)z * CDIM * HW + p0;
    int tid = threadIdx.x;
    for (int j = tid; j < CDIM * 16; j += 256){
        int c = j >> 4, p4 = (j & 15) * 4;
        float f[4];
        load4f(ib + (size_t)c * HW + p4, f);
        tile[c][p4]   = f[0]; tile[c][p4+1] = f[1];
        tile[c][p4+2] = f[2]; tile[c][p4+3] = f[3];
    }
    __syncthreads();
    int p = tid & 63, q = tid >> 6;
    float s = 0.f, s2 = 0.f;
    #pragma unroll 4
    for (int c = q * 48; c < q * 48 + 48; ++c){
        float v = tile[c][p]; s += v; s2 += v * v;
    }
    sred[q][p] = s; s2red[q][p] = s2;
    __syncthreads();
    if (tid < 64){
        float ts = sred[0][tid] + sred[1][tid] + sred[2][tid] + sred[3][tid];
        float t2 = s2red[0][tid] + s2red[1][tid] + s2red[2][tid] + s2red[3][tid];
        float mean = ts * (1.0f / CDIM);
        float var  = t2 * (1.0f / CDIM) - mean * mean;
        mrow[tid] = mean;
        rrow[tid] = rsqrtf(var + 1e-5f);
    }
    __syncthreads();
    unsigned short* oT = (unsigned short*)(outT + ((size_t)z * HW + p0) * CDIM);
    for (int j = tid; j < 64 * 48; j += 256){
        int pr = j / 48, c4 = (j % 48) * 4;
        float m = mrow[pr], r = rrow[pr];
        ushort4v o;
        #pragma unroll
        for (int k = 0; k < 4; ++k){
            int c = c4 + k;
            o[k] = f2bf_bits((tile[c][pr] - m) * r * g[c] + b[c]);
        }
        *(ushort4v*)&oT[(size_t)pr * CDIM + c4] = o;
    }
    if (WRES){
        unsigned short* oF = (unsigned short*)resF + (size_t)z * CDIM * HW + p0;
        for (int j = tid; j < CDIM * 16; j += 256){
            int c = j >> 4, p4 = (j & 15) * 4;
            float gg = g[c], bb = b[c];
            ushort4v v;
            #pragma unroll
            for (int k = 0; k < 4; ++k)
                v[k] = f2bf_bits((tile[c][p4 + k] - mrow[p4 + k]) * rrow[p4 + k] * gg + bb);
            *(ushort4v*)&oF[(size_t)c * HW + p4] = v;
        }
    }
}

// ---------------- MFMA GEMM: C[M,N] = Wb[M,K] @ XT[N,K]^T, batched -----------
// Round-8 structure (proven local optimum): 64m x 128n block, 2x2 waves
// (32m x 64n each), single-buffered LDS staging via global_load_lds,
// vmcnt(0)+syncthreads per K-tile. LDS 24 KB -> high occupancy (~35%).
// EPI: 0 = bf16 out [M][HW]; 1 = bf16 out + bf16 residual; 2 = bias+gelu bf16;
//      3 = bias+gelu -> transposed bf16 out [HW][M]
template<int EPI>
__global__ __launch_bounds__(256) void gemm_mfma_kernel(
    const bf16* __restrict__ Wb, const bf16* __restrict__ XT,
    void* __restrict__ Cout, const float* __restrict__ bias,
    const bf16* __restrict__ res, int M, int K)
{
    __shared__ bf16 smem[12288];              // A: 64x64 (4096), B: 128x64 (8192)
    bf16* Als = smem;
    bf16* Bls = smem + 4096;
    int z  = blockIdx.z;
    int n0 = blockIdx.x * 128;
    int m0 = blockIdx.y * 64;
    const bf16* Xb = XT + (size_t)z * (size_t)HW * K;
    int tid  = threadIdx.x;
    int lane = tid & 63, wid = tid >> 6;
    int wm = wid & 1, wn = wid >> 1;          // 2x2 waves, each 32m x 64n
    int r16 = lane & 15, grp = lane >> 4;

    f32x4 acc[2][4];
    #pragma unroll
    for (int i = 0; i < 2; ++i)
        #pragma unroll
        for (int j = 0; j < 4; ++j){ f32x4 zz = {0.f,0.f,0.f,0.f}; acc[i][j] = zz; }

    int nkt = K >> 6;
    for (int kt = 0; kt < nkt; ++kt){
        #pragma unroll
        for (int i = 0; i < 2; ++i){
            int s = i * 256 + tid;
            int row = s >> 3, ch = s & 7;
            gload16(Wb + (size_t)(m0 + row) * K + kt * 64 + ((ch ^ (row & 7)) * 8),
                    Als + s * 8);
        }
        #pragma unroll
        for (int i = 0; i < 4; ++i){
            int s = i * 256 + tid;
            int row = s >> 3, ch = s & 7;
            gload16(Xb + (size_t)(n0 + row) * K + kt * 64 + ((ch ^ (row & 7)) * 8),
                    Bls + s * 8);
        }
        asm volatile("s_waitcnt vmcnt(0)" ::: "memory");
        __syncthreads();
        #pragma unroll
        for (int ks = 0; ks < 2; ++ks){
            int kel = ks * 32 + grp * 8;
            short8 a[2], b[4];
            #pragma unroll
            for (int fi = 0; fi < 2; ++fi){
                int row = wm * 32 + fi * 16 + r16;
                a[fi] = *reinterpret_cast<const short8*>(Als + row * 64 + (kel ^ ((row & 7) * 8)));
            }
            #pragma unroll
            for (int fj = 0; fj < 4; ++fj){
                int row = wn * 64 + fj * 16 + r16;
                b[fj] = *reinterpret_cast<const short8*>(Bls + row * 64 + (kel ^ ((row & 7) * 8)));
            }
            #pragma unroll
            for (int fi = 0; fi < 2; ++fi)
                #pragma unroll
                for (int fj = 0; fj < 4; ++fj)
                    acc[fi][fj] = __builtin_amdgcn_mfma_f32_16x16x32_bf16(
                        a[fi], b[fj], acc[fi][fj], 0, 0, 0);
        }
        __syncthreads();
    }

    if (EPI == 3){
        // transposed bf16 out via LDS T[n(128)][m(64)] stride 72
        unsigned short* T = (unsigned short*)smem;
        #pragma unroll
        for (int fi = 0; fi < 2; ++fi)
            #pragma unroll
            for (int fj = 0; fj < 4; ++fj){
                int nl = wn * 64 + fj * 16 + r16;
                int mb = wm * 32 + fi * 16 + grp * 4;
                #pragma unroll
                for (int rr = 0; rr < 4; ++rr){
                    float v = gelu_exact(acc[fi][fj][rr] + bias[m0 + mb + rr]);
                    T[nl * 72 + mb + rr] = f2bf_bits(v);
                }
            }
        __syncthreads();
        bf16* Y = (bf16*)Cout;
        int rrow = tid >> 1, half = tid & 1;
        const short8* srcv = reinterpret_cast<const short8*>(T + rrow * 72 + half * 32);
        short8* dstv = reinterpret_cast<short8*>(
            Y + ((size_t)z * HW + n0 + rrow) * M + m0 + half * 32);
        #pragma unroll
        for (int i = 0; i < 4; ++i) dstv[i] = srcv[i];
        return;
    }

    // [M][HW] epilogues via LDS T[m(64)][n(128)] stride 136, 16B stores
    {
        unsigned short* T = (unsigned short*)smem;
        #pragma unroll
        for (int fi = 0; fi < 2; ++fi)
            #pragma unroll
            for (int fj = 0; fj < 4; ++fj){
                int m = wm * 32 + fi * 16 + grp * 4;
                int n = wn * 64 + fj * 16 + r16;
                #pragma unroll
                for (int rr = 0; rr < 4; ++rr)
                    T[(m + rr) * 136 + n] = f2bf_bits(acc[fi][fj][rr]);
            }
        __syncthreads();
        int row = tid >> 2, c8 = (tid & 3) * 8;      // 64 rows x 4 chunk-slots
        bf16* Cb = (bf16*)Cout;
        size_t gbase = (size_t)z * M * HW + (size_t)(m0 + row) * HW + n0 + c8;
        float bv = (EPI == 2) ? bias[m0 + row] : 0.f;
        #pragma unroll
        for (int j = 0; j < 4; ++j){
            int coff = j * 32;
            ushort8v t8 = *(const ushort8v*)&T[row * 136 + c8 + coff];
            ushort8v o8;
            if (EPI == 0){
                o8 = t8;
            } else if (EPI == 1){
                ushort8v r8 = *(const ushort8v*)((const unsigned short*)res + gbase + coff);
                #pragma unroll
                for (int k = 0; k < 8; ++k)
                    o8[k] = f2bf_bits(bfbits2f(t8[k]) + bfbits2f(r8[k]));
            } else {
                #pragma unroll
                for (int k = 0; k < 8; ++k)
                    o8[k] = f2bf_bits(gelu_exact(bfbits2f(t8[k]) + bv));
            }
            *(ushort8v*)((unsigned short*)Cb + gbase + coff) = o8;
        }
    }
}

// ---------------- depthwise 3x3: 2 rows x 8 px per thread + q/k sumsq --------
__global__ __launch_bounds__(256) void dw_kernel(
    const bf16* __restrict__ in, const float* __restrict__ wdw,
    bf16* __restrict__ out, float* __restrict__ sqp)
{
    int ch = blockIdx.y, z = blockIdx.z;
    int tid = threadIdx.x;
    int rp = tid >> 4;                          // 16 row-pairs per block
    int xx = (tid & 15) * 8;                    // 16 lanes per image row
    int y0 = blockIdx.x * 32 + rp * 2;          // first output row
    const unsigned short* p =
        (const unsigned short*)(in + ((size_t)z * 3 * CDIM + ch) * HW);
    float w[9];
    #pragma unroll
    for (int t = 0; t < 9; ++t) w[t] = wdw[ch * 9 + t];
    float f[4][8], lf[4], rf[4];
    #pragma unroll
    for (int r = 0; r < 4; ++r){
        int iy = y0 - 1 + r;
        if (iy >= 0 && iy < HImg){
            ushort8v v8 = *(const ushort8v*)(p + iy * WImg + xx);
            #pragma unroll
            for (int j = 0; j < 8; ++j) f[r][j] = bfbits2f(v8[j]);
        } else {
            #pragma unroll
            for (int j = 0; j < 8; ++j) f[r][j] = 0.f;
        }
        float l = __shfl_up(f[r][7], 1);
        float rr_ = __shfl_down(f[r][0], 1);
        lf[r] = (xx == 0) ? 0.f : l;
        rf[r] = (xx + 8 >= WImg) ? 0.f : rr_;
    }
    float sq = 0.f;
    unsigned short* ob = (unsigned short*)(out + ((size_t)z * 3 * CDIM + ch) * HW);
    #pragma unroll
    for (int orow = 0; orow < 2; ++orow){
        ushort8v o8;
        #pragma unroll
        for (int j = 0; j < 8; ++j){
            float a = 0.f;
            #pragma unroll
            for (int dy = 0; dy < 3; ++dy){
                int r = orow + dy;
                float e0 = (j == 0) ? lf[r] : f[r][j - 1];
                float e2 = (j == 7) ? rf[r] : f[r][j + 1];
                a = fmaf(w[dy*3], e0, fmaf(w[dy*3+1], f[r][j], fmaf(w[dy*3+2], e2, a)));
            }
            o8[j] = f2bf_bits(a);
            sq = fmaf(a, a, sq);
        }
        *(ushort8v*)(ob + (y0 + orow) * WImg + xx) = o8;
    }
    if (ch < 2 * CDIM){
        #pragma unroll
        for (int m = 1; m < 64; m <<= 1) sq += __shfl_xor(sq, m, 64);
        __shared__ float red[4];
        if ((tid & 63) == 0) red[tid >> 6] = sq;
        __syncthreads();
        if (tid == 0)
            sqp[((size_t)ch * BATCH + z) * DWCHUNK + blockIdx.x] =
                red[0] + red[1] + red[2] + red[3];
    }
}

// ---------------- attn partials (inline l2-inv from sqp) ---------------------
__global__ __launch_bounds__(256) void attn_qk_kernel(
    const bf16* __restrict__ qkv, const float* __restrict__ sqp,
    const float* __restrict__ temp, float* __restrict__ part)
{
    int chunk = blockIdx.x;
    int h = blockIdx.y, z = blockIdx.z;
    __shared__ unsigned short qs[CP][PCHUNK + 4];
    __shared__ unsigned short ks[CP][PCHUNK + 4];
    __shared__ float invqs[CP], invks[CP];
    int tid = threadIdx.x;
    if (tid < 2 * CP){
        int which = tid >> 5, cc = tid & 31;
        int ch = which * CDIM + h * CP + cc;
        const float* sp = &sqp[((size_t)ch * BATCH + z) * DWCHUNK];
        float s = sp[0] + sp[1] + sp[2] + sp[3];
        float inv = 1.0f / fmaxf(sqrtf(s), 1e-12f);
        (which ? invks : invqs)[cc] = inv;
    }
    int n0 = chunk * PCHUNK;
    const unsigned short* qb = (const unsigned short*)(qkv + ((size_t)z * 3 * CDIM + h * CP) * HW);
    const unsigned short* kb = (const unsigned short*)(qkv + ((size_t)z * 3 * CDIM + CDIM + h * CP) * HW);
    for (int i = tid; i < CP * (PCHUNK / 4); i += 256){
        int r = i >> 6, p4 = i & 63;
        *(ushort4v*)&qs[r][p4 * 4] = *(const ushort4v*)&qb[(size_t)r * HW + n0 + p4 * 4];
        *(ushort4v*)&ks[r][p4 * 4] = *(const ushort4v*)&kb[(size_t)r * HW + n0 + p4 * 4];
    }
    __syncthreads();
    int c  = tid >> 3;
    int d0 = (tid & 7) * 4;
    float acc[4] = {0.f, 0.f, 0.f, 0.f};
    for (int p4 = 0; p4 < PCHUNK / 4; ++p4){
        ushort4v qv = *(const ushort4v*)&qs[c][p4 * 4];
        float qf0 = bfbits2f(qv[0]), qf1 = bfbits2f(qv[1]);
        float qf2 = bfbits2f(qv[2]), qf3 = bfbits2f(qv[3]);
        #pragma unroll
        for (int j = 0; j < 4; ++j){
            ushort4v kv = *(const ushort4v*)&ks[d0 + j][p4 * 4];
            acc[j] = fmaf(qf0, bfbits2f(kv[0]),
                     fmaf(qf1, bfbits2f(kv[1]),
                     fmaf(qf2, bfbits2f(kv[2]),
                     fmaf(qf3, bfbits2f(kv[3]), acc[j]))));
        }
    }
    float sc = invqs[c] * temp[h];
    size_t base = ((size_t)chunk * BATCH * HEADS + (size_t)z * HEADS + h) * CP * CP
                + c * CP + d0;
    #pragma unroll
    for (int j = 0; j < 4; ++j)
        part[base + j] = acc[j] * sc * invks[d0 + j];
}

__global__ __launch_bounds__(256) void attn_reduce_kernel(
    const float* __restrict__ part, float* __restrict__ attn)
{
    int idx = blockIdx.x * 256 + threadIdx.x;
    float s = 0.f;
    for (int ch = 0; ch < HW / PCHUNK; ++ch)
        s += part[(size_t)ch * (BATCH * HEADS * CP * CP) + idx];
    attn[idx] = s;
}

// ---------------- head conv 3x3 + softmax (merged) ---------------------------
__global__ __launch_bounds__(256) void headconv_softmax_kernel(
    const float* __restrict__ attn, const float* __restrict__ wh,
    float* __restrict__ attn2)
{
    int oh = blockIdx.x, z = blockIdx.y;
    __shared__ float wsm[HEADS * 9];
    __shared__ float ain[HEADS][CP * CP];
    __shared__ float aout[CP * CP];
    int tid = threadIdx.x;
    if (tid < HEADS * 9) wsm[tid] = wh[oh * HEADS * 9 + tid];
    for (int i = tid; i < HEADS * CP * CP; i += 256)
        ain[i >> 10][i & 1023] = attn[((size_t)z * HEADS + (i >> 10)) * CP * CP + (i & 1023)];
    __syncthreads();
    for (int idx = tid; idx < CP * CP; idx += 256){
        int i = idx >> 5, j = idx & 31;
        float acc = 0.f;
        #pragma unroll
        for (int ih = 0; ih < HEADS; ++ih){
            #pragma unroll
            for (int dy = 0; dy < 3; ++dy){
                int ii = i + dy - 1;
                if (ii < 0 || ii >= CP) continue;
                #pragma unroll
                for (int dx = 0; dx < 3; ++dx){
                    int jj = j + dx - 1;
                    if (jj < 0 || jj >= CP) continue;
                    acc += wsm[ih * 9 + dy * 3 + dx] * ain[ih][ii * CP + jj];
                }
            }
        }
        aout[idx] = acc;
    }
    __syncthreads();
    int r = tid >> 3, l8 = tid & 7;
    float v[4];
    #pragma unroll
    for (int k = 0; k < 4; ++k) v[k] = aout[r * CP + l8 * 4 + k];
    float mx = fmaxf(fmaxf(v[0], v[1]), fmaxf(v[2], v[3]));
    #pragma unroll
    for (int m = 1; m < 8; m <<= 1) mx = fmaxf(mx, __shfl_xor(mx, m, 64));
    float sum = 0.f;
    #pragma unroll
    for (int k = 0; k < 4; ++k){ v[k] = expf(v[k] - mx); sum += v[k]; }
    #pragma unroll
    for (int m = 1; m < 8; m <<= 1) sum += __shfl_xor(sum, m, 64);
    float rs = 1.0f / sum;
    float* o = attn2 + ((size_t)z * HEADS + oh) * CP * CP + r * CP + l8 * 4;
    #pragma unroll
    for (int k = 0; k < 4; ++k) o[k] = v[k] * rs;
}

// ---------------- out = attn2 @ v -> transposed bf16 [HW][C] -----------------
__global__ __launch_bounds__(256) void av_kernel(
    const float* __restrict__ attn2, const bf16* __restrict__ qkv, bf16* __restrict__ outT)
{
    int h = blockIdx.y, z = blockIdx.z;
    int tid = threadIdx.x;
    __shared__ float As[CP][CP];
    __shared__ unsigned short Vs[CP][PCHUNK];
    __shared__ unsigned short ot[256][36];
    for (int i = tid; i < CP * CP; i += 256)
        As[i >> 5][i & 31] = attn2[((size_t)(z * HEADS + h)) * CP * CP + i];
    int n0 = blockIdx.x * 256;
    const unsigned short* vb =
        (const unsigned short*)(qkv + ((size_t)z * 3 * CDIM + 2 * CDIM + h * CP) * HW) + n0;
    for (int i = tid; i < CP * 64; i += 256){
        int d = i >> 6, p4 = (i & 63) * 4;
        *(ushort4v*)&Vs[d][p4] = *(const ushort4v*)(vb + (size_t)d * HW + p4);
    }
    __syncthreads();
    float vreg[CP];
    #pragma unroll
    for (int d = 0; d < CP; ++d) vreg[d] = bfbits2f(Vs[d][tid]);
    for (int c = 0; c < CP; ++c){
        float acc = 0.f;
        #pragma unroll
        for (int d = 0; d < CP; ++d) acc = fmaf(As[c][d], vreg[d], acc);
        ot[tid][c] = f2bf_bits(acc);
    }
    __syncthreads();
    unsigned short* ob = (unsigned short*)outT
        + ((size_t)z * HW + (size_t)n0) * CDIM + h * CP;
    for (int j = tid; j < 256 * 8; j += 256){
        int row = j >> 3, q4 = (j & 7) * 4;
        *(ushort4v*)&ob[(size_t)row * CDIM + q4] = *(ushort4v*)&ot[row][q4];
    }
}

// ---------------- spatial gate partials (16 ch/block, 8 px/thread, bf16 out) -
__global__ __launch_bounds__(256) void gate_partial_kernel(
    const bf16* __restrict__ y, const float* __restrict__ wsa,
    bf16* __restrict__ part_g)
{
    int cs = blockIdx.y, z = blockIdx.z;
    __shared__ float wsm[16 * 9];
    if (threadIdx.x < 144) wsm[threadIdx.x] = wsa[cs * 144 + threadIdx.x];
    __syncthreads();
    int idx = blockIdx.x * 2048 + threadIdx.x * 8;
    int yy = idx >> 7, xx = idx & 127;
    const unsigned short* yb =
        (const unsigned short*)(y + (size_t)z * CDIM * HW + (size_t)cs * 16 * HW);
    float acc[8] = {0.f,0.f,0.f,0.f,0.f,0.f,0.f,0.f};
    for (int c = 0; c < 16; ++c){
        const unsigned short* pc = yb + (size_t)c * HW;
        #pragma unroll
        for (int dy = 0; dy < 3; ++dy){
            int iy = yy + dy - 1;
            float f[8], lf, rf;
            if (iy >= 0 && iy < HImg){
                ushort8v v8 = *(const ushort8v*)(pc + iy * WImg + xx);
                #pragma unroll
                for (int j = 0; j < 8; ++j) f[j] = bfbits2f(v8[j]);
            } else {
                #pragma unroll
                for (int j = 0; j < 8; ++j) f[j] = 0.f;
            }
            float l = __shfl_up(f[7], 1);
            float r = __shfl_down(f[0], 1);
            lf = (xx == 0) ? 0.f : l;
            rf = (xx + 8 >= WImg) ? 0.f : r;
            const float* wr = &wsm[c * 9 + dy * 3];
            #pragma unroll
            for (int j = 0; j < 8; ++j){
                float e0 = (j == 0) ? lf : f[j - 1];
                float e2 = (j == 7) ? rf : f[j + 1];
                acc[j] = fmaf(wr[0], e0, fmaf(wr[1], f[j], fmaf(wr[2], e2, acc[j])));
            }
        }
    }
    ushort8v o8;
    #pragma unroll
    for (int j = 0; j < 8; ++j) o8[j] = f2bf_bits(acc[j]);
    *(ushort8v*)((unsigned short*)part_g + ((size_t)cs * BATCH + z) * HW + idx) = o8;
}

// ---------------- fused gate-finish + final ----------------------------------
// Each block: (2048-pixel group) x (16-channel group) x batch. Computes gate
// for its 2048 pixels once into LDS, then out = x2 + y2*gate for 16 channels.
__global__ __launch_bounds__(256) void gate_final_kernel(
    const bf16* __restrict__ part_g, const float* __restrict__ bsa,
    const bf16* __restrict__ x2, const bf16* __restrict__ y2,
    float* __restrict__ out)
{
    int pg = blockIdx.x;              // HW/2048 = 8 pixel groups
    int cg = blockIdx.y;              // 12 channel groups of 16
    int z  = blockIdx.z;
    int tid = threadIdx.x;
    int n0 = pg * 2048;
    __shared__ float gl[2048];
    {
        int n = tid * 8;
        float b0 = bsa[0];
        float acc[8];
        #pragma unroll
        for (int j = 0; j < 8; ++j) acc[j] = b0;
        #pragma unroll
        for (int cs = 0; cs < CSPLIT; ++cs){
            ushort8v v = *(const ushort8v*)((const unsigned short*)part_g
                          + ((size_t)cs * BATCH + z) * HW + n0 + n);
            #pragma unroll
            for (int j = 0; j < 8; ++j) acc[j] += bfbits2f(v[j]);
        }
        #pragma unroll
        for (int j = 0; j < 8; ++j)
            gl[n + j] = 1.0f / (1.0f + expf(-acc[j]));
    }
    __syncthreads();
    int n8 = tid * 8;
    #pragma unroll
    for (int c = 0; c < 16; ++c){
        int cc = cg * 16 + c;
        size_t base = ((size_t)z * CDIM + cc) * HW + n0 + n8;
        ushort8v a8 = *(const ushort8v*)((const unsigned short*)x2 + base);
        ushort8v b8 = *(const ushort8v*)((const unsigned short*)y2 + base);
        f32x4 o0, o1;
        #pragma unroll
        for (int j = 0; j < 4; ++j){
            o0[j] = bfbits2f(a8[j])     + bfbits2f(b8[j])     * gl[n8 + j];
            o1[j] = bfbits2f(a8[j + 4]) + bfbits2f(b8[j + 4]) * gl[n8 + j + 4];
        }
        *(f32x4*)(out + base) = o0;
        *(f32x4*)(out + base + 4) = o1;
    }
}

extern "C" void kernel_launch(void* const* d_in, const int* in_sizes, int n_in,
                              void* d_out, int out_size, void* d_ws, size_t ws_size,
                              hipStream_t stream)
{
    const float* x      = (const float*)d_in[0];
    const float* g1     = (const float*)d_in[1];
    const float* b1     = (const float*)d_in[2];
    const float* w_qkv  = (const float*)d_in[3];
    const float* w_dw   = (const float*)d_in[4];
    const float* temp   = (const float*)d_in[5];
    const float* w_head = (const float*)d_in[6];
    const float* w_proj = (const float*)d_in[7];
    const float* g2     = (const float*)d_in[8];
    const float* b2     = (const float*)d_in[9];
    const float* w_fc1  = (const float*)d_in[10];
    const float* b_fc1  = (const float*)d_in[11];
    const float* w_fc2  = (const float*)d_in[12];
    const float* b_fc2  = (const float*)d_in[13];
    const float* w_sa   = (const float*)d_in[14];
    const float* b_sa   = (const float*)d_in[15];
    float* out = (float*)d_out;

    char* ws = (char*)d_ws;
    const size_t FULL = (size_t)BATCH * CDIM * HW;      // 12.58M elems

    // R0 (FULL*2 B): x1 bf16 [C][HW] -> y2 bf16 [C][HW]
    bf16* x1 = (bf16*)ws;
    bf16* y2 = x1;
    // R1 (3*FULL*2 B): qkvA bf16 -> attn_outT bf16 / ln2T bf16 / y1T bf16
    char* R1 = ws + FULL * 2;
    bf16*  qkvA      = (bf16*)R1;
    bf16*  attn_outT = (bf16*)R1;
    bf16*  ln2T      = (bf16*)R1;
    bf16*  y1T       = (bf16*)(R1 + FULL * 2);
    // R2 (3*FULL*2 B): x1T bf16 -> dwB bf16 -> x2 bf16
    char* R2 = R1 + FULL * 3 * 2;
    bf16*  x1T = (bf16*)R2;
    bf16*  dwB = (bf16*)R2;
    bf16*  x2  = (bf16*)R2;
    // small region
    char* SM = R2 + FULL * 3 * 2;
    float* attn   = (float*)SM;                             // B*HEADS*CP*CP
    float* attn2  = attn + BATCH * HEADS * CP * CP;
    float* gate   = attn2 + BATCH * HEADS * CP * CP;        // (unused slot)
    float* sqp    = gate + BATCH * HW;                      // 2*CDIM*B*DWCHUNK
    float* part   = sqp + 2 * CDIM * BATCH * DWCHUNK;       // 64*B*H*CP*CP (6.3MB)
    bf16*  part_g = (bf16*)part;                            // aliases part (dead)
    bf16* wq_b  = (bf16*)(part + (HW / PCHUNK) * BATCH * HEADS * CP * CP);
    bf16* wp_b  = wq_b  + 576 * 192;
    bf16* wf1_b = wp_b  + 192 * 192;
    bf16* wf2_b = wf1_b + 384 * 192;

    dim3 blk(256);

    // 0. merged weight conversion to bf16
    convw_kernel<<<dim3((294912 + 255) / 256), blk, 0, stream>>>(
        w_qkv, w_proj, w_fc1, w_fc2, wq_b, wp_b, wf1_b, wf2_b);
    // 1. LayerNorm1 fused: x -> x1 (bf16 [C][HW] residual) + x1T (bf16 [HW][C])
    ln_fused_kernel<float, true><<<dim3(HW / 64, BATCH), blk, 0, stream>>>(
        x, g1, b1, x1, x1T);
    // 2. qkv GEMM -> bf16 [3C][HW]
    gemm_mfma_kernel<0><<<dim3(HW / 128, (3 * CDIM) / 64, BATCH), blk, 0, stream>>>(
        wq_b, x1T, qkvA, nullptr, nullptr, 3 * CDIM, CDIM);
    // 3. depthwise 3x3 (2 rows x 8 px per thread) + q/k sumsq partials
    dw_kernel<<<dim3(DWCHUNK, 3 * CDIM, BATCH), blk, 0, stream>>>(qkvA, w_dw, dwB, sqp);
    // 4. attn partial dot-products (inline l2-inv)
    attn_qk_kernel<<<dim3(HW / PCHUNK, HEADS, BATCH), blk, 0, stream>>>(
        dwB, sqp, temp, part);
    // 5. deterministic reduction of partials
    attn_reduce_kernel<<<dim3((BATCH * HEADS * CP * CP) / 256), blk, 0, stream>>>(part, attn);
    // 6. head conv + softmax (merged)
    headconv_softmax_kernel<<<dim3(HEADS, BATCH), blk, 0, stream>>>(attn, w_head, attn2);
    // 7. out = attn @ v -> bf16 [HW][C] (pre-transposed for proj)
    av_kernel<<<dim3(HW / 256, HEADS, BATCH), blk, 0, stream>>>(attn2, dwB, attn_outT);
    // 8. proj GEMM + residual(x1 bf16) -> x2 bf16 [C][HW]
    gemm_mfma_kernel<1><<<dim3(HW / 128, CDIM / 64, BATCH), blk, 0, stream>>>(
        wp_b, attn_outT, x2, nullptr, x1, CDIM, CDIM);
    // 9. LayerNorm2 fused (bf16 in) -> ln2T bf16 [HW][C]
    ln_fused_kernel<bf16, false><<<dim3(HW / 64, BATCH), blk, 0, stream>>>(
        x2, g2, b2, nullptr, ln2T);
    // 10. fc1 GEMM + bias + gelu -> y1T bf16 [HW][HIDDEN]
    gemm_mfma_kernel<3><<<dim3(HW / 128, HIDDEN / 64, BATCH), blk, 0, stream>>>(
        wf1_b, ln2T, y1T, b_fc1, nullptr, HIDDEN, CDIM);
    // 11. fc2 GEMM + bias + gelu -> y2 bf16 [C][HW]
    gemm_mfma_kernel<2><<<dim3(HW / 128, CDIM / 64, BATCH), blk, 0, stream>>>(
        wf2_b, y1T, y2, b_fc2, nullptr, CDIM, HIDDEN);
    // 12. spatial gate: channel-split partials (bf16 out)
    gate_partial_kernel<<<dim3(HW / 2048, CSPLIT, BATCH), blk, 0, stream>>>(
        y2, w_sa, part_g);
    // 13. fused gate-finish + final: out = x2 + y2*sigmoid(sum(part_g)+b)
    gate_final_kernel<<<dim3(HW / 2048, CDIM / 16, BATCH), blk, 0, stream>>>(
        part_g, b_sa, x2, y2, out);
}

// Round 14
// 268.326 us; speedup vs baseline: 1.1598x; 1.0594x over previous
//
#include <hip/hip_runtime.h>
#include <hip/hip_bf16.h>
#include <math.h>

using bf16 = __hip_bfloat16;

static constexpr int CDIM   = 192;
static constexpr int HEADS  = 6;
static constexpr int CP     = 32;     // CDIM / HEADS
static constexpr int HIDDEN = 384;
static constexpr int HImg   = 128;
static constexpr int WImg   = 128;
static constexpr int HW     = HImg * WImg;   // 16384
static constexpr int BATCH  = 4;
static constexpr int PCHUNK = 256;    // attn contraction chunk
static constexpr int CSPLIT = 12;     // gate conv channel splits (16 ch each)
static constexpr int DWCHUNK = 4;     // dw y-blocks per channel image (32 rows each)

typedef __attribute__((ext_vector_type(8))) short short8;
typedef __attribute__((ext_vector_type(4))) float f32x4;
typedef __attribute__((ext_vector_type(16))) float f32x16;
typedef __attribute__((ext_vector_type(4))) unsigned short ushort4v;
typedef __attribute__((ext_vector_type(8))) unsigned short ushort8v;

template<typename T> __device__ inline float tof(T v);
template<> __device__ inline float tof<float>(float v){ return v; }
template<> __device__ inline float tof<bf16>(bf16 v){ return __bfloat162float(v); }

template<typename T> __device__ inline T fromf(float v);
template<> __device__ inline float fromf<float>(float v){ return v; }
template<> __device__ inline bf16  fromf<bf16>(float v){ return __float2bfloat16(v); }

__device__ inline unsigned short f2bf_bits(float f){
    bf16 h = __float2bfloat16(f);
    return *reinterpret_cast<unsigned short*>(&h);
}
__device__ inline float bfbits2f(unsigned short u){
    union { unsigned int i; float f; } c; c.i = ((unsigned int)u) << 16; return c.f;
}

__device__ inline float gelu_exact(float x){
    return 0.5f * x * (1.0f + erff(x * 0.70710678118654752440f));
}

// load 4 consecutive elems as float
__device__ inline void load4f(const float* p, float* f){
    f32x4 v = *reinterpret_cast<const f32x4*>(p);
    f[0]=v[0]; f[1]=v[1]; f[2]=v[2]; f[3]=v[3];
}
__device__ inline void load4f(const bf16* p, float* f){
    ushort4v v = *reinterpret_cast<const ushort4v*>(p);
    f[0]=bfbits2f(v[0]); f[1]=bfbits2f(v[1]); f[2]=bfbits2f(v[2]); f[3]=bfbits2f(v[3]);
}

// async global(16B) -> LDS
__device__ __forceinline__ void gload16(const bf16* g, bf16* l){
    __builtin_amdgcn_global_load_lds(
        (const __attribute__((address_space(1))) void*)g,
        (__attribute__((address_space(3))) void*)l, 16, 0, 0);
}

// ---------------- merged f32 -> bf16 weight convert --------------------------
__global__ __launch_bounds__(256) void convw_kernel(
    const float* __restrict__ w_qkv, const float* __restrict__ w_proj,
    const float* __restrict__ w_fc1, const float* __restrict__ w_fc2,
    bf16* __restrict__ wq, bf16* __restrict__ wp,
    bf16* __restrict__ wf1, bf16* __restrict__ wf2)
{
    int i = blockIdx.x * 256 + threadIdx.x;
    const int n0 = 576*192, n1 = n0 + 192*192, n2 = n1 + 384*192, n3 = n2 + 192*384;
    if (i < n0)      wq[i]       = fromf<bf16>(w_qkv[i]);
    else if (i < n1) wp[i - n0]  = fromf<bf16>(w_proj[i - n0]);
    else if (i < n2) wf1[i - n1] = fromf<bf16>(w_fc1[i - n1]);
    else if (i < n3) wf2[i - n2] = fromf<bf16>(w_fc2[i - n2]);
}

// ---------------- fused LayerNorm (+optional bf16 [C][HW] copy) + transpose --
template<typename T, bool WRES>
__global__ __launch_bounds__(256) void ln_fused_kernel(
    const T* __restrict__ in, const float* __restrict__ g,
    const float* __restrict__ b, bf16* __restrict__ resF, bf16* __restrict__ outT)
{
    int z = blockIdx.y, p0 = blockIdx.x * 64;
    __shared__ float tile[CDIM][65];
    __shared__ float sred[4][64], s2red[4][64];
    __shared__ float mrow[64], rrow[64];
    const T* ib = in + (size_t)z * CDIM * HW + p0;
    int tid = threadIdx.x;
    for (int j = tid; j < CDIM * 16; j += 256){
        int c = j >> 4, p4 = (j & 15) * 4;
        float f[4];
        load4f(ib + (size_t)c * HW + p4, f);
        tile[c][p4]   = f[0]; tile[c][p4+1] = f[1];
        tile[c][p4+2] = f[2]; tile[c][p4+3] = f[3];
    }
    __syncthreads();
    int p = tid & 63, q = tid >> 6;
    float s = 0.f, s2 = 0.f;
    #pragma unroll 4
    for (int c = q * 48; c < q * 48 + 48; ++c){
        float v = tile[c][p]; s += v; s2 += v * v;
    }
    sred[q][p] = s; s2red[q][p] = s2;
    __syncthreads();
    if (tid < 64){
        float ts = sred[0][tid] + sred[1][tid] + sred[2][tid] + sred[3][tid];
        float t2 = s2red[0][tid] + s2red[1][tid] + s2red[2][tid] + s2red[3][tid];
        float mean = ts * (1.0f / CDIM);
        float var  = t2 * (1.0f / CDIM) - mean * mean;
        mrow[tid] = mean;
        rrow[tid] = rsqrtf(var + 1e-5f);
    }
    __syncthreads();
    unsigned short* oT = (unsigned short*)(outT + ((size_t)z * HW + p0) * CDIM);
    for (int j = tid; j < 64 * 48; j += 256){
        int pr = j / 48, c4 = (j % 48) * 4;
        float m = mrow[pr], r = rrow[pr];
        ushort4v o;
        #pragma unroll
        for (int k = 0; k < 4; ++k){
            int c = c4 + k;
            o[k] = f2bf_bits((tile[c][pr] - m) * r * g[c] + b[c]);
        }
        *(ushort4v*)&oT[(size_t)pr * CDIM + c4] = o;
    }
    if (WRES){
        unsigned short* oF = (unsigned short*)resF + (size_t)z * CDIM * HW + p0;
        for (int j = tid; j < CDIM * 16; j += 256){
            int c = j >> 4, p4 = (j & 15) * 4;
            float gg = g[c], bb = b[c];
            ushort4v v;
            #pragma unroll
            for (int k = 0; k < 4; ++k)
                v[k] = f2bf_bits((tile[c][p4 + k] - mrow[p4 + k]) * rrow[p4 + k] * gg + bb);
            *(ushort4v*)&oF[(size_t)c * HW + p4] = v;
        }
    }
}

// ---------------- MFMA GEMM: C[M,N] = Wb[M,K] @ XT[N,K]^T, batched -----------
// Round-8 structure (proven local optimum): 64m x 128n block, 2x2 waves
// (32m x 64n each), single-buffered LDS staging via global_load_lds,
// vmcnt(0)+syncthreads per K-tile. LDS 24 KB -> high occupancy (~35%).
// EPI: 0 = bf16 out [M][HW]; 1 = bf16 out + bf16 residual; 2 = bias+gelu bf16;
//      3 = bias+gelu -> transposed bf16 out [HW][M]
template<int EPI>
__global__ __launch_bounds__(256) void gemm_mfma_kernel(
    const bf16* __restrict__ Wb, const bf16* __restrict__ XT,
    void* __restrict__ Cout, const float* __restrict__ bias,
    const bf16* __restrict__ res, int M, int K)
{
    __shared__ bf16 smem[12288];              // A: 64x64 (4096), B: 128x64 (8192)
    bf16* Als = smem;
    bf16* Bls = smem + 4096;
    int z  = blockIdx.z;
    int n0 = blockIdx.x * 128;
    int m0 = blockIdx.y * 64;
    const bf16* Xb = XT + (size_t)z * (size_t)HW * K;
    int tid  = threadIdx.x;
    int lane = tid & 63, wid = tid >> 6;
    int wm = wid & 1, wn = wid >> 1;          // 2x2 waves, each 32m x 64n
    int r16 = lane & 15, grp = lane >> 4;

    f32x4 acc[2][4];
    #pragma unroll
    for (int i = 0; i < 2; ++i)
        #pragma unroll
        for (int j = 0; j < 4; ++j){ f32x4 zz = {0.f,0.f,0.f,0.f}; acc[i][j] = zz; }

    int nkt = K >> 6;
    for (int kt = 0; kt < nkt; ++kt){
        #pragma unroll
        for (int i = 0; i < 2; ++i){
            int s = i * 256 + tid;
            int row = s >> 3, ch = s & 7;
            gload16(Wb + (size_t)(m0 + row) * K + kt * 64 + ((ch ^ (row & 7)) * 8),
                    Als + s * 8);
        }
        #pragma unroll
        for (int i = 0; i < 4; ++i){
            int s = i * 256 + tid;
            int row = s >> 3, ch = s & 7;
            gload16(Xb + (size_t)(n0 + row) * K + kt * 64 + ((ch ^ (row & 7)) * 8),
                    Bls + s * 8);
        }
        asm volatile("s_waitcnt vmcnt(0)" ::: "memory");
        __syncthreads();
        #pragma unroll
        for (int ks = 0; ks < 2; ++ks){
            int kel = ks * 32 + grp * 8;
            short8 a[2], b[4];
            #pragma unroll
            for (int fi = 0; fi < 2; ++fi){
                int row = wm * 32 + fi * 16 + r16;
                a[fi] = *reinterpret_cast<const short8*>(Als + row * 64 + (kel ^ ((row & 7) * 8)));
            }
            #pragma unroll
            for (int fj = 0; fj < 4; ++fj){
                int row = wn * 64 + fj * 16 + r16;
                b[fj] = *reinterpret_cast<const short8*>(Bls + row * 64 + (kel ^ ((row & 7) * 8)));
            }
            #pragma unroll
            for (int fi = 0; fi < 2; ++fi)
                #pragma unroll
                for (int fj = 0; fj < 4; ++fj)
                    acc[fi][fj] = __builtin_amdgcn_mfma_f32_16x16x32_bf16(
                        a[fi], b[fj], acc[fi][fj], 0, 0, 0);
        }
        __syncthreads();
    }

    if (EPI == 3){
        // transposed bf16 out via LDS T[n(128)][m(64)] stride 72
        unsigned short* T = (unsigned short*)smem;
        #pragma unroll
        for (int fi = 0; fi < 2; ++fi)
            #pragma unroll
            for (int fj = 0; fj < 4; ++fj){
                int nl = wn * 64 + fj * 16 + r16;
                int mb = wm * 32 + fi * 16 + grp * 4;
                #pragma unroll
                for (int rr = 0; rr < 4; ++rr){
                    float v = gelu_exact(acc[fi][fj][rr] + bias[m0 + mb + rr]);
                    T[nl * 72 + mb + rr] = f2bf_bits(v);
                }
            }
        __syncthreads();
        bf16* Y = (bf16*)Cout;
        int rrow = tid >> 1, half = tid & 1;
        const short8* srcv = reinterpret_cast<const short8*>(T + rrow * 72 + half * 32);
        short8* dstv = reinterpret_cast<short8*>(
            Y + ((size_t)z * HW + n0 + rrow) * M + m0 + half * 32);
        #pragma unroll
        for (int i = 0; i < 4; ++i) dstv[i] = srcv[i];
        return;
    }

    // [M][HW] epilogues via LDS T[m(64)][n(128)] stride 136, 16B stores
    {
        unsigned short* T = (unsigned short*)smem;
        #pragma unroll
        for (int fi = 0; fi < 2; ++fi)
            #pragma unroll
            for (int fj = 0; fj < 4; ++fj){
                int m = wm * 32 + fi * 16 + grp * 4;
                int n = wn * 64 + fj * 16 + r16;
                #pragma unroll
                for (int rr = 0; rr < 4; ++rr)
                    T[(m + rr) * 136 + n] = f2bf_bits(acc[fi][fj][rr]);
            }
        __syncthreads();
        int row = tid >> 2, c8 = (tid & 3) * 8;      // 64 rows x 4 chunk-slots
        bf16* Cb = (bf16*)Cout;
        size_t gbase = (size_t)z * M * HW + (size_t)(m0 + row) * HW + n0 + c8;
        float bv = (EPI == 2) ? bias[m0 + row] : 0.f;
        #pragma unroll
        for (int j = 0; j < 4; ++j){
            int coff = j * 32;
            ushort8v t8 = *(const ushort8v*)&T[row * 136 + c8 + coff];
            ushort8v o8;
            if (EPI == 0){
                o8 = t8;
            } else if (EPI == 1){
                ushort8v r8 = *(const ushort8v*)((const unsigned short*)res + gbase + coff);
                #pragma unroll
                for (int k = 0; k < 8; ++k)
                    o8[k] = f2bf_bits(bfbits2f(t8[k]) + bfbits2f(r8[k]));
            } else {
                #pragma unroll
                for (int k = 0; k < 8; ++k)
                    o8[k] = f2bf_bits(gelu_exact(bfbits2f(t8[k]) + bv));
            }
            *(ushort8v*)((unsigned short*)Cb + gbase + coff) = o8;
        }
    }
}

// ---------------- depthwise 3x3: 2 rows x 8 px per thread + q/k sumsq --------
__global__ __launch_bounds__(256) void dw_kernel(
    const bf16* __restrict__ in, const float* __restrict__ wdw,
    bf16* __restrict__ out, float* __restrict__ sqp)
{
    int ch = blockIdx.y, z = blockIdx.z;
    int tid = threadIdx.x;
    int rp = tid >> 4;                          // 16 row-pairs per block
    int xx = (tid & 15) * 8;                    // 16 lanes per image row
    int y0 = blockIdx.x * 32 + rp * 2;          // first output row
    const unsigned short* p =
        (const unsigned short*)(in + ((size_t)z * 3 * CDIM + ch) * HW);
    float w[9];
    #pragma unroll
    for (int t = 0; t < 9; ++t) w[t] = wdw[ch * 9 + t];
    float f[4][8], lf[4], rf[4];
    #pragma unroll
    for (int r = 0; r < 4; ++r){
        int iy = y0 - 1 + r;
        if (iy >= 0 && iy < HImg){
            ushort8v v8 = *(const ushort8v*)(p + iy * WImg + xx);
            #pragma unroll
            for (int j = 0; j < 8; ++j) f[r][j] = bfbits2f(v8[j]);
        } else {
            #pragma unroll
            for (int j = 0; j < 8; ++j) f[r][j] = 0.f;
        }
        float l = __shfl_up(f[r][7], 1);
        float rr_ = __shfl_down(f[r][0], 1);
        lf[r] = (xx == 0) ? 0.f : l;
        rf[r] = (xx + 8 >= WImg) ? 0.f : rr_;
    }
    float sq = 0.f;
    unsigned short* ob = (unsigned short*)(out + ((size_t)z * 3 * CDIM + ch) * HW);
    #pragma unroll
    for (int orow = 0; orow < 2; ++orow){
        ushort8v o8;
        #pragma unroll
        for (int j = 0; j < 8; ++j){
            float a = 0.f;
            #pragma unroll
            for (int dy = 0; dy < 3; ++dy){
                int r = orow + dy;
                float e0 = (j == 0) ? lf[r] : f[r][j - 1];
                float e2 = (j == 7) ? rf[r] : f[r][j + 1];
                a = fmaf(w[dy*3], e0, fmaf(w[dy*3+1], f[r][j], fmaf(w[dy*3+2], e2, a)));
            }
            o8[j] = f2bf_bits(a);
            sq = fmaf(a, a, sq);
        }
        *(ushort8v*)(ob + (y0 + orow) * WImg + xx) = o8;
    }
    if (ch < 2 * CDIM){
        #pragma unroll
        for (int m = 1; m < 64; m <<= 1) sq += __shfl_xor(sq, m, 64);
        __shared__ float red[4];
        if ((tid & 63) == 0) red[tid >> 6] = sq;
        __syncthreads();
        if (tid == 0)
            sqp[((size_t)ch * BATCH + z) * DWCHUNK + blockIdx.x] =
                red[0] + red[1] + red[2] + red[3];
    }
}

// ---------------- attn partials via MFMA 32x32x16 ----------------------------
// Per block: one (chunk, h, z). Q,K staged to LDS (stride 264, 16B-aligned
// fragment reads). Each of 4 waves contracts 64 pixels = 4 MFMAs into a
// 32x32 f32 acc; cross-wave reduce via LDS (aliased over staging); scale by
// invq*temp*invk; write one partial per chunk (attn_reduce unchanged).
__global__ __launch_bounds__(256) void attn_qk_kernel(
    const bf16* __restrict__ qkv, const float* __restrict__ sqp,
    const float* __restrict__ temp, float* __restrict__ part)
{
    int chunk = blockIdx.x;
    int h = blockIdx.y, z = blockIdx.z;
    __shared__ unsigned short stg[2 * 32 * 264];   // 33 KB; aliased as red after
    float* red = (float*)stg;                      // 4*32*32 f32 = 16 KB
    __shared__ float invqs[CP], invks[CP];
    int tid = threadIdx.x;
    if (tid < 2 * CP){
        int which = tid >> 5, cc = tid & 31;
        int ch = which * CDIM + h * CP + cc;
        const float* sp = &sqp[((size_t)ch * BATCH + z) * DWCHUNK];
        float s = sp[0] + sp[1] + sp[2] + sp[3];
        float inv = 1.0f / fmaxf(sqrtf(s), 1e-12f);
        (which ? invks : invqs)[cc] = inv;
    }
    int n0 = chunk * PCHUNK;
    const unsigned short* qb = (const unsigned short*)(qkv + ((size_t)z * 3 * CDIM + h * CP) * HW);
    const unsigned short* kb = (const unsigned short*)(qkv + ((size_t)z * 3 * CDIM + CDIM + h * CP) * HW);
    for (int i = tid; i < CP * (PCHUNK / 4); i += 256){
        int r = i >> 6, p4 = (i & 63) * 4;
        *(ushort4v*)&stg[r * 264 + p4] =
            *(const ushort4v*)&qb[(size_t)r * HW + n0 + p4];
        *(ushort4v*)&stg[32 * 264 + r * 264 + p4] =
            *(const ushort4v*)&kb[(size_t)r * HW + n0 + p4];
    }
    __syncthreads();
    int wv = tid >> 6, lane = tid & 63;
    int row = lane & 31, koff = (lane >> 5) * 8;
    f32x16 acc;
    #pragma unroll
    for (int r = 0; r < 16; ++r) acc[r] = 0.f;
    int pxb = wv * 64;
    #pragma unroll
    for (int i = 0; i < 4; ++i){
        short8 a = *(const short8*)&stg[row * 264 + pxb + i * 16 + koff];
        short8 b = *(const short8*)&stg[32 * 264 + row * 264 + pxb + i * 16 + koff];
        acc = __builtin_amdgcn_mfma_f32_32x32x16_bf16(a, b, acc, 0, 0, 0);
    }
    __syncthreads();          // all staging reads done before aliasing as red
    #pragma unroll
    for (int r = 0; r < 16; ++r){
        int ro = (r & 3) + 8 * (r >> 2) + 4 * (lane >> 5);   // verified C/D map
        red[(wv * 32 + ro) * 32 + (lane & 31)] = acc[r];
    }
    __syncthreads();
    int c  = tid >> 3;
    int d0 = (tid & 7) * 4;
    float sc = invqs[c] * temp[h];
    size_t base = ((size_t)chunk * BATCH * HEADS + (size_t)z * HEADS + h) * CP * CP
                + c * CP + d0;
    #pragma unroll
    for (int j = 0; j < 4; ++j){
        int d = d0 + j;
        float s = red[(0 * 32 + c) * 32 + d] + red[(1 * 32 + c) * 32 + d]
                + red[(2 * 32 + c) * 32 + d] + red[(3 * 32 + c) * 32 + d];
        part[base + j] = s * sc * invks[d];
    }
}

__global__ __launch_bounds__(256) void attn_reduce_kernel(
    const float* __restrict__ part, float* __restrict__ attn)
{
    int idx = blockIdx.x * 256 + threadIdx.x;
    float s = 0.f;
    for (int ch = 0; ch < HW / PCHUNK; ++ch)
        s += part[(size_t)ch * (BATCH * HEADS * CP * CP) + idx];
    attn[idx] = s;
}

// ---------------- head conv 3x3 + softmax (merged) ---------------------------
__global__ __launch_bounds__(256) void headconv_softmax_kernel(
    const float* __restrict__ attn, const float* __restrict__ wh,
    float* __restrict__ attn2)
{
    int oh = blockIdx.x, z = blockIdx.y;
    __shared__ float wsm[HEADS * 9];
    __shared__ float ain[HEADS][CP * CP];
    __shared__ float aout[CP * CP];
    int tid = threadIdx.x;
    if (tid < HEADS * 9) wsm[tid] = wh[oh * HEADS * 9 + tid];
    for (int i = tid; i < HEADS * CP * CP; i += 256)
        ain[i >> 10][i & 1023] = attn[((size_t)z * HEADS + (i >> 10)) * CP * CP + (i & 1023)];
    __syncthreads();
    for (int idx = tid; idx < CP * CP; idx += 256){
        int i = idx >> 5, j = idx & 31;
        float acc = 0.f;
        #pragma unroll
        for (int ih = 0; ih < HEADS; ++ih){
            #pragma unroll
            for (int dy = 0; dy < 3; ++dy){
                int ii = i + dy - 1;
                if (ii < 0 || ii >= CP) continue;
                #pragma unroll
                for (int dx = 0; dx < 3; ++dx){
                    int jj = j + dx - 1;
                    if (jj < 0 || jj >= CP) continue;
                    acc += wsm[ih * 9 + dy * 3 + dx] * ain[ih][ii * CP + jj];
                }
            }
        }
        aout[idx] = acc;
    }
    __syncthreads();
    int r = tid >> 3, l8 = tid & 7;
    float v[4];
    #pragma unroll
    for (int k = 0; k < 4; ++k) v[k] = aout[r * CP + l8 * 4 + k];
    float mx = fmaxf(fmaxf(v[0], v[1]), fmaxf(v[2], v[3]));
    #pragma unroll
    for (int m = 1; m < 8; m <<= 1) mx = fmaxf(mx, __shfl_xor(mx, m, 64));
    float sum = 0.f;
    #pragma unroll
    for (int k = 0; k < 4; ++k){ v[k] = expf(v[k] - mx); sum += v[k]; }
    #pragma unroll
    for (int m = 1; m < 8; m <<= 1) sum += __shfl_xor(sum, m, 64);
    float rs = 1.0f / sum;
    float* o = attn2 + ((size_t)z * HEADS + oh) * CP * CP + r * CP + l8 * 4;
    #pragma unroll
    for (int k = 0; k < 4; ++k) o[k] = v[k] * rs;
}

// ---------------- out = attn2 @ v -> transposed bf16 [HW][C] -----------------
__global__ __launch_bounds__(256) void av_kernel(
    const float* __restrict__ attn2, const bf16* __restrict__ qkv, bf16* __restrict__ outT)
{
    int h = blockIdx.y, z = blockIdx.z;
    int tid = threadIdx.x;
    __shared__ float As[CP][CP];
    __shared__ unsigned short Vs[CP][PCHUNK];
    __shared__ unsigned short ot[256][36];
    for (int i = tid; i < CP * CP; i += 256)
        As[i >> 5][i & 31] = attn2[((size_t)(z * HEADS + h)) * CP * CP + i];
    int n0 = blockIdx.x * 256;
    const unsigned short* vb =
        (const unsigned short*)(qkv + ((size_t)z * 3 * CDIM + 2 * CDIM + h * CP) * HW) + n0;
    for (int i = tid; i < CP * 64; i += 256){
        int d = i >> 6, p4 = (i & 63) * 4;
        *(ushort4v*)&Vs[d][p4] = *(const ushort4v*)(vb + (size_t)d * HW + p4);
    }
    __syncthreads();
    float vreg[CP];
    #pragma unroll
    for (int d = 0; d < CP; ++d) vreg[d] = bfbits2f(Vs[d][tid]);
    for (int c = 0; c < CP; ++c){
        float acc = 0.f;
        #pragma unroll
        for (int d = 0; d < CP; ++d) acc = fmaf(As[c][d], vreg[d], acc);
        ot[tid][c] = f2bf_bits(acc);
    }
    __syncthreads();
    unsigned short* ob = (unsigned short*)outT
        + ((size_t)z * HW + (size_t)n0) * CDIM + h * CP;
    for (int j = tid; j < 256 * 8; j += 256){
        int row = j >> 3, q4 = (j & 7) * 4;
        *(ushort4v*)&ob[(size_t)row * CDIM + q4] = *(ushort4v*)&ot[row][q4];
    }
}

// ---------------- spatial gate partials (16 ch/block, 8 px/thread, bf16 out) -
__global__ __launch_bounds__(256) void gate_partial_kernel(
    const bf16* __restrict__ y, const float* __restrict__ wsa,
    bf16* __restrict__ part_g)
{
    int cs = blockIdx.y, z = blockIdx.z;
    __shared__ float wsm[16 * 9];
    if (threadIdx.x < 144) wsm[threadIdx.x] = wsa[cs * 144 + threadIdx.x];
    __syncthreads();
    int idx = blockIdx.x * 2048 + threadIdx.x * 8;
    int yy = idx >> 7, xx = idx & 127;
    const unsigned short* yb =
        (const unsigned short*)(y + (size_t)z * CDIM * HW + (size_t)cs * 16 * HW);
    float acc[8] = {0.f,0.f,0.f,0.f,0.f,0.f,0.f,0.f};
    for (int c = 0; c < 16; ++c){
        const unsigned short* pc = yb + (size_t)c * HW;
        #pragma unroll
        for (int dy = 0; dy < 3; ++dy){
            int iy = yy + dy - 1;
            float f[8], lf, rf;
            if (iy >= 0 && iy < HImg){
                ushort8v v8 = *(const ushort8v*)(pc + iy * WImg + xx);
                #pragma unroll
                for (int j = 0; j < 8; ++j) f[j] = bfbits2f(v8[j]);
            } else {
                #pragma unroll
                for (int j = 0; j < 8; ++j) f[j] = 0.f;
            }
            float l = __shfl_up(f[7], 1);
            float r = __shfl_down(f[0], 1);
            lf = (xx == 0) ? 0.f : l;
            rf = (xx + 8 >= WImg) ? 0.f : r;
            const float* wr = &wsm[c * 9 + dy * 3];
            #pragma unroll
            for (int j = 0; j < 8; ++j){
                float e0 = (j == 0) ? lf : f[j - 1];
                float e2 = (j == 7) ? rf : f[j + 1];
                acc[j] = fmaf(wr[0], e0, fmaf(wr[1], f[j], fmaf(wr[2], e2, acc[j])));
            }
        }
    }
    ushort8v o8;
    #pragma unroll
    for (int j = 0; j < 8; ++j) o8[j] = f2bf_bits(acc[j]);
    *(ushort8v*)((unsigned short*)part_g + ((size_t)cs * BATCH + z) * HW + idx) = o8;
}

// ---------------- fused gate-finish + final ----------------------------------
__global__ __launch_bounds__(256) void gate_final_kernel(
    const bf16* __restrict__ part_g, const float* __restrict__ bsa,
    const bf16* __restrict__ x2, const bf16* __restrict__ y2,
    float* __restrict__ out)
{
    int pg = blockIdx.x;              // HW/2048 = 8 pixel groups
    int cg = blockIdx.y;              // 12 channel groups of 16
    int z  = blockIdx.z;
    int tid = threadIdx.x;
    int n0 = pg * 2048;
    __shared__ float gl[2048];
    {
        int n = tid * 8;
        float b0 = bsa[0];
        float acc[8];
        #pragma unroll
        for (int j = 0; j < 8; ++j) acc[j] = b0;
        #pragma unroll
        for (int cs = 0; cs < CSPLIT; ++cs){
            ushort8v v = *(const ushort8v*)((const unsigned short*)part_g
                          + ((size_t)cs * BATCH + z) * HW + n0 + n);
            #pragma unroll
            for (int j = 0; j < 8; ++j) acc[j] += bfbits2f(v[j]);
        }
        #pragma unroll
        for (int j = 0; j < 8; ++j)
            gl[n + j] = 1.0f / (1.0f + expf(-acc[j]));
    }
    __syncthreads();
    int n8 = tid * 8;
    #pragma unroll
    for (int c = 0; c < 16; ++c){
        int cc = cg * 16 + c;
        size_t base = ((size_t)z * CDIM + cc) * HW + n0 + n8;
        ushort8v a8 = *(const ushort8v*)((const unsigned short*)x2 + base);
        ushort8v b8 = *(const ushort8v*)((const unsigned short*)y2 + base);
        f32x4 o0, o1;
        #pragma unroll
        for (int j = 0; j < 4; ++j){
            o0[j] = bfbits2f(a8[j])     + bfbits2f(b8[j])     * gl[n8 + j];
            o1[j] = bfbits2f(a8[j + 4]) + bfbits2f(b8[j + 4]) * gl[n8 + j + 4];
        }
        *(f32x4*)(out + base) = o0;
        *(f32x4*)(out + base + 4) = o1;
    }
}

extern "C" void kernel_launch(void* const* d_in, const int* in_sizes, int n_in,
                              void* d_out, int out_size, void* d_ws, size_t ws_size,
                              hipStream_t stream)
{
    const float* x      = (const float*)d_in[0];
    const float* g1     = (const float*)d_in[1];
    const float* b1     = (const float*)d_in[2];
    const float* w_qkv  = (const float*)d_in[3];
    const float* w_dw   = (const float*)d_in[4];
    const float* temp   = (const float*)d_in[5];
    const float* w_head = (const float*)d_in[6];
    const float* w_proj = (const float*)d_in[7];
    const float* g2     = (const float*)d_in[8];
    const float* b2     = (const float*)d_in[9];
    const float* w_fc1  = (const float*)d_in[10];
    const float* b_fc1  = (const float*)d_in[11];
    const float* w_fc2  = (const float*)d_in[12];
    const float* b_fc2  = (const float*)d_in[13];
    const float* w_sa   = (const float*)d_in[14];
    const float* b_sa   = (const float*)d_in[15];
    float* out = (float*)d_out;

    char* ws = (char*)d_ws;
    const size_t FULL = (size_t)BATCH * CDIM * HW;      // 12.58M elems

    // R0 (FULL*2 B): x1 bf16 [C][HW] -> y2 bf16 [C][HW]
    bf16* x1 = (bf16*)ws;
    bf16* y2 = x1;
    // R1 (3*FULL*2 B): qkvA bf16 -> attn_outT bf16 / ln2T bf16 / y1T bf16
    char* R1 = ws + FULL * 2;
    bf16*  qkvA      = (bf16*)R1;
    bf16*  attn_outT = (bf16*)R1;
    bf16*  ln2T      = (bf16*)R1;
    bf16*  y1T       = (bf16*)(R1 + FULL * 2);
    // R2 (3*FULL*2 B): x1T bf16 -> dwB bf16 -> x2 bf16
    char* R2 = R1 + FULL * 3 * 2;
    bf16*  x1T = (bf16*)R2;
    bf16*  dwB = (bf16*)R2;
    bf16*  x2  = (bf16*)R2;
    // small region
    char* SM = R2 + FULL * 3 * 2;
    float* attn   = (float*)SM;                             // B*HEADS*CP*CP
    float* attn2  = attn + BATCH * HEADS * CP * CP;
    float* gate   = attn2 + BATCH * HEADS * CP * CP;        // (unused slot)
    float* sqp    = gate + BATCH * HW;                      // 2*CDIM*B*DWCHUNK
    float* part   = sqp + 2 * CDIM * BATCH * DWCHUNK;       // 64*B*H*CP*CP (6.3MB)
    bf16*  part_g = (bf16*)part;                            // aliases part (dead)
    bf16* wq_b  = (bf16*)(part + (HW / PCHUNK) * BATCH * HEADS * CP * CP);
    bf16* wp_b  = wq_b  + 576 * 192;
    bf16* wf1_b = wp_b  + 192 * 192;
    bf16* wf2_b = wf1_b + 384 * 192;

    dim3 blk(256);

    // 0. merged weight conversion to bf16
    convw_kernel<<<dim3((294912 + 255) / 256), blk, 0, stream>>>(
        w_qkv, w_proj, w_fc1, w_fc2, wq_b, wp_b, wf1_b, wf2_b);
    // 1. LayerNorm1 fused: x -> x1 (bf16 [C][HW] residual) + x1T (bf16 [HW][C])
    ln_fused_kernel<float, true><<<dim3(HW / 64, BATCH), blk, 0, stream>>>(
        x, g1, b1, x1, x1T);
    // 2. qkv GEMM -> bf16 [3C][HW]
    gemm_mfma_kernel<0><<<dim3(HW / 128, (3 * CDIM) / 64, BATCH), blk, 0, stream>>>(
        wq_b, x1T, qkvA, nullptr, nullptr, 3 * CDIM, CDIM);
    // 3. depthwise 3x3 (2 rows x 8 px per thread) + q/k sumsq partials
    dw_kernel<<<dim3(DWCHUNK, 3 * CDIM, BATCH), blk, 0, stream>>>(qkvA, w_dw, dwB, sqp);
    // 4. attn partials via MFMA (inline l2-inv)
    attn_qk_kernel<<<dim3(HW / PCHUNK, HEADS, BATCH), blk, 0, stream>>>(
        dwB, sqp, temp, part);
    // 5. deterministic reduction of partials
    attn_reduce_kernel<<<dim3((BATCH * HEADS * CP * CP) / 256), blk, 0, stream>>>(part, attn);
    // 6. head conv + softmax (merged)
    headconv_softmax_kernel<<<dim3(HEADS, BATCH), blk, 0, stream>>>(attn, w_head, attn2);
    // 7. out = attn @ v -> bf16 [HW][C] (pre-transposed for proj)
    av_kernel<<<dim3(HW / 256, HEADS, BATCH), blk, 0, stream>>>(attn2, dwB, attn_outT);
    // 8. proj GEMM + residual(x1 bf16) -> x2 bf16 [C][HW]
    gemm_mfma_kernel<1><<<dim3(HW / 128, CDIM / 64, BATCH), blk, 0, stream>>>(
        wp_b, attn_outT, x2, nullptr, x1, CDIM, CDIM);
    // 9. LayerNorm2 fused (bf16 in) -> ln2T bf16 [HW][C]
    ln_fused_kernel<bf16, false><<<dim3(HW / 64, BATCH), blk, 0, stream>>>(
        x2, g2, b2, nullptr, ln2T);
    // 10. fc1 GEMM + bias + gelu -> y1T bf16 [HW][HIDDEN]
    gemm_mfma_kernel<3><<<dim3(HW / 128, HIDDEN / 64, BATCH), blk, 0, stream>>>(
        wf1_b, ln2T, y1T, b_fc1, nullptr, HIDDEN, CDIM);
    // 11. fc2 GEMM + bias + gelu -> y2 bf16 [C][HW]
    gemm_mfma_kernel<2><<<dim3(HW / 128, CDIM / 64, BATCH), blk, 0, stream>>>(
        wf2_b, y1T, y2, b_fc2, nullptr, CDIM, HIDDEN);
    // 12. spatial gate: channel-split partials (bf16 out)
    gate_partial_kernel<<<dim3(HW / 2048, CSPLIT, BATCH), blk, 0, stream>>>(
        y2, w_sa, part_g);
    // 13. fused gate-finish + final: out = x2 + y2*sigmoid(sum(part_g)+b)
    gate_final_kernel<<<dim3(HW / 2048, CDIM / 16, BATCH), blk, 0, stream>>>(
        part_g, b_sa, x2, y2, out);
}

// Round 15
// 258.442 us; speedup vs baseline: 1.2042x; 1.0382x over previous
//
#include <hip/hip_runtime.h>
#include <hip/hip_bf16.h>
#include <math.h>

using bf16 = __hip_bfloat16;

static constexpr int CDIM   = 192;
static constexpr int HEADS  = 6;
static constexpr int CP     = 32;     // CDIM / HEADS
static constexpr int HIDDEN = 384;
static constexpr int HImg   = 128;
static constexpr int WImg   = 128;
static constexpr int HW     = HImg * WImg;   // 16384
static constexpr int BATCH  = 4;
static constexpr int PCHUNK = 256;    // attn contraction chunk
static constexpr int CSPLIT = 12;     // gate conv channel splits (16 ch each)
static constexpr int DWCHUNK = 4;     // dw y-blocks per channel image (32 rows each)

typedef __attribute__((ext_vector_type(8))) short short8;
typedef __attribute__((ext_vector_type(4))) float f32x4;
typedef __attribute__((ext_vector_type(16))) float f32x16;
typedef __attribute__((ext_vector_type(4))) unsigned short ushort4v;
typedef __attribute__((ext_vector_type(8))) unsigned short ushort8v;

template<typename T> __device__ inline float tof(T v);
template<> __device__ inline float tof<float>(float v){ return v; }
template<> __device__ inline float tof<bf16>(bf16 v){ return __bfloat162float(v); }

template<typename T> __device__ inline T fromf(float v);
template<> __device__ inline float fromf<float>(float v){ return v; }
template<> __device__ inline bf16  fromf<bf16>(float v){ return __float2bfloat16(v); }

__device__ inline unsigned short f2bf_bits(float f){
    bf16 h = __float2bfloat16(f);
    return *reinterpret_cast<unsigned short*>(&h);
}
__device__ inline float bfbits2f(unsigned short u){
    union { unsigned int i; float f; } c; c.i = ((unsigned int)u) << 16; return c.f;
}

__device__ inline float gelu_exact(float x){
    return 0.5f * x * (1.0f + erff(x * 0.70710678118654752440f));
}

// load 4 consecutive elems as float
__device__ inline void load4f(const float* p, float* f){
    f32x4 v = *reinterpret_cast<const f32x4*>(p);
    f[0]=v[0]; f[1]=v[1]; f[2]=v[2]; f[3]=v[3];
}
__device__ inline void load4f(const bf16* p, float* f){
    ushort4v v = *reinterpret_cast<const ushort4v*>(p);
    f[0]=bfbits2f(v[0]); f[1]=bfbits2f(v[1]); f[2]=bfbits2f(v[2]); f[3]=bfbits2f(v[3]);
}

// async global(16B) -> LDS
__device__ __forceinline__ void gload16(const bf16* g, bf16* l){
    __builtin_amdgcn_global_load_lds(
        (const __attribute__((address_space(1))) void*)g,
        (__attribute__((address_space(3))) void*)l, 16, 0, 0);
}

// ---------------- merged f32 -> bf16 weight convert --------------------------
__global__ __launch_bounds__(256) void convw_kernel(
    const float* __restrict__ w_qkv, const float* __restrict__ w_proj,
    const float* __restrict__ w_fc1, const float* __restrict__ w_fc2,
    bf16* __restrict__ wq, bf16* __restrict__ wp,
    bf16* __restrict__ wf1, bf16* __restrict__ wf2)
{
    int i = blockIdx.x * 256 + threadIdx.x;
    const int n0 = 576*192, n1 = n0 + 192*192, n2 = n1 + 384*192, n3 = n2 + 192*384;
    if (i < n0)      wq[i]       = fromf<bf16>(w_qkv[i]);
    else if (i < n1) wp[i - n0]  = fromf<bf16>(w_proj[i - n0]);
    else if (i < n2) wf1[i - n1] = fromf<bf16>(w_fc1[i - n1]);
    else if (i < n3) wf2[i - n2] = fromf<bf16>(w_fc2[i - n2]);
}

// ---------------- fused LayerNorm (+optional bf16 [C][HW] copy) + transpose --
template<typename T, bool WRES>
__global__ __launch_bounds__(256) void ln_fused_kernel(
    const T* __restrict__ in, const float* __restrict__ g,
    const float* __restrict__ b, bf16* __restrict__ resF, bf16* __restrict__ outT)
{
    int z = blockIdx.y, p0 = blockIdx.x * 64;
    __shared__ float tile[CDIM][65];
    __shared__ float sred[4][64], s2red[4][64];
    __shared__ float mrow[64], rrow[64];
    const T* ib = in + (size_t)z * CDIM * HW + p0;
    int tid = threadIdx.x;
    for (int j = tid; j < CDIM * 16; j += 256){
        int c = j >> 4, p4 = (j & 15) * 4;
        float f[4];
        load4f(ib + (size_t)c * HW + p4, f);
        tile[c][p4]   = f[0]; tile[c][p4+1] = f[1];
        tile[c][p4+2] = f[2]; tile[c][p4+3] = f[3];
    }
    __syncthreads();
    int p = tid & 63, q = tid >> 6;
    float s = 0.f, s2 = 0.f;
    #pragma unroll 4
    for (int c = q * 48; c < q * 48 + 48; ++c){
        float v = tile[c][p]; s += v; s2 += v * v;
    }
    sred[q][p] = s; s2red[q][p] = s2;
    __syncthreads();
    if (tid < 64){
        float ts = sred[0][tid] + sred[1][tid] + sred[2][tid] + sred[3][tid];
        float t2 = s2red[0][tid] + s2red[1][tid] + s2red[2][tid] + s2red[3][tid];
        float mean = ts * (1.0f / CDIM);
        float var  = t2 * (1.0f / CDIM) - mean * mean;
        mrow[tid] = mean;
        rrow[tid] = rsqrtf(var + 1e-5f);
    }
    __syncthreads();
    unsigned short* oT = (unsigned short*)(outT + ((size_t)z * HW + p0) * CDIM);
    for (int j = tid; j < 64 * 48; j += 256){
        int pr = j / 48, c4 = (j % 48) * 4;
        float m = mrow[pr], r = rrow[pr];
        ushort4v o;
        #pragma unroll
        for (int k = 0; k < 4; ++k){
            int c = c4 + k;
            o[k] = f2bf_bits((tile[c][pr] - m) * r * g[c] + b[c]);
        }
        *(ushort4v*)&oT[(size_t)pr * CDIM + c4] = o;
    }
    if (WRES){
        unsigned short* oF = (unsigned short*)resF + (size_t)z * CDIM * HW + p0;
        for (int j = tid; j < CDIM * 16; j += 256){
            int c = j >> 4, p4 = (j & 15) * 4;
            float gg = g[c], bb = b[c];
            ushort4v v;
            #pragma unroll
            for (int k = 0; k < 4; ++k)
                v[k] = f2bf_bits((tile[c][p4 + k] - mrow[p4 + k]) * rrow[p4 + k] * gg + bb);
            *(ushort4v*)&oF[(size_t)c * HW + p4] = v;
        }
    }
}

// ---------------- MFMA GEMM: C[M,N] = Wb[M,K] @ XT[N,K]^T, batched -----------
// Round-8 structure (proven local optimum): 64m x 128n block, 2x2 waves
// (32m x 64n each), single-buffered LDS staging via global_load_lds,
// vmcnt(0)+syncthreads per K-tile. LDS 24 KB -> high occupancy (~35%).
// EPI: 0 = bf16 out [M][HW]; 1 = bf16 out + bf16 residual; 2 = bias+gelu bf16;
//      3 = bias+gelu -> transposed bf16 out [HW][M]
template<int EPI>
__global__ __launch_bounds__(256) void gemm_mfma_kernel(
    const bf16* __restrict__ Wb, const bf16* __restrict__ XT,
    void* __restrict__ Cout, const float* __restrict__ bias,
    const bf16* __restrict__ res, int M, int K)
{
    __shared__ bf16 smem[12288];              // A: 64x64 (4096), B: 128x64 (8192)
    bf16* Als = smem;
    bf16* Bls = smem + 4096;
    int z  = blockIdx.z;
    int n0 = blockIdx.x * 128;
    int m0 = blockIdx.y * 64;
    const bf16* Xb = XT + (size_t)z * (size_t)HW * K;
    int tid  = threadIdx.x;
    int lane = tid & 63, wid = tid >> 6;
    int wm = wid & 1, wn = wid >> 1;          // 2x2 waves, each 32m x 64n
    int r16 = lane & 15, grp = lane >> 4;

    f32x4 acc[2][4];
    #pragma unroll
    for (int i = 0; i < 2; ++i)
        #pragma unroll
        for (int j = 0; j < 4; ++j){ f32x4 zz = {0.f,0.f,0.f,0.f}; acc[i][j] = zz; }

    int nkt = K >> 6;
    for (int kt = 0; kt < nkt; ++kt){
        #pragma unroll
        for (int i = 0; i < 2; ++i){
            int s = i * 256 + tid;
            int row = s >> 3, ch = s & 7;
            gload16(Wb + (size_t)(m0 + row) * K + kt * 64 + ((ch ^ (row & 7)) * 8),
                    Als + s * 8);
        }
        #pragma unroll
        for (int i = 0; i < 4; ++i){
            int s = i * 256 + tid;
            int row = s >> 3, ch = s & 7;
            gload16(Xb + (size_t)(n0 + row) * K + kt * 64 + ((ch ^ (row & 7)) * 8),
                    Bls + s * 8);
        }
        asm volatile("s_waitcnt vmcnt(0)" ::: "memory");
        __syncthreads();
        #pragma unroll
        for (int ks = 0; ks < 2; ++ks){
            int kel = ks * 32 + grp * 8;
            short8 a[2], b[4];
            #pragma unroll
            for (int fi = 0; fi < 2; ++fi){
                int row = wm * 32 + fi * 16 + r16;
                a[fi] = *reinterpret_cast<const short8*>(Als + row * 64 + (kel ^ ((row & 7) * 8)));
            }
            #pragma unroll
            for (int fj = 0; fj < 4; ++fj){
                int row = wn * 64 + fj * 16 + r16;
                b[fj] = *reinterpret_cast<const short8*>(Bls + row * 64 + (kel ^ ((row & 7) * 8)));
            }
            #pragma unroll
            for (int fi = 0; fi < 2; ++fi)
                #pragma unroll
                for (int fj = 0; fj < 4; ++fj)
                    acc[fi][fj] = __builtin_amdgcn_mfma_f32_16x16x32_bf16(
                        a[fi], b[fj], acc[fi][fj], 0, 0, 0);
        }
        __syncthreads();
    }

    if (EPI == 3){
        // transposed bf16 out via LDS T[n(128)][m(64)] stride 72
        unsigned short* T = (unsigned short*)smem;
        #pragma unroll
        for (int fi = 0; fi < 2; ++fi)
            #pragma unroll
            for (int fj = 0; fj < 4; ++fj){
                int nl = wn * 64 + fj * 16 + r16;
                int mb = wm * 32 + fi * 16 + grp * 4;
                #pragma unroll
                for (int rr = 0; rr < 4; ++rr){
                    float v = gelu_exact(acc[fi][fj][rr] + bias[m0 + mb + rr]);
                    T[nl * 72 + mb + rr] = f2bf_bits(v);
                }
            }
        __syncthreads();
        bf16* Y = (bf16*)Cout;
        int rrow = tid >> 1, half = tid & 1;
        const short8* srcv = reinterpret_cast<const short8*>(T + rrow * 72 + half * 32);
        short8* dstv = reinterpret_cast<short8*>(
            Y + ((size_t)z * HW + n0 + rrow) * M + m0 + half * 32);
        #pragma unroll
        for (int i = 0; i < 4; ++i) dstv[i] = srcv[i];
        return;
    }

    // [M][HW] epilogues via LDS T[m(64)][n(128)] stride 136, 16B stores
    {
        unsigned short* T = (unsigned short*)smem;
        #pragma unroll
        for (int fi = 0; fi < 2; ++fi)
            #pragma unroll
            for (int fj = 0; fj < 4; ++fj){
                int m = wm * 32 + fi * 16 + grp * 4;
                int n = wn * 64 + fj * 16 + r16;
                #pragma unroll
                for (int rr = 0; rr < 4; ++rr)
                    T[(m + rr) * 136 + n] = f2bf_bits(acc[fi][fj][rr]);
            }
        __syncthreads();
        int row = tid >> 2, c8 = (tid & 3) * 8;      // 64 rows x 4 chunk-slots
        bf16* Cb = (bf16*)Cout;
        size_t gbase = (size_t)z * M * HW + (size_t)(m0 + row) * HW + n0 + c8;
        float bv = (EPI == 2) ? bias[m0 + row] : 0.f;
        #pragma unroll
        for (int j = 0; j < 4; ++j){
            int coff = j * 32;
            ushort8v t8 = *(const ushort8v*)&T[row * 136 + c8 + coff];
            ushort8v o8;
            if (EPI == 0){
                o8 = t8;
            } else if (EPI == 1){
                ushort8v r8 = *(const ushort8v*)((const unsigned short*)res + gbase + coff);
                #pragma unroll
                for (int k = 0; k < 8; ++k)
                    o8[k] = f2bf_bits(bfbits2f(t8[k]) + bfbits2f(r8[k]));
            } else {
                #pragma unroll
                for (int k = 0; k < 8; ++k)
                    o8[k] = f2bf_bits(gelu_exact(bfbits2f(t8[k]) + bv));
            }
            *(ushort8v*)((unsigned short*)Cb + gbase + coff) = o8;
        }
    }
}

// ---------------- depthwise 3x3: 2 rows x 8 px per thread + q/k sumsq --------
__global__ __launch_bounds__(256) void dw_kernel(
    const bf16* __restrict__ in, const float* __restrict__ wdw,
    bf16* __restrict__ out, float* __restrict__ sqp)
{
    int ch = blockIdx.y, z = blockIdx.z;
    int tid = threadIdx.x;
    int rp = tid >> 4;                          // 16 row-pairs per block
    int xx = (tid & 15) * 8;                    // 16 lanes per image row
    int y0 = blockIdx.x * 32 + rp * 2;          // first output row
    const unsigned short* p =
        (const unsigned short*)(in + ((size_t)z * 3 * CDIM + ch) * HW);
    float w[9];
    #pragma unroll
    for (int t = 0; t < 9; ++t) w[t] = wdw[ch * 9 + t];
    float f[4][8], lf[4], rf[4];
    #pragma unroll
    for (int r = 0; r < 4; ++r){
        int iy = y0 - 1 + r;
        if (iy >= 0 && iy < HImg){
            ushort8v v8 = *(const ushort8v*)(p + iy * WImg + xx);
            #pragma unroll
            for (int j = 0; j < 8; ++j) f[r][j] = bfbits2f(v8[j]);
        } else {
            #pragma unroll
            for (int j = 0; j < 8; ++j) f[r][j] = 0.f;
        }
        float l = __shfl_up(f[r][7], 1);
        float rr_ = __shfl_down(f[r][0], 1);
        lf[r] = (xx == 0) ? 0.f : l;
        rf[r] = (xx + 8 >= WImg) ? 0.f : rr_;
    }
    float sq = 0.f;
    unsigned short* ob = (unsigned short*)(out + ((size_t)z * 3 * CDIM + ch) * HW);
    #pragma unroll
    for (int orow = 0; orow < 2; ++orow){
        ushort8v o8;
        #pragma unroll
        for (int j = 0; j < 8; ++j){
            float a = 0.f;
            #pragma unroll
            for (int dy = 0; dy < 3; ++dy){
                int r = orow + dy;
                float e0 = (j == 0) ? lf[r] : f[r][j - 1];
                float e2 = (j == 7) ? rf[r] : f[r][j + 1];
                a = fmaf(w[dy*3], e0, fmaf(w[dy*3+1], f[r][j], fmaf(w[dy*3+2], e2, a)));
            }
            o8[j] = f2bf_bits(a);
            sq = fmaf(a, a, sq);
        }
        *(ushort8v*)(ob + (y0 + orow) * WImg + xx) = o8;
    }
    if (ch < 2 * CDIM){
        #pragma unroll
        for (int m = 1; m < 64; m <<= 1) sq += __shfl_xor(sq, m, 64);
        __shared__ float red[4];
        if ((tid & 63) == 0) red[tid >> 6] = sq;
        __syncthreads();
        if (tid == 0)
            sqp[((size_t)ch * BATCH + z) * DWCHUNK + blockIdx.x] =
                red[0] + red[1] + red[2] + red[3];
    }
}

// ---------------- attn partials via MFMA 32x32x16 ----------------------------
__global__ __launch_bounds__(256) void attn_qk_kernel(
    const bf16* __restrict__ qkv, const float* __restrict__ sqp,
    const float* __restrict__ temp, float* __restrict__ part)
{
    int chunk = blockIdx.x;
    int h = blockIdx.y, z = blockIdx.z;
    __shared__ unsigned short stg[2 * 32 * 264];   // 33 KB; aliased as red after
    float* red = (float*)stg;                      // 4*32*32 f32 = 16 KB
    __shared__ float invqs[CP], invks[CP];
    int tid = threadIdx.x;
    if (tid < 2 * CP){
        int which = tid >> 5, cc = tid & 31;
        int ch = which * CDIM + h * CP + cc;
        const float* sp = &sqp[((size_t)ch * BATCH + z) * DWCHUNK];
        float s = sp[0] + sp[1] + sp[2] + sp[3];
        float inv = 1.0f / fmaxf(sqrtf(s), 1e-12f);
        (which ? invks : invqs)[cc] = inv;
    }
    int n0 = chunk * PCHUNK;
    const unsigned short* qb = (const unsigned short*)(qkv + ((size_t)z * 3 * CDIM + h * CP) * HW);
    const unsigned short* kb = (const unsigned short*)(qkv + ((size_t)z * 3 * CDIM + CDIM + h * CP) * HW);
    for (int i = tid; i < CP * (PCHUNK / 4); i += 256){
        int r = i >> 6, p4 = (i & 63) * 4;
        *(ushort4v*)&stg[r * 264 + p4] =
            *(const ushort4v*)&qb[(size_t)r * HW + n0 + p4];
        *(ushort4v*)&stg[32 * 264 + r * 264 + p4] =
            *(const ushort4v*)&kb[(size_t)r * HW + n0 + p4];
    }
    __syncthreads();
    int wv = tid >> 6, lane = tid & 63;
    int row = lane & 31, koff = (lane >> 5) * 8;
    f32x16 acc;
    #pragma unroll
    for (int r = 0; r < 16; ++r) acc[r] = 0.f;
    int pxb = wv * 64;
    #pragma unroll
    for (int i = 0; i < 4; ++i){
        short8 a = *(const short8*)&stg[row * 264 + pxb + i * 16 + koff];
        short8 b = *(const short8*)&stg[32 * 264 + row * 264 + pxb + i * 16 + koff];
        acc = __builtin_amdgcn_mfma_f32_32x32x16_bf16(a, b, acc, 0, 0, 0);
    }
    __syncthreads();          // all staging reads done before aliasing as red
    #pragma unroll
    for (int r = 0; r < 16; ++r){
        int ro = (r & 3) + 8 * (r >> 2) + 4 * (lane >> 5);   // verified C/D map
        red[(wv * 32 + ro) * 32 + (lane & 31)] = acc[r];
    }
    __syncthreads();
    int c  = tid >> 3;
    int d0 = (tid & 7) * 4;
    float sc = invqs[c] * temp[h];
    size_t base = ((size_t)chunk * BATCH * HEADS + (size_t)z * HEADS + h) * CP * CP
                + c * CP + d0;
    #pragma unroll
    for (int j = 0; j < 4; ++j){
        int d = d0 + j;
        float s = red[(0 * 32 + c) * 32 + d] + red[(1 * 32 + c) * 32 + d]
                + red[(2 * 32 + c) * 32 + d] + red[(3 * 32 + c) * 32 + d];
        part[base + j] = s * sc * invks[d];
    }
}

__global__ __launch_bounds__(256) void attn_reduce_kernel(
    const float* __restrict__ part, float* __restrict__ attn)
{
    int idx = blockIdx.x * 256 + threadIdx.x;
    float s = 0.f;
    for (int ch = 0; ch < HW / PCHUNK; ++ch)
        s += part[(size_t)ch * (BATCH * HEADS * CP * CP) + idx];
    attn[idx] = s;
}

// ---------------- head conv 3x3 + softmax (merged) ---------------------------
__global__ __launch_bounds__(256) void headconv_softmax_kernel(
    const float* __restrict__ attn, const float* __restrict__ wh,
    float* __restrict__ attn2)
{
    int oh = blockIdx.x, z = blockIdx.y;
    __shared__ float wsm[HEADS * 9];
    __shared__ float ain[HEADS][CP * CP];
    __shared__ float aout[CP * CP];
    int tid = threadIdx.x;
    if (tid < HEADS * 9) wsm[tid] = wh[oh * HEADS * 9 + tid];
    for (int i = tid; i < HEADS * CP * CP; i += 256)
        ain[i >> 10][i & 1023] = attn[((size_t)z * HEADS + (i >> 10)) * CP * CP + (i & 1023)];
    __syncthreads();
    for (int idx = tid; idx < CP * CP; idx += 256){
        int i = idx >> 5, j = idx & 31;
        float acc = 0.f;
        #pragma unroll
        for (int ih = 0; ih < HEADS; ++ih){
            #pragma unroll
            for (int dy = 0; dy < 3; ++dy){
                int ii = i + dy - 1;
                if (ii < 0 || ii >= CP) continue;
                #pragma unroll
                for (int dx = 0; dx < 3; ++dx){
                    int jj = j + dx - 1;
                    if (jj < 0 || jj >= CP) continue;
                    acc += wsm[ih * 9 + dy * 3 + dx] * ain[ih][ii * CP + jj];
                }
            }
        }
        aout[idx] = acc;
    }
    __syncthreads();
    int r = tid >> 3, l8 = tid & 7;
    float v[4];
    #pragma unroll
    for (int k = 0; k < 4; ++k) v[k] = aout[r * CP + l8 * 4 + k];
    float mx = fmaxf(fmaxf(v[0], v[1]), fmaxf(v[2], v[3]));
    #pragma unroll
    for (int m = 1; m < 8; m <<= 1) mx = fmaxf(mx, __shfl_xor(mx, m, 64));
    float sum = 0.f;
    #pragma unroll
    for (int k = 0; k < 4; ++k){ v[k] = expf(v[k] - mx); sum += v[k]; }
    #pragma unroll
    for (int m = 1; m < 8; m <<= 1) sum += __shfl_xor(sum, m, 64);
    float rs = 1.0f / sum;
    float* o = attn2 + ((size_t)z * HEADS + oh) * CP * CP + r * CP + l8 * 4;
    #pragma unroll
    for (int k = 0; k < 4; ++k) o[k] = v[k] * rs;
}

// ---------------- out = attn2 @ v via MFMA -> transposed bf16 [HW][C] --------
// A (softmax probs) -> bf16 [32][40]; V transposed into Vt[n(256)][d(32)+8].
// Each wave: 2 col-groups x 2 k-halves = 4 MFMAs (32x32x16). ot aliases Vt.
__global__ __launch_bounds__(256) void av_kernel(
    const float* __restrict__ attn2, const bf16* __restrict__ qkv, bf16* __restrict__ outT)
{
    int h = blockIdx.y, z = blockIdx.z;
    int tid = threadIdx.x;
    __shared__ unsigned short Abf[32 * 40];        // 2.5 KB
    __shared__ unsigned short Vt[256 * 40];        // 20 KB; aliased as ot after
    unsigned short* ot = Vt;                       // ot[n*36 + c], 18.4 KB
    const float* ab = attn2 + ((size_t)(z * HEADS + h)) * CP * CP;
    for (int i = tid; i < CP * CP; i += 256)
        Abf[(i >> 5) * 40 + (i & 31)] = f2bf_bits(ab[i]);
    int n0 = blockIdx.x * 256;
    const unsigned short* vb =
        (const unsigned short*)(qkv + ((size_t)z * 3 * CDIM + 2 * CDIM + h * CP) * HW) + n0;
    for (int i = tid; i < CP * 64; i += 256){
        int d = i >> 6, p4 = (i & 63) * 4;
        ushort4v v = *(const ushort4v*)(vb + (size_t)d * HW + p4);
        Vt[(p4 + 0) * 40 + d] = v[0];
        Vt[(p4 + 1) * 40 + d] = v[1];
        Vt[(p4 + 2) * 40 + d] = v[2];
        Vt[(p4 + 3) * 40 + d] = v[3];
    }
    __syncthreads();
    int wv = tid >> 6, lane = tid & 63;
    int rowa = lane & 31, koff = (lane >> 5) * 8;
    f32x16 acc[2];
    #pragma unroll
    for (int g = 0; g < 2; ++g)
        #pragma unroll
        for (int r = 0; r < 16; ++r) acc[g][r] = 0.f;
    #pragma unroll
    for (int kh = 0; kh < 2; ++kh){
        short8 a = *(const short8*)&Abf[rowa * 40 + kh * 16 + koff];
        #pragma unroll
        for (int g = 0; g < 2; ++g){
            int ncol = wv * 64 + g * 32 + (lane & 31);
            short8 b = *(const short8*)&Vt[ncol * 40 + kh * 16 + koff];
            acc[g] = __builtin_amdgcn_mfma_f32_32x32x16_bf16(a, b, acc[g], 0, 0, 0);
        }
    }
    __syncthreads();          // Vt reads complete before aliasing as ot
    #pragma unroll
    for (int g = 0; g < 2; ++g){
        int n = wv * 64 + g * 32 + (lane & 31);
        #pragma unroll
        for (int r = 0; r < 16; ++r){
            int c = (r & 3) + 8 * (r >> 2) + 4 * (lane >> 5);
            ot[n * 36 + c] = f2bf_bits(acc[g][r]);
        }
    }
    __syncthreads();
    unsigned short* ob = (unsigned short*)outT
        + ((size_t)z * HW + (size_t)n0) * CDIM + h * CP;
    for (int j = tid; j < 256 * 8; j += 256){
        int row = j >> 3, q4 = (j & 7) * 4;
        *(ushort4v*)&ob[(size_t)row * CDIM + q4] = *(ushort4v*)&ot[row * 36 + q4];
    }
}

// ---------------- spatial gate partials (16 ch/block, 8 px/thread, bf16 out) -
__global__ __launch_bounds__(256) void gate_partial_kernel(
    const bf16* __restrict__ y, const float* __restrict__ wsa,
    bf16* __restrict__ part_g)
{
    int cs = blockIdx.y, z = blockIdx.z;
    __shared__ float wsm[16 * 9];
    if (threadIdx.x < 144) wsm[threadIdx.x] = wsa[cs * 144 + threadIdx.x];
    __syncthreads();
    int idx = blockIdx.x * 2048 + threadIdx.x * 8;
    int yy = idx >> 7, xx = idx & 127;
    const unsigned short* yb =
        (const unsigned short*)(y + (size_t)z * CDIM * HW + (size_t)cs * 16 * HW);
    float acc[8] = {0.f,0.f,0.f,0.f,0.f,0.f,0.f,0.f};
    for (int c = 0; c < 16; ++c){
        const unsigned short* pc = yb + (size_t)c * HW;
        #pragma unroll
        for (int dy = 0; dy < 3; ++dy){
            int iy = yy + dy - 1;
            float f[8], lf, rf;
            if (iy >= 0 && iy < HImg){
                ushort8v v8 = *(const ushort8v*)(pc + iy * WImg + xx);
                #pragma unroll
                for (int j = 0; j < 8; ++j) f[j] = bfbits2f(v8[j]);
            } else {
                #pragma unroll
                for (int j = 0; j < 8; ++j) f[j] = 0.f;
            }
            float l = __shfl_up(f[7], 1);
            float r = __shfl_down(f[0], 1);
            lf = (xx == 0) ? 0.f : l;
            rf = (xx + 8 >= WImg) ? 0.f : r;
            const float* wr = &wsm[c * 9 + dy * 3];
            #pragma unroll
            for (int j = 0; j < 8; ++j){
                float e0 = (j == 0) ? lf : f[j - 1];
                float e2 = (j == 7) ? rf : f[j + 1];
                acc[j] = fmaf(wr[0], e0, fmaf(wr[1], f[j], fmaf(wr[2], e2, acc[j])));
            }
        }
    }
    ushort8v o8;
    #pragma unroll
    for (int j = 0; j < 8; ++j) o8[j] = f2bf_bits(acc[j]);
    *(ushort8v*)((unsigned short*)part_g + ((size_t)cs * BATCH + z) * HW + idx) = o8;
}

// ---------------- fused gate-finish + final ----------------------------------
__global__ __launch_bounds__(256) void gate_final_kernel(
    const bf16* __restrict__ part_g, const float* __restrict__ bsa,
    const bf16* __restrict__ x2, const bf16* __restrict__ y2,
    float* __restrict__ out)
{
    int pg = blockIdx.x;              // HW/2048 = 8 pixel groups
    int cg = blockIdx.y;              // 12 channel groups of 16
    int z  = blockIdx.z;
    int tid = threadIdx.x;
    int n0 = pg * 2048;
    __shared__ float gl[2048];
    {
        int n = tid * 8;
        float b0 = bsa[0];
        float acc[8];
        #pragma unroll
        for (int j = 0; j < 8; ++j) acc[j] = b0;
        #pragma unroll
        for (int cs = 0; cs < CSPLIT; ++cs){
            ushort8v v = *(const ushort8v*)((const unsigned short*)part_g
                          + ((size_t)cs * BATCH + z) * HW + n0 + n);
            #pragma unroll
            for (int j = 0; j < 8; ++j) acc[j] += bfbits2f(v[j]);
        }
        #pragma unroll
        for (int j = 0; j < 8; ++j)
            gl[n + j] = 1.0f / (1.0f + expf(-acc[j]));
    }
    __syncthreads();
    int n8 = tid * 8;
    #pragma unroll
    for (int c = 0; c < 16; ++c){
        int cc = cg * 16 + c;
        size_t base = ((size_t)z * CDIM + cc) * HW + n0 + n8;
        ushort8v a8 = *(const ushort8v*)((const unsigned short*)x2 + base);
        ushort8v b8 = *(const ushort8v*)((const unsigned short*)y2 + base);
        f32x4 o0, o1;
        #pragma unroll
        for (int j = 0; j < 4; ++j){
            o0[j] = bfbits2f(a8[j])     + bfbits2f(b8[j])     * gl[n8 + j];
            o1[j] = bfbits2f(a8[j + 4]) + bfbits2f(b8[j + 4]) * gl[n8 + j + 4];
        }
        *(f32x4*)(out + base) = o0;
        *(f32x4*)(out + base + 4) = o1;
    }
}

extern "C" void kernel_launch(void* const* d_in, const int* in_sizes, int n_in,
                              void* d_out, int out_size, void* d_ws, size_t ws_size,
                              hipStream_t stream)
{
    const float* x      = (const float*)d_in[0];
    const float* g1     = (const float*)d_in[1];
    const float* b1     = (const float*)d_in[2];
    const float* w_qkv  = (const float*)d_in[3];
    const float* w_dw   = (const float*)d_in[4];
    const float* temp   = (const float*)d_in[5];
    const float* w_head = (const float*)d_in[6];
    const float* w_proj = (const float*)d_in[7];
    const float* g2     = (const float*)d_in[8];
    const float* b2     = (const float*)d_in[9];
    const float* w_fc1  = (const float*)d_in[10];
    const float* b_fc1  = (const float*)d_in[11];
    const float* w_fc2  = (const float*)d_in[12];
    const float* b_fc2  = (const float*)d_in[13];
    const float* w_sa   = (const float*)d_in[14];
    const float* b_sa   = (const float*)d_in[15];
    float* out = (float*)d_out;

    char* ws = (char*)d_ws;
    const size_t FULL = (size_t)BATCH * CDIM * HW;      // 12.58M elems

    // R0 (FULL*2 B): x1 bf16 [C][HW] -> y2 bf16 [C][HW]
    bf16* x1 = (bf16*)ws;
    bf16* y2 = x1;
    // R1 (3*FULL*2 B): qkvA bf16 -> attn_outT bf16 / ln2T bf16 / y1T bf16
    char* R1 = ws + FULL * 2;
    bf16*  qkvA      = (bf16*)R1;
    bf16*  attn_outT = (bf16*)R1;
    bf16*  ln2T      = (bf16*)R1;
    bf16*  y1T       = (bf16*)(R1 + FULL * 2);
    // R2 (3*FULL*2 B): x1T bf16 -> dwB bf16 -> x2 bf16
    char* R2 = R1 + FULL * 3 * 2;
    bf16*  x1T = (bf16*)R2;
    bf16*  dwB = (bf16*)R2;
    bf16*  x2  = (bf16*)R2;
    // small region
    char* SM = R2 + FULL * 3 * 2;
    float* attn   = (float*)SM;                             // B*HEADS*CP*CP
    float* attn2  = attn + BATCH * HEADS * CP * CP;
    float* gate   = attn2 + BATCH * HEADS * CP * CP;        // (unused slot)
    float* sqp    = gate + BATCH * HW;                      // 2*CDIM*B*DWCHUNK
    float* part   = sqp + 2 * CDIM * BATCH * DWCHUNK;       // 64*B*H*CP*CP (6.3MB)
    bf16*  part_g = (bf16*)part;                            // aliases part (dead)
    bf16* wq_b  = (bf16*)(part + (HW / PCHUNK) * BATCH * HEADS * CP * CP);
    bf16* wp_b  = wq_b  + 576 * 192;
    bf16* wf1_b = wp_b  + 192 * 192;
    bf16* wf2_b = wf1_b + 384 * 192;

    dim3 blk(256);

    // 0. merged weight conversion to bf16
    convw_kernel<<<dim3((294912 + 255) / 256), blk, 0, stream>>>(
        w_qkv, w_proj, w_fc1, w_fc2, wq_b, wp_b, wf1_b, wf2_b);
    // 1. LayerNorm1 fused: x -> x1 (bf16 [C][HW] residual) + x1T (bf16 [HW][C])
    ln_fused_kernel<float, true><<<dim3(HW / 64, BATCH), blk, 0, stream>>>(
        x, g1, b1, x1, x1T);
    // 2. qkv GEMM -> bf16 [3C][HW]
    gemm_mfma_kernel<0><<<dim3(HW / 128, (3 * CDIM) / 64, BATCH), blk, 0, stream>>>(
        wq_b, x1T, qkvA, nullptr, nullptr, 3 * CDIM, CDIM);
    // 3. depthwise 3x3 (2 rows x 8 px per thread) + q/k sumsq partials
    dw_kernel<<<dim3(DWCHUNK, 3 * CDIM, BATCH), blk, 0, stream>>>(qkvA, w_dw, dwB, sqp);
    // 4. attn partials via MFMA (inline l2-inv)
    attn_qk_kernel<<<dim3(HW / PCHUNK, HEADS, BATCH), blk, 0, stream>>>(
        dwB, sqp, temp, part);
    // 5. deterministic reduction of partials
    attn_reduce_kernel<<<dim3((BATCH * HEADS * CP * CP) / 256), blk, 0, stream>>>(part, attn);
    // 6. head conv + softmax (merged)
    headconv_softmax_kernel<<<dim3(HEADS, BATCH), blk, 0, stream>>>(attn, w_head, attn2);
    // 7. out = attn @ v via MFMA -> bf16 [HW][C] (pre-transposed for proj)
    av_kernel<<<dim3(HW / 256, HEADS, BATCH), blk, 0, stream>>>(attn2, dwB, attn_outT);
    // 8. proj GEMM + residual(x1 bf16) -> x2 bf16 [C][HW]
    gemm_mfma_kernel<1><<<dim3(HW / 128, CDIM / 64, BATCH), blk, 0, stream>>>(
        wp_b, attn_outT, x2, nullptr, x1, CDIM, CDIM);
    // 9. LayerNorm2 fused (bf16 in) -> ln2T bf16 [HW][C]
    ln_fused_kernel<bf16, false><<<dim3(HW / 64, BATCH), blk, 0, stream>>>(
        x2, g2, b2, nullptr, ln2T);
    // 10. fc1 GEMM + bias + gelu -> y1T bf16 [HW][HIDDEN]
    gemm_mfma_kernel<3><<<dim3(HW / 128, HIDDEN / 64, BATCH), blk, 0, stream>>>(
        wf1_b, ln2T, y1T, b_fc1, nullptr, HIDDEN, CDIM);
    // 11. fc2 GEMM + bias + gelu -> y2 bf16 [C][HW]
    gemm_mfma_kernel<2><<<dim3(HW / 128, CDIM / 64, BATCH), blk, 0, stream>>>(
        wf2_b, y1T, y2, b_fc2, nullptr, CDIM, HIDDEN);
    // 12. spatial gate: channel-split partials (bf16 out)
    gate_partial_kernel<<<dim3(HW / 2048, CSPLIT, BATCH), blk, 0, stream>>>(
        y2, w_sa, part_g);
    // 13. fused gate-finish + final: out = x2 + y2*sigmoid(sum(part_g)+b)
    gate_final_kernel<<<dim3(HW / 2048, CDIM / 16, BATCH), blk, 0, stream>>>(
        part_g, b_sa, x2, y2, out);
}

// Round 16
// 252.694 us; speedup vs baseline: 1.2316x; 1.0227x over previous
//
#include <hip/hip_runtime.h>
#include <hip/hip_bf16.h>
#include <math.h>

using bf16 = __hip_bfloat16;

static constexpr int CDIM   = 192;
static constexpr int HEADS  = 6;
static constexpr int CP     = 32;     // CDIM / HEADS
static constexpr int HIDDEN = 384;
static constexpr int HImg   = 128;
static constexpr int WImg   = 128;
static constexpr int HW     = HImg * WImg;   // 16384
static constexpr int BATCH  = 4;
static constexpr int PCHUNK = 256;    // attn contraction sub-chunk
static constexpr int NSUB   = 2;      // sub-chunks per attn block (512 px window)
static constexpr int NCHUNK = HW / (PCHUNK * NSUB);   // 32 partial chunks
static constexpr int CSPLIT = 12;     // gate conv channel splits (16 ch each)
static constexpr int DWCHUNK = 4;     // dw y-blocks per channel image (32 rows each)

typedef __attribute__((ext_vector_type(8))) short short8;
typedef __attribute__((ext_vector_type(4))) float f32x4;
typedef __attribute__((ext_vector_type(16))) float f32x16;
typedef __attribute__((ext_vector_type(4))) unsigned short ushort4v;
typedef __attribute__((ext_vector_type(8))) unsigned short ushort8v;

template<typename T> __device__ inline float tof(T v);
template<> __device__ inline float tof<float>(float v){ return v; }
template<> __device__ inline float tof<bf16>(bf16 v){ return __bfloat162float(v); }

template<typename T> __device__ inline T fromf(float v);
template<> __device__ inline float fromf<float>(float v){ return v; }
template<> __device__ inline bf16  fromf<bf16>(float v){ return __float2bfloat16(v); }

__device__ inline unsigned short f2bf_bits(float f){
    bf16 h = __float2bfloat16(f);
    return *reinterpret_cast<unsigned short*>(&h);
}
__device__ inline float bfbits2f(unsigned short u){
    union { unsigned int i; float f; } c; c.i = ((unsigned int)u) << 16; return c.f;
}

__device__ inline float gelu_exact(float x){
    return 0.5f * x * (1.0f + erff(x * 0.70710678118654752440f));
}

// load 4 consecutive elems as float
__device__ inline void load4f(const float* p, float* f){
    f32x4 v = *reinterpret_cast<const f32x4*>(p);
    f[0]=v[0]; f[1]=v[1]; f[2]=v[2]; f[3]=v[3];
}
__device__ inline void load4f(const bf16* p, float* f){
    ushort4v v = *reinterpret_cast<const ushort4v*>(p);
    f[0]=bfbits2f(v[0]); f[1]=bfbits2f(v[1]); f[2]=bfbits2f(v[2]); f[3]=bfbits2f(v[3]);
}

// async global(16B) -> LDS
__device__ __forceinline__ void gload16(const bf16* g, bf16* l){
    __builtin_amdgcn_global_load_lds(
        (const __attribute__((address_space(1))) void*)g,
        (__attribute__((address_space(3))) void*)l, 16, 0, 0);
}

// ---------------- merged f32 -> bf16 weight convert --------------------------
__global__ __launch_bounds__(256) void convw_kernel(
    const float* __restrict__ w_qkv, const float* __restrict__ w_proj,
    const float* __restrict__ w_fc1, const float* __restrict__ w_fc2,
    bf16* __restrict__ wq, bf16* __restrict__ wp,
    bf16* __restrict__ wf1, bf16* __restrict__ wf2)
{
    int i = blockIdx.x * 256 + threadIdx.x;
    const int n0 = 576*192, n1 = n0 + 192*192, n2 = n1 + 384*192, n3 = n2 + 192*384;
    if (i < n0)      wq[i]       = fromf<bf16>(w_qkv[i]);
    else if (i < n1) wp[i - n0]  = fromf<bf16>(w_proj[i - n0]);
    else if (i < n2) wf1[i - n1] = fromf<bf16>(w_fc1[i - n1]);
    else if (i < n3) wf2[i - n2] = fromf<bf16>(w_fc2[i - n2]);
}

// ---------------- fused LayerNorm (+optional bf16 [C][HW] copy) + transpose --
template<typename T, bool WRES>
__global__ __launch_bounds__(256) void ln_fused_kernel(
    const T* __restrict__ in, const float* __restrict__ g,
    const float* __restrict__ b, bf16* __restrict__ resF, bf16* __restrict__ outT)
{
    int z = blockIdx.y, p0 = blockIdx.x * 64;
    __shared__ float tile[CDIM][65];
    __shared__ float sred[4][64], s2red[4][64];
    __shared__ float mrow[64], rrow[64];
    const T* ib = in + (size_t)z * CDIM * HW + p0;
    int tid = threadIdx.x;
    for (int j = tid; j < CDIM * 16; j += 256){
        int c = j >> 4, p4 = (j & 15) * 4;
        float f[4];
        load4f(ib + (size_t)c * HW + p4, f);
        tile[c][p4]   = f[0]; tile[c][p4+1] = f[1];
        tile[c][p4+2] = f[2]; tile[c][p4+3] = f[3];
    }
    __syncthreads();
    int p = tid & 63, q = tid >> 6;
    float s = 0.f, s2 = 0.f;
    #pragma unroll 4
    for (int c = q * 48; c < q * 48 + 48; ++c){
        float v = tile[c][p]; s += v; s2 += v * v;
    }
    sred[q][p] = s; s2red[q][p] = s2;
    __syncthreads();
    if (tid < 64){
        float ts = sred[0][tid] + sred[1][tid] + sred[2][tid] + sred[3][tid];
        float t2 = s2red[0][tid] + s2red[1][tid] + s2red[2][tid] + s2red[3][tid];
        float mean = ts * (1.0f / CDIM);
        float var  = t2 * (1.0f / CDIM) - mean * mean;
        mrow[tid] = mean;
        rrow[tid] = rsqrtf(var + 1e-5f);
    }
    __syncthreads();
    unsigned short* oT = (unsigned short*)(outT + ((size_t)z * HW + p0) * CDIM);
    for (int j = tid; j < 64 * 48; j += 256){
        int pr = j / 48, c4 = (j % 48) * 4;
        float m = mrow[pr], r = rrow[pr];
        ushort4v o;
        #pragma unroll
        for (int k = 0; k < 4; ++k){
            int c = c4 + k;
            o[k] = f2bf_bits((tile[c][pr] - m) * r * g[c] + b[c]);
        }
        *(ushort4v*)&oT[(size_t)pr * CDIM + c4] = o;
    }
    if (WRES){
        unsigned short* oF = (unsigned short*)resF + (size_t)z * CDIM * HW + p0;
        for (int j = tid; j < CDIM * 16; j += 256){
            int c = j >> 4, p4 = (j & 15) * 4;
            float gg = g[c], bb = b[c];
            ushort4v v;
            #pragma unroll
            for (int k = 0; k < 4; ++k)
                v[k] = f2bf_bits((tile[c][p4 + k] - mrow[p4 + k]) * rrow[p4 + k] * gg + bb);
            *(ushort4v*)&oF[(size_t)c * HW + p4] = v;
        }
    }
}

// ---------------- MFMA GEMM: C[M,N] = Wb[M,K] @ XT[N,K]^T, batched -----------
// Round-8 structure (proven local optimum): 64m x 128n block, 2x2 waves
// (32m x 64n each), single-buffered LDS staging via global_load_lds,
// vmcnt(0)+syncthreads per K-tile. LDS 24 KB -> high occupancy (~35%).
// EPI: 0 = bf16 out [M][HW]; 1 = bf16 out + bf16 residual; 2 = bias+gelu bf16;
//      3 = bias+gelu -> transposed bf16 out [HW][M]
template<int EPI>
__global__ __launch_bounds__(256) void gemm_mfma_kernel(
    const bf16* __restrict__ Wb, const bf16* __restrict__ XT,
    void* __restrict__ Cout, const float* __restrict__ bias,
    const bf16* __restrict__ res, int M, int K)
{
    __shared__ bf16 smem[12288];              // A: 64x64 (4096), B: 128x64 (8192)
    bf16* Als = smem;
    bf16* Bls = smem + 4096;
    int z  = blockIdx.z;
    int n0 = blockIdx.x * 128;
    int m0 = blockIdx.y * 64;
    const bf16* Xb = XT + (size_t)z * (size_t)HW * K;
    int tid  = threadIdx.x;
    int lane = tid & 63, wid = tid >> 6;
    int wm = wid & 1, wn = wid >> 1;          // 2x2 waves, each 32m x 64n
    int r16 = lane & 15, grp = lane >> 4;

    f32x4 acc[2][4];
    #pragma unroll
    for (int i = 0; i < 2; ++i)
        #pragma unroll
        for (int j = 0; j < 4; ++j){ f32x4 zz = {0.f,0.f,0.f,0.f}; acc[i][j] = zz; }

    int nkt = K >> 6;
    for (int kt = 0; kt < nkt; ++kt){
        #pragma unroll
        for (int i = 0; i < 2; ++i){
            int s = i * 256 + tid;
            int row = s >> 3, ch = s & 7;
            gload16(Wb + (size_t)(m0 + row) * K + kt * 64 + ((ch ^ (row & 7)) * 8),
                    Als + s * 8);
        }
        #pragma unroll
        for (int i = 0; i < 4; ++i){
            int s = i * 256 + tid;
            int row = s >> 3, ch = s & 7;
            gload16(Xb + (size_t)(n0 + row) * K + kt * 64 + ((ch ^ (row & 7)) * 8),
                    Bls + s * 8);
        }
        asm volatile("s_waitcnt vmcnt(0)" ::: "memory");
        __syncthreads();
        #pragma unroll
        for (int ks = 0; ks < 2; ++ks){
            int kel = ks * 32 + grp * 8;
            short8 a[2], b[4];
            #pragma unroll
            for (int fi = 0; fi < 2; ++fi){
                int row = wm * 32 + fi * 16 + r16;
                a[fi] = *reinterpret_cast<const short8*>(Als + row * 64 + (kel ^ ((row & 7) * 8)));
            }
            #pragma unroll
            for (int fj = 0; fj < 4; ++fj){
                int row = wn * 64 + fj * 16 + r16;
                b[fj] = *reinterpret_cast<const short8*>(Bls + row * 64 + (kel ^ ((row & 7) * 8)));
            }
            #pragma unroll
            for (int fi = 0; fi < 2; ++fi)
                #pragma unroll
                for (int fj = 0; fj < 4; ++fj)
                    acc[fi][fj] = __builtin_amdgcn_mfma_f32_16x16x32_bf16(
                        a[fi], b[fj], acc[fi][fj], 0, 0, 0);
        }
        __syncthreads();
    }

    if (EPI == 3){
        // transposed bf16 out via LDS T[n(128)][m(64)] stride 72
        unsigned short* T = (unsigned short*)smem;
        #pragma unroll
        for (int fi = 0; fi < 2; ++fi)
            #pragma unroll
            for (int fj = 0; fj < 4; ++fj){
                int nl = wn * 64 + fj * 16 + r16;
                int mb = wm * 32 + fi * 16 + grp * 4;
                #pragma unroll
                for (int rr = 0; rr < 4; ++rr){
                    float v = gelu_exact(acc[fi][fj][rr] + bias[m0 + mb + rr]);
                    T[nl * 72 + mb + rr] = f2bf_bits(v);
                }
            }
        __syncthreads();
        bf16* Y = (bf16*)Cout;
        int rrow = tid >> 1, half = tid & 1;
        const short8* srcv = reinterpret_cast<const short8*>(T + rrow * 72 + half * 32);
        short8* dstv = reinterpret_cast<short8*>(
            Y + ((size_t)z * HW + n0 + rrow) * M + m0 + half * 32);
        #pragma unroll
        for (int i = 0; i < 4; ++i) dstv[i] = srcv[i];
        return;
    }

    // [M][HW] epilogues via LDS T[m(64)][n(128)] stride 136, 16B stores
    {
        unsigned short* T = (unsigned short*)smem;
        #pragma unroll
        for (int fi = 0; fi < 2; ++fi)
            #pragma unroll
            for (int fj = 0; fj < 4; ++fj){
                int m = wm * 32 + fi * 16 + grp * 4;
                int n = wn * 64 + fj * 16 + r16;
                #pragma unroll
                for (int rr = 0; rr < 4; ++rr)
                    T[(m + rr) * 136 + n] = f2bf_bits(acc[fi][fj][rr]);
            }
        __syncthreads();
        int row = tid >> 2, c8 = (tid & 3) * 8;      // 64 rows x 4 chunk-slots
        bf16* Cb = (bf16*)Cout;
        size_t gbase = (size_t)z * M * HW + (size_t)(m0 + row) * HW + n0 + c8;
        float bv = (EPI == 2) ? bias[m0 + row] : 0.f;
        #pragma unroll
        for (int j = 0; j < 4; ++j){
            int coff = j * 32;
            ushort8v t8 = *(const ushort8v*)&T[row * 136 + c8 + coff];
            ushort8v o8;
            if (EPI == 0){
                o8 = t8;
            } else if (EPI == 1){
                ushort8v r8 = *(const ushort8v*)((const unsigned short*)res + gbase + coff);
                #pragma unroll
                for (int k = 0; k < 8; ++k)
                    o8[k] = f2bf_bits(bfbits2f(t8[k]) + bfbits2f(r8[k]));
            } else {
                #pragma unroll
                for (int k = 0; k < 8; ++k)
                    o8[k] = f2bf_bits(gelu_exact(bfbits2f(t8[k]) + bv));
            }
            *(ushort8v*)((unsigned short*)Cb + gbase + coff) = o8;
        }
    }
}

// ---------------- depthwise 3x3: 2 rows x 8 px per thread + q/k sumsq --------
__global__ __launch_bounds__(256) void dw_kernel(
    const bf16* __restrict__ in, const float* __restrict__ wdw,
    bf16* __restrict__ out, float* __restrict__ sqp)
{
    int ch = blockIdx.y, z = blockIdx.z;
    int tid = threadIdx.x;
    int rp = tid >> 4;                          // 16 row-pairs per block
    int xx = (tid & 15) * 8;                    // 16 lanes per image row
    int y0 = blockIdx.x * 32 + rp * 2;          // first output row
    const unsigned short* p =
        (const unsigned short*)(in + ((size_t)z * 3 * CDIM + ch) * HW);
    float w[9];
    #pragma unroll
    for (int t = 0; t < 9; ++t) w[t] = wdw[ch * 9 + t];
    float f[4][8], lf[4], rf[4];
    #pragma unroll
    for (int r = 0; r < 4; ++r){
        int iy = y0 - 1 + r;
        if (iy >= 0 && iy < HImg){
            ushort8v v8 = *(const ushort8v*)(p + iy * WImg + xx);
            #pragma unroll
            for (int j = 0; j < 8; ++j) f[r][j] = bfbits2f(v8[j]);
        } else {
            #pragma unroll
            for (int j = 0; j < 8; ++j) f[r][j] = 0.f;
        }
        float l = __shfl_up(f[r][7], 1);
        float rr_ = __shfl_down(f[r][0], 1);
        lf[r] = (xx == 0) ? 0.f : l;
        rf[r] = (xx + 8 >= WImg) ? 0.f : rr_;
    }
    float sq = 0.f;
    unsigned short* ob = (unsigned short*)(out + ((size_t)z * 3 * CDIM + ch) * HW);
    #pragma unroll
    for (int orow = 0; orow < 2; ++orow){
        ushort8v o8;
        #pragma unroll
        for (int j = 0; j < 8; ++j){
            float a = 0.f;
            #pragma unroll
            for (int dy = 0; dy < 3; ++dy){
                int r = orow + dy;
                float e0 = (j == 0) ? lf[r] : f[r][j - 1];
                float e2 = (j == 7) ? rf[r] : f[r][j + 1];
                a = fmaf(w[dy*3], e0, fmaf(w[dy*3+1], f[r][j], fmaf(w[dy*3+2], e2, a)));
            }
            o8[j] = f2bf_bits(a);
            sq = fmaf(a, a, sq);
        }
        *(ushort8v*)(ob + (y0 + orow) * WImg + xx) = o8;
    }
    if (ch < 2 * CDIM){
        #pragma unroll
        for (int m = 1; m < 64; m <<= 1) sq += __shfl_xor(sq, m, 64);
        __shared__ float red[4];
        if ((tid & 63) == 0) red[tid >> 6] = sq;
        __syncthreads();
        if (tid == 0)
            sqp[((size_t)ch * BATCH + z) * DWCHUNK + blockIdx.x] =
                red[0] + red[1] + red[2] + red[3];
    }
}

// ---------------- attn partials via MFMA 32x32x16, 2 sub-chunks/block --------
// Per block: one (chunk of 512 px, h, z). Q,K staged per 256-px sub-chunk;
// 8 MFMAs accumulate into one 32x32 f32 acc; cross-wave reduce via LDS
// (aliased over staging); scale; write one partial per 512-px chunk.
__global__ __launch_bounds__(256) void attn_qk_kernel(
    const bf16* __restrict__ qkv, const float* __restrict__ sqp,
    const float* __restrict__ temp, float* __restrict__ part)
{
    int chunk = blockIdx.x;                        // NCHUNK = 32
    int h = blockIdx.y, z = blockIdx.z;
    __shared__ unsigned short stg[2 * 32 * 264];   // 33 KB; aliased as red after
    float* red = (float*)stg;                      // 4*32*32 f32 = 16 KB
    __shared__ float invqs[CP], invks[CP];
    int tid = threadIdx.x;
    if (tid < 2 * CP){
        int which = tid >> 5, cc = tid & 31;
        int ch = which * CDIM + h * CP + cc;
        const float* sp = &sqp[((size_t)ch * BATCH + z) * DWCHUNK];
        float s = sp[0] + sp[1] + sp[2] + sp[3];
        float inv = 1.0f / fmaxf(sqrtf(s), 1e-12f);
        (which ? invks : invqs)[cc] = inv;
    }
    const unsigned short* qb = (const unsigned short*)(qkv + ((size_t)z * 3 * CDIM + h * CP) * HW);
    const unsigned short* kb = (const unsigned short*)(qkv + ((size_t)z * 3 * CDIM + CDIM + h * CP) * HW);
    int wv = tid >> 6, lane = tid & 63;
    int row = lane & 31, koff = (lane >> 5) * 8;
    int pxb = wv * 64;
    f32x16 acc;
    #pragma unroll
    for (int r = 0; r < 16; ++r) acc[r] = 0.f;
    for (int sub = 0; sub < NSUB; ++sub){
        int n0 = (chunk * NSUB + sub) * PCHUNK;
        for (int i = tid; i < CP * (PCHUNK / 4); i += 256){
            int r = i >> 6, p4 = (i & 63) * 4;
            *(ushort4v*)&stg[r * 264 + p4] =
                *(const ushort4v*)&qb[(size_t)r * HW + n0 + p4];
            *(ushort4v*)&stg[32 * 264 + r * 264 + p4] =
                *(const ushort4v*)&kb[(size_t)r * HW + n0 + p4];
        }
        __syncthreads();
        #pragma unroll
        for (int i = 0; i < 4; ++i){
            short8 a = *(const short8*)&stg[row * 264 + pxb + i * 16 + koff];
            short8 b = *(const short8*)&stg[32 * 264 + row * 264 + pxb + i * 16 + koff];
            acc = __builtin_amdgcn_mfma_f32_32x32x16_bf16(a, b, acc, 0, 0, 0);
        }
        __syncthreads();      // ds_reads done before restage / aliasing
    }
    #pragma unroll
    for (int r = 0; r < 16; ++r){
        int ro = (r & 3) + 8 * (r >> 2) + 4 * (lane >> 5);   // verified C/D map
        red[(wv * 32 + ro) * 32 + (lane & 31)] = acc[r];
    }
    __syncthreads();
    int c  = tid >> 3;
    int d0 = (tid & 7) * 4;
    float sc = invqs[c] * temp[h];
    size_t base = ((size_t)chunk * BATCH * HEADS + (size_t)z * HEADS + h) * CP * CP
                + c * CP + d0;
    #pragma unroll
    for (int j = 0; j < 4; ++j){
        int d = d0 + j;
        float s = red[(0 * 32 + c) * 32 + d] + red[(1 * 32 + c) * 32 + d]
                + red[(2 * 32 + c) * 32 + d] + red[(3 * 32 + c) * 32 + d];
        part[base + j] = s * sc * invks[d];
    }
}

__global__ __launch_bounds__(256) void attn_reduce_kernel(
    const float* __restrict__ part, float* __restrict__ attn)
{
    int idx = blockIdx.x * 256 + threadIdx.x;
    float s = 0.f;
    for (int ch = 0; ch < NCHUNK; ++ch)
        s += part[(size_t)ch * (BATCH * HEADS * CP * CP) + idx];
    attn[idx] = s;
}

// ---------------- head conv 3x3 + softmax (merged) ---------------------------
__global__ __launch_bounds__(256) void headconv_softmax_kernel(
    const float* __restrict__ attn, const float* __restrict__ wh,
    float* __restrict__ attn2)
{
    int oh = blockIdx.x, z = blockIdx.y;
    __shared__ float wsm[HEADS * 9];
    __shared__ float ain[HEADS][CP * CP];
    __shared__ float aout[CP * CP];
    int tid = threadIdx.x;
    if (tid < HEADS * 9) wsm[tid] = wh[oh * HEADS * 9 + tid];
    for (int i = tid; i < HEADS * CP * CP; i += 256)
        ain[i >> 10][i & 1023] = attn[((size_t)z * HEADS + (i >> 10)) * CP * CP + (i & 1023)];
    __syncthreads();
    for (int idx = tid; idx < CP * CP; idx += 256){
        int i = idx >> 5, j = idx & 31;
        float acc = 0.f;
        #pragma unroll
        for (int ih = 0; ih < HEADS; ++ih){
            #pragma unroll
            for (int dy = 0; dy < 3; ++dy){
                int ii = i + dy - 1;
                if (ii < 0 || ii >= CP) continue;
                #pragma unroll
                for (int dx = 0; dx < 3; ++dx){
                    int jj = j + dx - 1;
                    if (jj < 0 || jj >= CP) continue;
                    acc += wsm[ih * 9 + dy * 3 + dx] * ain[ih][ii * CP + jj];
                }
            }
        }
        aout[idx] = acc;
    }
    __syncthreads();
    int r = tid >> 3, l8 = tid & 7;
    float v[4];
    #pragma unroll
    for (int k = 0; k < 4; ++k) v[k] = aout[r * CP + l8 * 4 + k];
    float mx = fmaxf(fmaxf(v[0], v[1]), fmaxf(v[2], v[3]));
    #pragma unroll
    for (int m = 1; m < 8; m <<= 1) mx = fmaxf(mx, __shfl_xor(mx, m, 64));
    float sum = 0.f;
    #pragma unroll
    for (int k = 0; k < 4; ++k){ v[k] = expf(v[k] - mx); sum += v[k]; }
    #pragma unroll
    for (int m = 1; m < 8; m <<= 1) sum += __shfl_xor(sum, m, 64);
    float rs = 1.0f / sum;
    float* o = attn2 + ((size_t)z * HEADS + oh) * CP * CP + r * CP + l8 * 4;
    #pragma unroll
    for (int k = 0; k < 4; ++k) o[k] = v[k] * rs;
}

// ---------------- out = attn2 @ v via MFMA -> transposed bf16 [HW][C] --------
__global__ __launch_bounds__(256) void av_kernel(
    const float* __restrict__ attn2, const bf16* __restrict__ qkv, bf16* __restrict__ outT)
{
    int h = blockIdx.y, z = blockIdx.z;
    int tid = threadIdx.x;
    __shared__ unsigned short Abf[32 * 40];        // 2.5 KB
    __shared__ unsigned short Vt[256 * 40];        // 20 KB; aliased as ot after
    unsigned short* ot = Vt;                       // ot[n*36 + c], 18.4 KB
    const float* ab = attn2 + ((size_t)(z * HEADS + h)) * CP * CP;
    for (int i = tid; i < CP * CP; i += 256)
        Abf[(i >> 5) * 40 + (i & 31)] = f2bf_bits(ab[i]);
    int n0 = blockIdx.x * 256;
    const unsigned short* vb =
        (const unsigned short*)(qkv + ((size_t)z * 3 * CDIM + 2 * CDIM + h * CP) * HW) + n0;
    for (int i = tid; i < CP * 64; i += 256){
        int d = i >> 6, p4 = (i & 63) * 4;
        ushort4v v = *(const ushort4v*)(vb + (size_t)d * HW + p4);
        Vt[(p4 + 0) * 40 + d] = v[0];
        Vt[(p4 + 1) * 40 + d] = v[1];
        Vt[(p4 + 2) * 40 + d] = v[2];
        Vt[(p4 + 3) * 40 + d] = v[3];
    }
    __syncthreads();
    int wv = tid >> 6, lane = tid & 63;
    int rowa = lane & 31, koff = (lane >> 5) * 8;
    f32x16 acc[2];
    #pragma unroll
    for (int g = 0; g < 2; ++g)
        #pragma unroll
        for (int r = 0; r < 16; ++r) acc[g][r] = 0.f;
    #pragma unroll
    for (int kh = 0; kh < 2; ++kh){
        short8 a = *(const short8*)&Abf[rowa * 40 + kh * 16 + koff];
        #pragma unroll
        for (int g = 0; g < 2; ++g){
            int ncol = wv * 64 + g * 32 + (lane & 31);
            short8 b = *(const short8*)&Vt[ncol * 40 + kh * 16 + koff];
            acc[g] = __builtin_amdgcn_mfma_f32_32x32x16_bf16(a, b, acc[g], 0, 0, 0);
        }
    }
    __syncthreads();          // Vt reads complete before aliasing as ot
    #pragma unroll
    for (int g = 0; g < 2; ++g){
        int n = wv * 64 + g * 32 + (lane & 31);
        #pragma unroll
        for (int r = 0; r < 16; ++r){
            int c = (r & 3) + 8 * (r >> 2) + 4 * (lane >> 5);
            ot[n * 36 + c] = f2bf_bits(acc[g][r]);
        }
    }
    __syncthreads();
    unsigned short* ob = (unsigned short*)outT
        + ((size_t)z * HW + (size_t)n0) * CDIM + h * CP;
    for (int j = tid; j < 256 * 8; j += 256){
        int row = j >> 3, q4 = (j & 7) * 4;
        *(ushort4v*)&ob[(size_t)row * CDIM + q4] = *(ushort4v*)&ot[row * 36 + q4];
    }
}

// ---------------- spatial gate partials (16 ch/block, 8 px/thread, bf16 out) -
__global__ __launch_bounds__(256) void gate_partial_kernel(
    const bf16* __restrict__ y, const float* __restrict__ wsa,
    bf16* __restrict__ part_g)
{
    int cs = blockIdx.y, z = blockIdx.z;
    __shared__ float wsm[16 * 9];
    if (threadIdx.x < 144) wsm[threadIdx.x] = wsa[cs * 144 + threadIdx.x];
    __syncthreads();
    int idx = blockIdx.x * 2048 + threadIdx.x * 8;
    int yy = idx >> 7, xx = idx & 127;
    const unsigned short* yb =
        (const unsigned short*)(y + (size_t)z * CDIM * HW + (size_t)cs * 16 * HW);
    float acc[8] = {0.f,0.f,0.f,0.f,0.f,0.f,0.f,0.f};
    for (int c = 0; c < 16; ++c){
        const unsigned short* pc = yb + (size_t)c * HW;
        #pragma unroll
        for (int dy = 0; dy < 3; ++dy){
            int iy = yy + dy - 1;
            float f[8], lf, rf;
            if (iy >= 0 && iy < HImg){
                ushort8v v8 = *(const ushort8v*)(pc + iy * WImg + xx);
                #pragma unroll
                for (int j = 0; j < 8; ++j) f[j] = bfbits2f(v8[j]);
            } else {
                #pragma unroll
                for (int j = 0; j < 8; ++j) f[j] = 0.f;
            }
            float l = __shfl_up(f[7], 1);
            float r = __shfl_down(f[0], 1);
            lf = (xx == 0) ? 0.f : l;
            rf = (xx + 8 >= WImg) ? 0.f : r;
            const float* wr = &wsm[c * 9 + dy * 3];
            #pragma unroll
            for (int j = 0; j < 8; ++j){
                float e0 = (j == 0) ? lf : f[j - 1];
                float e2 = (j == 7) ? rf : f[j + 1];
                acc[j] = fmaf(wr[0], e0, fmaf(wr[1], f[j], fmaf(wr[2], e2, acc[j])));
            }
        }
    }
    ushort8v o8;
    #pragma unroll
    for (int j = 0; j < 8; ++j) o8[j] = f2bf_bits(acc[j]);
    *(ushort8v*)((unsigned short*)part_g + ((size_t)cs * BATCH + z) * HW + idx) = o8;
}

// ---------------- fused gate-finish + final ----------------------------------
__global__ __launch_bounds__(256) void gate_final_kernel(
    const bf16* __restrict__ part_g, const float* __restrict__ bsa,
    const bf16* __restrict__ x2, const bf16* __restrict__ y2,
    float* __restrict__ out)
{
    int pg = blockIdx.x;              // HW/2048 = 8 pixel groups
    int cg = blockIdx.y;              // 12 channel groups of 16
    int z  = blockIdx.z;
    int tid = threadIdx.x;
    int n0 = pg * 2048;
    __shared__ float gl[2048];
    {
        int n = tid * 8;
        float b0 = bsa[0];
        float acc[8];
        #pragma unroll
        for (int j = 0; j < 8; ++j) acc[j] = b0;
        #pragma unroll
        for (int cs = 0; cs < CSPLIT; ++cs){
            ushort8v v = *(const ushort8v*)((const unsigned short*)part_g
                          + ((size_t)cs * BATCH + z) * HW + n0 + n);
            #pragma unroll
            for (int j = 0; j < 8; ++j) acc[j] += bfbits2f(v[j]);
        }
        #pragma unroll
        for (int j = 0; j < 8; ++j)
            gl[n + j] = 1.0f / (1.0f + expf(-acc[j]));
    }
    __syncthreads();
    int n8 = tid * 8;
    #pragma unroll
    for (int c = 0; c < 16; ++c){
        int cc = cg * 16 + c;
        size_t base = ((size_t)z * CDIM + cc) * HW + n0 + n8;
        ushort8v a8 = *(const ushort8v*)((const unsigned short*)x2 + base);
        ushort8v b8 = *(const ushort8v*)((const unsigned short*)y2 + base);
        f32x4 o0, o1;
        #pragma unroll
        for (int j = 0; j < 4; ++j){
            o0[j] = bfbits2f(a8[j])     + bfbits2f(b8[j])     * gl[n8 + j];
            o1[j] = bfbits2f(a8[j + 4]) + bfbits2f(b8[j + 4]) * gl[n8 + j + 4];
        }
        *(f32x4*)(out + base) = o0;
        *(f32x4*)(out + base + 4) = o1;
    }
}

extern "C" void kernel_launch(void* const* d_in, const int* in_sizes, int n_in,
                              void* d_out, int out_size, void* d_ws, size_t ws_size,
                              hipStream_t stream)
{
    const float* x      = (const float*)d_in[0];
    const float* g1     = (const float*)d_in[1];
    const float* b1     = (const float*)d_in[2];
    const float* w_qkv  = (const float*)d_in[3];
    const float* w_dw   = (const float*)d_in[4];
    const float* temp   = (const float*)d_in[5];
    const float* w_head = (const float*)d_in[6];
    const float* w_proj = (const float*)d_in[7];
    const float* g2     = (const float*)d_in[8];
    const float* b2     = (const float*)d_in[9];
    const float* w_fc1  = (const float*)d_in[10];
    const float* b_fc1  = (const float*)d_in[11];
    const float* w_fc2  = (const float*)d_in[12];
    const float* b_fc2  = (const float*)d_in[13];
    const float* w_sa   = (const float*)d_in[14];
    const float* b_sa   = (const float*)d_in[15];
    float* out = (float*)d_out;

    char* ws = (char*)d_ws;
    const size_t FULL = (size_t)BATCH * CDIM * HW;      // 12.58M elems

    // R0 (FULL*2 B): x1 bf16 [C][HW] -> y2 bf16 [C][HW]
    bf16* x1 = (bf16*)ws;
    bf16* y2 = x1;
    // R1 (3*FULL*2 B): qkvA bf16 -> attn_outT bf16 / ln2T bf16 / y1T bf16
    char* R1 = ws + FULL * 2;
    bf16*  qkvA      = (bf16*)R1;
    bf16*  attn_outT = (bf16*)R1;
    bf16*  ln2T      = (bf16*)R1;
    bf16*  y1T       = (bf16*)(R1 + FULL * 2);
    // R2 (3*FULL*2 B): x1T bf16 -> dwB bf16 -> x2 bf16
    char* R2 = R1 + FULL * 3 * 2;
    bf16*  x1T = (bf16*)R2;
    bf16*  dwB = (bf16*)R2;
    bf16*  x2  = (bf16*)R2;
    // small region
    char* SM = R2 + FULL * 3 * 2;
    float* attn   = (float*)SM;                             // B*HEADS*CP*CP
    float* attn2  = attn + BATCH * HEADS * CP * CP;
    float* gate   = attn2 + BATCH * HEADS * CP * CP;        // (unused slot)
    float* sqp    = gate + BATCH * HW;                      // 2*CDIM*B*DWCHUNK
    float* part   = sqp + 2 * CDIM * BATCH * DWCHUNK;       // 32*B*H*CP*CP (3.1MB)
    bf16*  part_g = (bf16*)part;                            // aliases part (dead)
    bf16* wq_b  = (bf16*)(part + (size_t)NCHUNK * BATCH * HEADS * CP * CP);
    bf16* wp_b  = wq_b  + 576 * 192;
    bf16* wf1_b = wp_b  + 192 * 192;
    bf16* wf2_b = wf1_b + 384 * 192;

    dim3 blk(256);

    // 0. merged weight conversion to bf16
    convw_kernel<<<dim3((294912 + 255) / 256), blk, 0, stream>>>(
        w_qkv, w_proj, w_fc1, w_fc2, wq_b, wp_b, wf1_b, wf2_b);
    // 1. LayerNorm1 fused: x -> x1 (bf16 [C][HW] residual) + x1T (bf16 [HW][C])
    ln_fused_kernel<float, true><<<dim3(HW / 64, BATCH), blk, 0, stream>>>(
        x, g1, b1, x1, x1T);
    // 2. qkv GEMM -> bf16 [3C][HW]
    gemm_mfma_kernel<0><<<dim3(HW / 128, (3 * CDIM) / 64, BATCH), blk, 0, stream>>>(
        wq_b, x1T, qkvA, nullptr, nullptr, 3 * CDIM, CDIM);
    // 3. depthwise 3x3 (2 rows x 8 px per thread) + q/k sumsq partials
    dw_kernel<<<dim3(DWCHUNK, 3 * CDIM, BATCH), blk, 0, stream>>>(qkvA, w_dw, dwB, sqp);
    // 4. attn partials via MFMA, 2 sub-chunks/block (inline l2-inv)
    attn_qk_kernel<<<dim3(NCHUNK, HEADS, BATCH), blk, 0, stream>>>(
        dwB, sqp, temp, part);
    // 5. deterministic reduction of partials
    attn_reduce_kernel<<<dim3((BATCH * HEADS * CP * CP) / 256), blk, 0, stream>>>(part, attn);
    // 6. head conv + softmax (merged)
    headconv_softmax_kernel<<<dim3(HEADS, BATCH), blk, 0, stream>>>(attn, w_head, attn2);
    // 7. out = attn @ v via MFMA -> bf16 [HW][C] (pre-transposed for proj)
    av_kernel<<<dim3(HW / 256, HEADS, BATCH), blk, 0, stream>>>(attn2, dwB, attn_outT);
    // 8. proj GEMM + residual(x1 bf16) -> x2 bf16 [C][HW]
    gemm_mfma_kernel<1><<<dim3(HW / 128, CDIM / 64, BATCH), blk, 0, stream>>>(
        wp_b, attn_outT, x2, nullptr, x1, CDIM, CDIM);
    // 9. LayerNorm2 fused (bf16 in) -> ln2T bf16 [HW][C]
    ln_fused_kernel<bf16, false><<<dim3(HW / 64, BATCH), blk, 0, stream>>>(
        x2, g2, b2, nullptr, ln2T);
    // 10. fc1 GEMM + bias + gelu -> y1T bf16 [HW][HIDDEN]
    gemm_mfma_kernel<3><<<dim3(HW / 128, HIDDEN / 64, BATCH), blk, 0, stream>>>(
        wf1_b, ln2T, y1T, b_fc1, nullptr, HIDDEN, CDIM);
    // 11. fc2 GEMM + bias + gelu -> y2 bf16 [C][HW]
    gemm_mfma_kernel<2><<<dim3(HW / 128, CDIM / 64, BATCH), blk, 0, stream>>>(
        wf2_b, y1T, y2, b_fc2, nullptr, CDIM, HIDDEN);
    // 12. spatial gate: channel-split partials (bf16 out)
    gate_partial_kernel<<<dim3(HW / 2048, CSPLIT, BATCH), blk, 0, stream>>>(
        y2, w_sa, part_g);
    // 13. fused gate-finish + final: out = x2 + y2*sigmoid(sum(part_g)+b)
    gate_final_kernel<<<dim3(HW / 2048, CDIM / 16, BATCH), blk, 0, stream>>>(
        part_g, b_sa, x2, y2, out);
}